// Round 5
// baseline (179.704 us; speedup 1.0000x reference)
//
#include <hip/hip_runtime.h>
#include <math.h>

#define N 16384
#define KNN 16
#define G 14
#define NCELL (G * G * G)  // 2744

typedef __attribute__((ext_vector_type(8))) short bf16x8;
typedef __attribute__((ext_vector_type(4))) float f32x4;
typedef unsigned short ushort_t;
typedef unsigned long long u64;

__device__ __forceinline__ float lrelu(float a) { return a > 0.f ? a : 0.01f * a; }

__device__ __forceinline__ ushort_t f2bf(float f) {
  unsigned u = __float_as_uint(f);
  u += 0x7FFF + ((u >> 16) & 1);
  return (ushort_t)(u >> 16);
}
__device__ __forceinline__ float bf2f(ushort_t h) {
  return __uint_as_float((unsigned)h << 16);
}
__device__ __forceinline__ float bflo(unsigned u) {  // low bf16 of a pair
  return __uint_as_float(u << 16);
}
__device__ __forceinline__ float bfhi(unsigned u) {  // high bf16 of a pair
  return __uint_as_float(u & 0xffff0000u);
}
__device__ __forceinline__ int lanerank(u64 mask) {
  return __builtin_amdgcn_mbcnt_hi((unsigned)(mask >> 32),
         __builtin_amdgcn_mbcnt_lo((unsigned)mask, 0));
}
__device__ __forceinline__ int cellof(float x) {
  int c = (int)(x * (float)G);
  return c < 0 ? 0 : (c > G - 1 ? G - 1 : c);
}
__device__ __forceinline__ int cellid(float x, float y, float z) {
  return (cellof(z) * G + cellof(y)) * G + cellof(x);
}

// ---------------------------------------------------------------------------
// prepw: prep (blocks 0..255, + cell histogram) + weight conv (256..603).
// fwp2 layout: element (j,ch) at (j>>2)*128 + ch*4 + (j&3), j<416.
// ---------------------------------------------------------------------------
#define PPB 64
__global__ __launch_bounds__(256) void prepw_kernel(
    const float* __restrict__ img, const float* __restrict__ cloud,
    const float* __restrict__ p1w, const float* __restrict__ p1b,
    const float* __restrict__ p2w, const float* __restrict__ p2b,
    const float* __restrict__ ps1w, const float* __restrict__ ps2w,
    const float* __restrict__ c1w, const float* __restrict__ c2w,
    const float* __restrict__ fw,
    float4* __restrict__ pts4, ushort_t* __restrict__ cfh,
    ushort_t* __restrict__ imfh,
    ushort_t* __restrict__ w1h, ushort_t* __restrict__ w2h,
    ushort_t* __restrict__ c1h, ushort_t* __restrict__ c2h,
    float* __restrict__ fwp2, int* __restrict__ count) {
  int t = threadIdx.x;
  if (blockIdx.x >= 256) {
    int e = (blockIdx.x - 256) * 256 + t;
    if (e < 32768) w1h[e] = f2bf(ps1w[e]);
    else if (e < 65536) w2h[e - 32768] = f2bf(ps2w[e - 32768]);
    else if (e < 67584) c1h[e - 65536] = f2bf(c1w[e - 65536]);
    else if (e < 75776) c2h[e - 67584] = f2bf(c2w[e - 67584]);
    else if (e < 89088) {
      int e2 = e - 75776;
      int j4 = e2 >> 7, r2 = e2 & 127;
      int ch = r2 >> 2, sub = r2 & 3;
      fwp2[e2] = fw[ch * 416 + j4 * 4 + sub];
    }
    return;
  }
  __shared__ alignas(16) float w2t[64 * 132];
  __shared__ alignas(16) float hs[PPB * 68];
  __shared__ alignas(16) float w1s[192];
  __shared__ alignas(16) float b1s[64];
  __shared__ alignas(16) float b2s[128];
  __shared__ float ptmp[PPB * 3];
  __shared__ float psx[PPB], psy[PPB], psz[PPB];
  int pb = blockIdx.x * PPB;

  for (int e = t; e < 128 * 64; e += 256) {
    int ch = e >> 6, k = e & 63;
    w2t[k * 132 + ch] = p2w[e];
  }
  if (t < 192) w1s[t] = p1w[t];
  if (t < 64) b1s[t] = p1b[t];
  if (t < 128) b2s[t] = p2b[t];
  if (t < PPB * 3) ptmp[t] = cloud[pb * 3 + t];
  __syncthreads();
  if (t < PPB) {
    float x = ptmp[t * 3], y = ptmp[t * 3 + 1], z = ptmp[t * 3 + 2];
    psx[t] = x; psy[t] = y; psz[t] = z;
    pts4[pb + t] = make_float4(x, y, z, x * x + y * y + z * z);
    atomicAdd(&count[cellid(x, y, z)], 1);
  }
  for (int e = t; e < 32 * PPB; e += 256) {
    int c = e >> 6, p = e & 63;
    imfh[(size_t)(pb + p) * 32 + c] = f2bf(img[(size_t)c * N + pb + p]);
  }
  __syncthreads();
  for (int e = t; e < PPB * 64; e += 256) {
    int pt_ = e >> 6, ch = e & 63;
    float a = b1s[ch] + psx[pt_] * w1s[ch * 3] + psy[pt_] * w1s[ch * 3 + 1] +
              psz[pt_] * w1s[ch * 3 + 2];
    hs[pt_ * 68 + ch] = lrelu(a);
  }
  __syncthreads();
  for (int e = t; e < PPB * 32; e += 256) {
    int pt_ = e >> 5, c4 = (e & 31) << 2;
    float4 acc = *(const float4*)&b2s[c4];
    const float* hrow = &hs[pt_ * 68];
    #pragma unroll
    for (int k = 0; k < 64; k += 4) {
      float4 h4 = *(const float4*)&hrow[k];
      float4 w0 = *(const float4*)&w2t[(k + 0) * 132 + c4];
      float4 w1_ = *(const float4*)&w2t[(k + 1) * 132 + c4];
      float4 w2_ = *(const float4*)&w2t[(k + 2) * 132 + c4];
      float4 w3 = *(const float4*)&w2t[(k + 3) * 132 + c4];
      acc.x = fmaf(h4.x, w0.x, fmaf(h4.y, w1_.x, fmaf(h4.z, w2_.x, fmaf(h4.w, w3.x, acc.x))));
      acc.y = fmaf(h4.x, w0.y, fmaf(h4.y, w1_.y, fmaf(h4.z, w2_.y, fmaf(h4.w, w3.y, acc.y))));
      acc.z = fmaf(h4.x, w0.z, fmaf(h4.y, w1_.z, fmaf(h4.z, w2_.z, fmaf(h4.w, w3.z, acc.z))));
      acc.w = fmaf(h4.x, w0.w, fmaf(h4.y, w1_.w, fmaf(h4.z, w2_.w, fmaf(h4.w, w3.w, acc.w))));
    }
    unsigned lo = (unsigned)f2bf(acc.x) | ((unsigned)f2bf(acc.y) << 16);
    unsigned hi = (unsigned)f2bf(acc.z) | ((unsigned)f2bf(acc.w) << 16);
    *(uint2*)&cfh[(size_t)(pb + pt_) * 128 + c4] = make_uint2(lo, hi);
  }
}

// ---------------------------------------------------------------------------
// scan: exclusive prefix over NCELL cell counts (1 block, 11 cells/thread).
// ---------------------------------------------------------------------------
__global__ __launch_bounds__(256) void scan_kernel(
    const int* __restrict__ count, int* __restrict__ cellStart,
    int* __restrict__ cellofs) {
  __shared__ int part[256];
  int t = threadIdx.x;
  int local[11];
  int s = 0;
  #pragma unroll
  for (int j = 0; j < 11; ++j) {
    int idx = t * 11 + j;
    local[j] = s;
    s += (idx < NCELL) ? count[idx] : 0;
  }
  part[t] = s;
  __syncthreads();
  for (int off = 1; off < 256; off <<= 1) {
    int v = (t >= off) ? part[t - off] : 0;
    __syncthreads();
    part[t] += v;
    __syncthreads();
  }
  int base = part[t] - s;
  #pragma unroll
  for (int j = 0; j < 11; ++j) {
    int idx = t * 11 + j;
    int v = base + local[j];
    if (idx < NCELL) { cellStart[idx] = v; cellofs[idx] = v; }
  }
  if (t == 255) cellStart[NCELL] = part[255];
}

// ---------------------------------------------------------------------------
// scatter: points into cell-sorted order; original index packed into .w.
// ---------------------------------------------------------------------------
__global__ __launch_bounds__(256) void scatter_kernel(
    const float4* __restrict__ pts4, int* __restrict__ cellofs,
    float4* __restrict__ spts) {
  int p = blockIdx.x * 256 + threadIdx.x;
  float4 v = pts4[p];
  int pos = atomicAdd(&cellofs[cellid(v.x, v.y, v.z)], 1);
  spts[pos] = make_float4(v.x, v.y, v.z, __int_as_float(p));
}

// ---------------------------------------------------------------------------
// ymlp: deduplicated dense MLPs (unchanged).
// ---------------------------------------------------------------------------
#define NB_LD 136
#define S1_LD 264
#define NI_LD 40
#define H1_LD 72
__global__ __launch_bounds__(256) void ymlp_kernel(
    const ushort_t* __restrict__ cfh, const ushort_t* __restrict__ imfh,
    const ushort_t* __restrict__ w1h, const float* __restrict__ b1,
    const ushort_t* __restrict__ w2h, const float* __restrict__ b2,
    const ushort_t* __restrict__ c1h, const float* __restrict__ c1b,
    const ushort_t* __restrict__ c2h, const float* __restrict__ c2b,
    ushort_t* __restrict__ ycf, ushort_t* __restrict__ yimg) {
  __shared__ ushort_t nb[64 * NB_LD];
  __shared__ ushort_t s1[64 * S1_LD];
  int t = threadIdx.x;
  int w = t >> 6, lane = t & 63;
  int col = lane & 15, quad = lane >> 4;

  if (blockIdx.x < 256) {
    int pbase = blockIdx.x * 64;
    for (int e = t; e < 1024; e += 256) {
      int row = e >> 4, c8 = (e & 15) << 3;
      *(uint4*)&nb[row * NB_LD + c8] =
          *(const uint4*)&cfh[(size_t)(pbase + row) * 128 + c8];
    }
    __syncthreads();
    f32x4 acc1[4][4];
    #pragma unroll
    for (int tt = 0; tt < 4; ++tt)
      #pragma unroll
      for (int p = 0; p < 4; ++p) acc1[tt][p] = (f32x4){0.f, 0.f, 0.f, 0.f};
    for (int k0 = 0; k0 < 128; k0 += 32) {
      bf16x8 a[4];
      #pragma unroll
      for (int p = 0; p < 4; ++p)
        a[p] = *(const bf16x8*)&nb[(p * 16 + col) * NB_LD + k0 + quad * 8];
      #pragma unroll
      for (int tt = 0; tt < 4; ++tt) {
        int n = w * 64 + tt * 16 + col;
        bf16x8 b = *(const bf16x8*)&w1h[n * 128 + k0 + quad * 8];
        #pragma unroll
        for (int p = 0; p < 4; ++p)
          acc1[tt][p] = __builtin_amdgcn_mfma_f32_16x16x32_bf16(a[p], b, acc1[tt][p], 0, 0, 0);
      }
    }
    #pragma unroll
    for (int tt = 0; tt < 4; ++tt) {
      int n = w * 64 + tt * 16 + col;
      float bb = b1[n];
      #pragma unroll
      for (int p = 0; p < 4; ++p)
        #pragma unroll
        for (int r = 0; r < 4; ++r)
          s1[(p * 16 + quad * 4 + r) * S1_LD + n] = f2bf(lrelu(acc1[tt][p][r] + bb));
    }
    __syncthreads();
    f32x4 acc2[2][4];
    #pragma unroll
    for (int tt = 0; tt < 2; ++tt)
      #pragma unroll
      for (int p = 0; p < 4; ++p) acc2[tt][p] = (f32x4){0.f, 0.f, 0.f, 0.f};
    for (int k0 = 0; k0 < 256; k0 += 32) {
      bf16x8 a[4];
      #pragma unroll
      for (int p = 0; p < 4; ++p)
        a[p] = *(const bf16x8*)&s1[(p * 16 + col) * S1_LD + k0 + quad * 8];
      #pragma unroll
      for (int tt = 0; tt < 2; ++tt) {
        int n = w * 32 + tt * 16 + col;
        bf16x8 b = *(const bf16x8*)&w2h[n * 256 + k0 + quad * 8];
        #pragma unroll
        for (int p = 0; p < 4; ++p)
          acc2[tt][p] = __builtin_amdgcn_mfma_f32_16x16x32_bf16(a[p], b, acc2[tt][p], 0, 0, 0);
      }
    }
    #pragma unroll
    for (int tt = 0; tt < 2; ++tt) {
      int n = w * 32 + tt * 16 + col;
      float bb = b2[n];
      #pragma unroll
      for (int p = 0; p < 4; ++p)
        #pragma unroll
        for (int r = 0; r < 4; ++r)
          ycf[(size_t)(pbase + p * 16 + quad * 4 + r) * 128 + n] =
              f2bf(acc2[tt][p][r] + bb);
    }
  } else {
    int pbase = (blockIdx.x - 256) * 64;
    ushort_t* nbi = nb;
    ushort_t* h1 = s1;
    {
      int row = t >> 2, c8 = (t & 3) << 3;
      *(uint4*)&nbi[row * NI_LD + c8] =
          *(const uint4*)&imfh[(size_t)(pbase + row) * 32 + c8];
    }
    __syncthreads();
    {
      f32x4 accA[4];
      #pragma unroll
      for (int p = 0; p < 4; ++p) accA[p] = (f32x4){0.f, 0.f, 0.f, 0.f};
      int n = w * 16 + col;
      bf16x8 b = *(const bf16x8*)&c1h[n * 32 + quad * 8];
      #pragma unroll
      for (int p = 0; p < 4; ++p) {
        bf16x8 a = *(const bf16x8*)&nbi[(p * 16 + col) * NI_LD + quad * 8];
        accA[p] = __builtin_amdgcn_mfma_f32_16x16x32_bf16(a, b, accA[p], 0, 0, 0);
      }
      __syncthreads();
      float bb = c1b[n];
      #pragma unroll
      for (int p = 0; p < 4; ++p)
        #pragma unroll
        for (int r = 0; r < 4; ++r)
          h1[(p * 16 + quad * 4 + r) * H1_LD + n] = f2bf(lrelu(accA[p][r] + bb));
    }
    __syncthreads();
    f32x4 acc2[2][4];
    #pragma unroll
    for (int tt = 0; tt < 2; ++tt)
      #pragma unroll
      for (int p = 0; p < 4; ++p) acc2[tt][p] = (f32x4){0.f, 0.f, 0.f, 0.f};
    for (int k0 = 0; k0 < 64; k0 += 32) {
      bf16x8 a[4];
      #pragma unroll
      for (int p = 0; p < 4; ++p)
        a[p] = *(const bf16x8*)&h1[(p * 16 + col) * H1_LD + k0 + quad * 8];
      #pragma unroll
      for (int tt = 0; tt < 2; ++tt) {
        int n = w * 32 + tt * 16 + col;
        bf16x8 b = *(const bf16x8*)&c2h[n * 64 + k0 + quad * 8];
        #pragma unroll
        for (int p = 0; p < 4; ++p)
          acc2[tt][p] = __builtin_amdgcn_mfma_f32_16x16x32_bf16(a[p], b, acc2[tt][p], 0, 0, 0);
      }
    }
    #pragma unroll
    for (int tt = 0; tt < 2; ++tt) {
      int n = w * 32 + tt * 16 + col;
      float bb = c2b[n];
      #pragma unroll
      for (int p = 0; p < 4; ++p)
        #pragma unroll
        for (int r = 0; r < 4; ++r)
          yimg[(size_t)(pbase + p * 16 + quad * 4 + r) * 128 + n] =
              f2bf(acc2[tt][p][r] + bb);
    }
  }
}

// ---------------------------------------------------------------------------
// knng: grid KNN (exact top-16) fused with gather-max + feat + final GEMV.
// 256-deep key buffer: ring-1 (~161 cand) runs ONE select instead of two
// (compaction only at cnt>192). Select = 2-bit-per-iter ballot radix
// (16 dependent iterations, 3 independent ballots each), NS-templated on
// buffer occupancy. Binary search depth adapts to run count (4/5/6 steps).
// ---------------------------------------------------------------------------
__device__ __forceinline__ float tadj(float tau, float qw) {
  float a = tau - qw;
  return a + fabsf(a) * 2e-7f + 1e-35f;
}

template <int NS>
__device__ __forceinline__ u64 selimpl(u64* buf, int cnt, int lane,
                                       float& tau) {
  u64 v[NS];
  unsigned k[NS];
  #pragma unroll
  for (int s = 0; s < NS; ++s) {
    int idx = s * 64 + lane;
    v[s] = (idx < cnt) ? buf[idx] : ~0ULL;
    k[s] = (unsigned)(v[s] >> 32);
  }
  // phase 1: m = 16th smallest d2-bits, 2 bits per iteration.
  unsigned m = 0u;
  #pragma unroll
  for (int b = 30; b >= 0; b -= 2) {
    unsigned p1 = m | (1u << b);
    unsigned p2 = m | (2u << b);
    unsigned p3 = m | (3u << b);
    int c1 = 0, c2 = 0, c3 = 0;
    #pragma unroll
    for (int s = 0; s < NS; ++s) {
      c1 += __popcll(__ballot(k[s] < p1));
      c2 += __popcll(__ballot(k[s] < p2));
      c3 += __popcll(__ballot(k[s] < p3));
    }
    if (c3 < KNN) m = p3;
    else if (c2 < KNN) m = p2;
    else if (c1 < KNN) m = p1;
  }
  // phase 2: tie-break on oid among keys equal to m (rare).
  int c_lt = 0, ne = 0;
  bool e[NS];
  #pragma unroll
  for (int s = 0; s < NS; ++s) {
    c_lt += __popcll(__ballot(k[s] < m));
    e[s] = (k[s] == m);
    ne += __popcll(__ballot(e[s]));
  }
  int need_eq = KNN - c_lt;
  unsigned m2 = 0xFFFFFFFFu;
  if (ne != need_eq) {
    m2 = 0u;
    #pragma unroll
    for (int b = 13; b >= 0; --b) {
      unsigned probe = m2 | (1u << b);
      int c = 0;
      #pragma unroll
      for (int s = 0; s < NS; ++s)
        c += __popcll(__ballot(e[s] && ((unsigned)v[s] < probe)));
      if (c < need_eq) m2 = probe;
    }
  }
  // compact the exact top-16 set to buf[0..15]
  int base = 0;
  #pragma unroll
  for (int s = 0; s < NS; ++s) {
    bool sel = (k[s] < m) || (e[s] && ((unsigned)v[s] <= m2));
    u64 msk = __ballot(sel);
    if (sel) buf[base + lanerank(msk)] = v[s];
    base += __popcll(msk);
  }
  tau = __uint_as_float(m);
  if (!(tau == tau)) tau = INFINITY;  // cnt<16: sentinel bits are NaN
  return buf[lane & 15];
}

__device__ __forceinline__ u64 select16(u64* buf, int& cnt, int lane,
                                        float& tau) {
  u64 r;
  if (cnt <= 64) r = selimpl<1>(buf, cnt, lane, tau);
  else if (cnt <= 128) r = selimpl<2>(buf, cnt, lane, tau);
  else r = selimpl<3>(buf, cnt, lane, tau);  // cnt<=192 guaranteed by trigger
  cnt = KNN;
  return r;
}

__global__ __launch_bounds__(256) void knng_kernel(
    const float4* __restrict__ pts4, const float4* __restrict__ spts,
    const int* __restrict__ cellStart,
    const ushort_t* __restrict__ ycf, const ushort_t* __restrict__ yimg,
    const ushort_t* __restrict__ cfh, const ushort_t* __restrict__ imfh,
    const float* __restrict__ fwp2, const float* __restrict__ fb,
    float* __restrict__ outT) {
  __shared__ u64 sbuf[4][256];                 // 8 KB
  __shared__ alignas(16) float feat[4][416];   // 6.5 KB
  int t = threadIdx.x;
  int wv = t >> 6, lane = t & 63;
  // XCD-chunked swizzle: each XCD's L2 holds one spatial slab.
  int sblk = (blockIdx.x & 7) * 512 + (blockIdx.x >> 3);
  int sid = sblk * 4 + wv;
  u64* buf = sbuf[wv];

  float4 q = spts[sid];                        // cell-sorted query
  int pid = __float_as_int(q.w);               // original point index
  float qw = fmaf(q.z, q.z, fmaf(q.y, q.y, q.x * q.x));
  float q2x = -2.f * q.x, q2y = -2.f * q.y, q2z = -2.f * q.z;
  int cx = cellof(q.x), cy = cellof(q.y), cz = cellof(q.z);
  float tau = INFINITY;
  u64 vres;

  for (int r = 1;; ++r) {
    int lx = max(cx - r, 0), hx = min(cx + r, G - 1);
    int ly = max(cy - r, 0), hy = min(cy + r, G - 1);
    int lz = max(cz - r, 0), hz = min(cz + r, G - 1);
    int ny = hy - ly + 1, nz = hz - lz + 1, nruns = ny * nz;
    int cnt = 0;
    float ta = tadj(tau, qw);

    for (int rb = 0; rb < nruns; rb += 64) {
      int ln = rb + lane;
      int rs = 0, rc = 0;
      if (ln < nruns) {
        int z = lz + ln / ny, y = ly + ln % ny;
        int row = (z * G + y) * G;
        rs = cellStart[row + lx];
        rc = cellStart[row + hx + 1] - rs;
      }
      int nr = nruns - rb; nr = nr > 64 ? 64 : nr;
      int off = rc;
      #pragma unroll
      for (int d = 1; d < 64; d <<= 1) {
        int v = __shfl_up(off, d);
        if (lane >= d) off += v;
      }
      int T = __shfl(off, 63);
      off -= rc;

      for (int cb = 0; cb < T; cb += 64) {
        int rk = cb + lane;
        int j = 0;
        if (nr <= 16) {
          #pragma unroll
          for (int step = 8; step; step >>= 1) {
            int nj = j + step;
            if (__shfl(off, nj) <= rk) j = nj;
          }
        } else if (nr <= 32) {
          #pragma unroll
          for (int step = 16; step; step >>= 1) {
            int nj = j + step;
            if (__shfl(off, nj) <= rk) j = nj;
          }
        } else {
          #pragma unroll
          for (int step = 32; step; step >>= 1) {
            int nj = j + step;
            if (__shfl(off, nj) <= rk) j = nj;
          }
        }
        int src = __shfl(rs, j) + rk - __shfl(off, j);
        bool valid = rk < T;
        if (!valid) src = 0;
        float4 c = spts[src];
        float cw = fmaf(c.z, c.z, fmaf(c.y, c.y, c.x * c.x));
        float d2 = fmaf(q2x, c.x, fmaf(q2y, c.y, fmaf(q2z, c.z, cw)));
        bool pass = valid && (d2 <= ta);
        u64 mask = __ballot(pass);
        if (mask) {
          if (pass) {
            int oid = __float_as_int(c.w);
            u64 key = ((u64)__float_as_uint(fmaxf(d2 + qw, 0.f)) << 32) | (unsigned)oid;
            buf[cnt + lanerank(mask)] = key;
          }
          cnt += __popcll(mask);
          if (cnt > 192) {  // keep room for one more 64-append
            selimpl<4>(buf, cnt, lane, tau);
            cnt = KNN;
            ta = tadj(tau, qw);
          }
        }
      }
    }
    u64 v = select16(buf, cnt, lane, tau);
    float cl = INFINITY;
    if (lx > 0)     cl = fminf(cl, q.x - (float)lx / (float)G);
    if (hx < G - 1) cl = fminf(cl, (float)(hx + 1) / (float)G - q.x);
    if (ly > 0)     cl = fminf(cl, q.y - (float)ly / (float)G);
    if (hy < G - 1) cl = fminf(cl, (float)(hy + 1) / (float)G - q.y);
    if (lz > 0)     cl = fminf(cl, q.z - (float)lz / (float)G);
    if (hz < G - 1) cl = fminf(cl, (float)(hz + 1) / (float)G - q.z);
    bool full = (lx == 0 && hx == G - 1 && ly == 0 && hy == G - 1 &&
                 lz == 0 && hz == G - 1);
    if (full || tau * 1.00002f <= cl * cl) { vres = v; break; }
  }

  // ---- softmax weights (lanes 0-15 hold exact top-16, unordered) ----
  int myid = (lane < KNN) ? (int)(unsigned)(vres & 0xffffffffULL) : 0;
  float mywg = 0.f;
  {
    float4 c = pts4[myid];
    float dx = q.x - c.x, dy = q.y - c.y, dz = q.z - c.z;
    float dist = sqrtf(fmaxf(dx * dx + dy * dy + dz * dz, 1e-12f));
    float md = (lane < KNN) ? dist : INFINITY;
    #pragma unroll
    for (int off = 1; off < KNN; off <<= 1) md = fminf(md, __shfl_xor(md, off));
    float e = __expf(md - dist);
    float se = (lane < KNN) ? e : 0.f;
    #pragma unroll
    for (int off = 1; off < KNN; off <<= 1) se += __shfl_xor(se, off);
    mywg = e / se;  // valid on lanes < 16
  }

  // ---- gather-max over ycf / yimg rows ----
  int ksub = lane >> 4, c8 = lane & 15;
  float vimf = (lane < 32) ? bf2f(imfh[(size_t)pid * 32 + lane]) : 0.f;
  unsigned vcf = *(const unsigned*)&cfh[(size_t)pid * 128 + lane * 2];

  float a0[8], a1[8];
  #pragma unroll
  for (int j = 0; j < 8; ++j) { a0[j] = -INFINITY; a1[j] = -INFINITY; }
  #pragma unroll
  for (int kk = 0; kk < 4; ++kk) {
    int k = kk * 4 + ksub;
    int id = __shfl(myid, k);
    float wg = __shfl(mywg, k);
    uint4 v = *(const uint4*)&ycf[(size_t)id * 128 + c8 * 8];
    uint4 u = *(const uint4*)&yimg[(size_t)id * 128 + c8 * 8];
    unsigned vv[4] = {v.x, v.y, v.z, v.w};
    unsigned uu[4] = {u.x, u.y, u.z, u.w};
    #pragma unroll
    for (int h = 0; h < 4; ++h) {
      a0[h * 2]     = fmaxf(a0[h * 2],     bflo(vv[h]) * wg);
      a0[h * 2 + 1] = fmaxf(a0[h * 2 + 1], bfhi(vv[h]) * wg);
      a1[h * 2]     = fmaxf(a1[h * 2],     bflo(uu[h]) * wg);
      a1[h * 2 + 1] = fmaxf(a1[h * 2 + 1], bfhi(uu[h]) * wg);
    }
  }
  #pragma unroll
  for (int j = 0; j < 8; ++j) {
    a0[j] = fmaxf(a0[j], __shfl_xor(a0[j], 16));
    a0[j] = fmaxf(a0[j], __shfl_xor(a0[j], 32));
    a1[j] = fmaxf(a1[j], __shfl_xor(a1[j], 16));
    a1[j] = fmaxf(a1[j], __shfl_xor(a1[j], 32));
  }
  if (lane < 16) {
    #pragma unroll
    for (int j = 0; j < 8; ++j) {
      feat[wv][c8 * 8 + j] = lrelu(a0[j]);        // sfp -> [0,128)
      feat[wv][160 + c8 * 8 + j] = lrelu(a1[j]);  // sf  -> [160,288)
    }
  }
  if (lane < 32) feat[wv][128 + lane] = lrelu(vimf);
  feat[wv][288 + lane * 2] = lrelu(bflo(vcf));
  feat[wv][288 + lane * 2 + 1] = lrelu(bfhi(vcf));
  // same-wave LDS producer/consumer: no barrier needed

  // ---- final GEMV (coalesced fwp2) ----
  int ch = lane & 31, half = lane >> 5;
  float acc = half ? 0.f : fb[ch];
  const float* wr = fwp2 + (half * 52) * 128 + ch * 4;
  const float* fr = &feat[wv][half * 208];
  #pragma unroll 4
  for (int j4 = 0; j4 < 52; ++j4) {
    float4 w4 = *(const float4*)(wr + j4 * 128);
    float4 f4 = *(const float4*)(fr + j4 * 4);
    acc = fmaf(f4.x, w4.x, fmaf(f4.y, w4.y, fmaf(f4.z, w4.z, fmaf(f4.w, w4.w, acc))));
  }
  acc += __shfl_xor(acc, 32);
  if (lane < 32) outT[(size_t)pid * 32 + ch] = acc;  // coalesced 128B row
}

// ---------------------------------------------------------------------------
// tran: [N][32] -> [32][N] transpose (4 MB traffic, LDS-tiled, both sides
// coalesced, conflict-free via 129-stride).
// ---------------------------------------------------------------------------
__global__ __launch_bounds__(256) void tran_kernel(
    const float* __restrict__ outT, float* __restrict__ out) {
  __shared__ float tile[32][129];
  int t = threadIdx.x;
  int pbase = blockIdx.x * 128;
  #pragma unroll
  for (int i = 0; i < 16; ++i) {
    int e = i * 256 + t;
    int p = e >> 5, c = e & 31;
    tile[c][p] = outT[(size_t)(pbase + p) * 32 + c];
  }
  __syncthreads();
  #pragma unroll
  for (int i = 0; i < 16; ++i) {
    int e = i * 256 + t;
    int c = e >> 7, p = e & 127;
    out[(size_t)c * N + pbase + p] = tile[c][p];
  }
}

// ---------------------------------------------------------------------------
extern "C" void kernel_launch(void* const* d_in, const int* in_sizes, int n_in,
                              void* d_out, int out_size, void* d_ws, size_t ws_size,
                              hipStream_t stream) {
  const float* img   = (const float*)d_in[0];
  const float* cloud = (const float*)d_in[1];
  const float* c1w   = (const float*)d_in[2];
  const float* c1b   = (const float*)d_in[3];
  const float* c2w   = (const float*)d_in[4];
  const float* c2b   = (const float*)d_in[5];
  const float* ps1w  = (const float*)d_in[6];
  const float* ps1b  = (const float*)d_in[7];
  const float* ps2w  = (const float*)d_in[8];
  const float* ps2b  = (const float*)d_in[9];
  const float* p1w   = (const float*)d_in[10];
  const float* p1b   = (const float*)d_in[11];
  const float* p2w   = (const float*)d_in[12];
  const float* p2b   = (const float*)d_in[13];
  const float* fw    = (const float*)d_in[14];
  const float* fb    = (const float*)d_in[15];
  float* out = (float*)d_out;

  char* ws = (char*)d_ws;
  float4*   pts4  = (float4*)(ws + 0);             // 256 KB
  ushort_t* cfh   = (ushort_t*)(ws + 262144);      // 4 MB
  ushort_t* imfh  = (ushort_t*)(ws + 4456448);     // 1 MB
  ushort_t* w1h   = (ushort_t*)(ws + 7602176);     // 64 KB
  ushort_t* w2h   = (ushort_t*)(ws + 7667712);     // 64 KB
  ushort_t* c1h   = (ushort_t*)(ws + 7733248);     // 4 KB
  ushort_t* c2h   = (ushort_t*)(ws + 7737344);     // 16 KB
  ushort_t* ycf   = (ushort_t*)(ws + 7753472);     // 4 MB
  ushort_t* yimg  = (ushort_t*)(ws + 11947776);    // 4 MB
  float4*   spts  = (float4*)(ws + 16142080);      // 256 KB
  int*      cellStart = (int*)(ws + 16404224);     // 32 KB (2745 used)
  int*      cellofs   = (int*)(ws + 16436992);     // 16 KB
  int*      count     = (int*)(ws + 16453376);     // 16 KB
  float*    fwp2      = (float*)(ws + 16469760);   // 53 KB
  float*    outT      = (float*)(ws + 16523008);   // 2 MB

  hipMemsetAsync(count, 0, NCELL * sizeof(int), stream);
  prepw_kernel<<<604, 256, 0, stream>>>(img, cloud, p1w, p1b, p2w, p2b,
                                        ps1w, ps2w, c1w, c2w, fw,
                                        pts4, cfh, imfh, w1h, w2h, c1h, c2h,
                                        fwp2, count);
  scan_kernel<<<1, 256, 0, stream>>>(count, cellStart, cellofs);
  scatter_kernel<<<64, 256, 0, stream>>>(pts4, cellofs, spts);
  ymlp_kernel<<<512, 256, 0, stream>>>(cfh, imfh, w1h, ps1b, w2h, ps2b,
                                       c1h, c1b, c2h, c2b, ycf, yimg);
  knng_kernel<<<N / 4, 256, 0, stream>>>(pts4, spts, cellStart,
                                         ycf, yimg, cfh, imfh,
                                         fwp2, fb, outT);
  tran_kernel<<<N / 128, 256, 0, stream>>>(outT, out);
}

// Round 6
// 179.198 us; speedup vs baseline: 1.0028x; 1.0028x over previous
//
#include <hip/hip_runtime.h>
#include <math.h>

#define N 16384
#define KNN 16
#define G 14
#define NCELL (G * G * G)  // 2744

typedef __attribute__((ext_vector_type(8))) short bf16x8;
typedef __attribute__((ext_vector_type(4))) float f32x4;
typedef unsigned short ushort_t;
typedef unsigned long long u64;

__device__ __forceinline__ float lrelu(float a) { return a > 0.f ? a : 0.01f * a; }

__device__ __forceinline__ ushort_t f2bf(float f) {
  unsigned u = __float_as_uint(f);
  u += 0x7FFF + ((u >> 16) & 1);
  return (ushort_t)(u >> 16);
}
__device__ __forceinline__ float bf2f(ushort_t h) {
  return __uint_as_float((unsigned)h << 16);
}
__device__ __forceinline__ float bflo(unsigned u) {  // low bf16 of a pair
  return __uint_as_float(u << 16);
}
__device__ __forceinline__ float bfhi(unsigned u) {  // high bf16 of a pair
  return __uint_as_float(u & 0xffff0000u);
}
__device__ __forceinline__ int lanerank(u64 mask) {
  return __builtin_amdgcn_mbcnt_hi((unsigned)(mask >> 32),
         __builtin_amdgcn_mbcnt_lo((unsigned)mask, 0));
}
__device__ __forceinline__ int cellof(float x) {
  int c = (int)(x * (float)G);
  return c < 0 ? 0 : (c > G - 1 ? G - 1 : c);
}
__device__ __forceinline__ int cellid(float x, float y, float z) {
  return (cellof(z) * G + cellof(y)) * G + cellof(x);
}

// ---------------------------------------------------------------------------
// prepw: prep (blocks 0..255, + cell histogram) + weight conv (256..603).
// fwp2 layout: element (j,ch) at (j>>2)*128 + ch*4 + (j&3), j<416.
// ---------------------------------------------------------------------------
#define PPB 64
__global__ __launch_bounds__(256) void prepw_kernel(
    const float* __restrict__ img, const float* __restrict__ cloud,
    const float* __restrict__ p1w, const float* __restrict__ p1b,
    const float* __restrict__ p2w, const float* __restrict__ p2b,
    const float* __restrict__ ps1w, const float* __restrict__ ps2w,
    const float* __restrict__ c1w, const float* __restrict__ c2w,
    const float* __restrict__ fw,
    float4* __restrict__ pts4, ushort_t* __restrict__ cfh,
    ushort_t* __restrict__ imfh,
    ushort_t* __restrict__ w1h, ushort_t* __restrict__ w2h,
    ushort_t* __restrict__ c1h, ushort_t* __restrict__ c2h,
    float* __restrict__ fwp2, int* __restrict__ count) {
  int t = threadIdx.x;
  if (blockIdx.x >= 256) {
    int e = (blockIdx.x - 256) * 256 + t;
    if (e < 32768) w1h[e] = f2bf(ps1w[e]);
    else if (e < 65536) w2h[e - 32768] = f2bf(ps2w[e - 32768]);
    else if (e < 67584) c1h[e - 65536] = f2bf(c1w[e - 65536]);
    else if (e < 75776) c2h[e - 67584] = f2bf(c2w[e - 67584]);
    else if (e < 89088) {
      int e2 = e - 75776;
      int j4 = e2 >> 7, r2 = e2 & 127;
      int ch = r2 >> 2, sub = r2 & 3;
      fwp2[e2] = fw[ch * 416 + j4 * 4 + sub];
    }
    return;
  }
  __shared__ alignas(16) float w2t[64 * 132];
  __shared__ alignas(16) float hs[PPB * 68];
  __shared__ alignas(16) float w1s[192];
  __shared__ alignas(16) float b1s[64];
  __shared__ alignas(16) float b2s[128];
  __shared__ float ptmp[PPB * 3];
  __shared__ float psx[PPB], psy[PPB], psz[PPB];
  int pb = blockIdx.x * PPB;

  for (int e = t; e < 128 * 64; e += 256) {
    int ch = e >> 6, k = e & 63;
    w2t[k * 132 + ch] = p2w[e];
  }
  if (t < 192) w1s[t] = p1w[t];
  if (t < 64) b1s[t] = p1b[t];
  if (t < 128) b2s[t] = p2b[t];
  if (t < PPB * 3) ptmp[t] = cloud[pb * 3 + t];
  __syncthreads();
  if (t < PPB) {
    float x = ptmp[t * 3], y = ptmp[t * 3 + 1], z = ptmp[t * 3 + 2];
    psx[t] = x; psy[t] = y; psz[t] = z;
    pts4[pb + t] = make_float4(x, y, z, x * x + y * y + z * z);
    atomicAdd(&count[cellid(x, y, z)], 1);
  }
  for (int e = t; e < 32 * PPB; e += 256) {
    int c = e >> 6, p = e & 63;
    imfh[(size_t)(pb + p) * 32 + c] = f2bf(img[(size_t)c * N + pb + p]);
  }
  __syncthreads();
  for (int e = t; e < PPB * 64; e += 256) {
    int pt_ = e >> 6, ch = e & 63;
    float a = b1s[ch] + psx[pt_] * w1s[ch * 3] + psy[pt_] * w1s[ch * 3 + 1] +
              psz[pt_] * w1s[ch * 3 + 2];
    hs[pt_ * 68 + ch] = lrelu(a);
  }
  __syncthreads();
  for (int e = t; e < PPB * 32; e += 256) {
    int pt_ = e >> 5, c4 = (e & 31) << 2;
    float4 acc = *(const float4*)&b2s[c4];
    const float* hrow = &hs[pt_ * 68];
    #pragma unroll
    for (int k = 0; k < 64; k += 4) {
      float4 h4 = *(const float4*)&hrow[k];
      float4 w0 = *(const float4*)&w2t[(k + 0) * 132 + c4];
      float4 w1_ = *(const float4*)&w2t[(k + 1) * 132 + c4];
      float4 w2_ = *(const float4*)&w2t[(k + 2) * 132 + c4];
      float4 w3 = *(const float4*)&w2t[(k + 3) * 132 + c4];
      acc.x = fmaf(h4.x, w0.x, fmaf(h4.y, w1_.x, fmaf(h4.z, w2_.x, fmaf(h4.w, w3.x, acc.x))));
      acc.y = fmaf(h4.x, w0.y, fmaf(h4.y, w1_.y, fmaf(h4.z, w2_.y, fmaf(h4.w, w3.y, acc.y))));
      acc.z = fmaf(h4.x, w0.z, fmaf(h4.y, w1_.z, fmaf(h4.z, w2_.z, fmaf(h4.w, w3.z, acc.z))));
      acc.w = fmaf(h4.x, w0.w, fmaf(h4.y, w1_.w, fmaf(h4.z, w2_.w, fmaf(h4.w, w3.w, acc.w))));
    }
    unsigned lo = (unsigned)f2bf(acc.x) | ((unsigned)f2bf(acc.y) << 16);
    unsigned hi = (unsigned)f2bf(acc.z) | ((unsigned)f2bf(acc.w) << 16);
    *(uint2*)&cfh[(size_t)(pb + pt_) * 128 + c4] = make_uint2(lo, hi);
  }
}

// ---------------------------------------------------------------------------
// scan: exclusive prefix over NCELL cell counts (1 block, 11 cells/thread).
// ---------------------------------------------------------------------------
__global__ __launch_bounds__(256) void scan_kernel(
    const int* __restrict__ count, int* __restrict__ cellStart,
    int* __restrict__ cellofs) {
  __shared__ int part[256];
  int t = threadIdx.x;
  int local[11];
  int s = 0;
  #pragma unroll
  for (int j = 0; j < 11; ++j) {
    int idx = t * 11 + j;
    local[j] = s;
    s += (idx < NCELL) ? count[idx] : 0;
  }
  part[t] = s;
  __syncthreads();
  for (int off = 1; off < 256; off <<= 1) {
    int v = (t >= off) ? part[t - off] : 0;
    __syncthreads();
    part[t] += v;
    __syncthreads();
  }
  int base = part[t] - s;
  #pragma unroll
  for (int j = 0; j < 11; ++j) {
    int idx = t * 11 + j;
    int v = base + local[j];
    if (idx < NCELL) { cellStart[idx] = v; cellofs[idx] = v; }
  }
  if (t == 255) cellStart[NCELL] = part[255];
}

// ---------------------------------------------------------------------------
// scatter: points into cell-sorted order; original index packed into .w.
// ---------------------------------------------------------------------------
__global__ __launch_bounds__(256) void scatter_kernel(
    const float4* __restrict__ pts4, int* __restrict__ cellofs,
    float4* __restrict__ spts) {
  int p = blockIdx.x * 256 + threadIdx.x;
  float4 v = pts4[p];
  int pos = atomicAdd(&cellofs[cellid(v.x, v.y, v.z)], 1);
  spts[pos] = make_float4(v.x, v.y, v.z, __int_as_float(p));
}

// ---------------------------------------------------------------------------
// ymlp: deduplicated dense MLPs (unchanged).
// ---------------------------------------------------------------------------
#define NB_LD 136
#define S1_LD 264
#define NI_LD 40
#define H1_LD 72
__global__ __launch_bounds__(256) void ymlp_kernel(
    const ushort_t* __restrict__ cfh, const ushort_t* __restrict__ imfh,
    const ushort_t* __restrict__ w1h, const float* __restrict__ b1,
    const ushort_t* __restrict__ w2h, const float* __restrict__ b2,
    const ushort_t* __restrict__ c1h, const float* __restrict__ c1b,
    const ushort_t* __restrict__ c2h, const float* __restrict__ c2b,
    ushort_t* __restrict__ ycf, ushort_t* __restrict__ yimg) {
  __shared__ ushort_t nb[64 * NB_LD];
  __shared__ ushort_t s1[64 * S1_LD];
  int t = threadIdx.x;
  int w = t >> 6, lane = t & 63;
  int col = lane & 15, quad = lane >> 4;

  if (blockIdx.x < 256) {
    int pbase = blockIdx.x * 64;
    for (int e = t; e < 1024; e += 256) {
      int row = e >> 4, c8 = (e & 15) << 3;
      *(uint4*)&nb[row * NB_LD + c8] =
          *(const uint4*)&cfh[(size_t)(pbase + row) * 128 + c8];
    }
    __syncthreads();
    f32x4 acc1[4][4];
    #pragma unroll
    for (int tt = 0; tt < 4; ++tt)
      #pragma unroll
      for (int p = 0; p < 4; ++p) acc1[tt][p] = (f32x4){0.f, 0.f, 0.f, 0.f};
    for (int k0 = 0; k0 < 128; k0 += 32) {
      bf16x8 a[4];
      #pragma unroll
      for (int p = 0; p < 4; ++p)
        a[p] = *(const bf16x8*)&nb[(p * 16 + col) * NB_LD + k0 + quad * 8];
      #pragma unroll
      for (int tt = 0; tt < 4; ++tt) {
        int n = w * 64 + tt * 16 + col;
        bf16x8 b = *(const bf16x8*)&w1h[n * 128 + k0 + quad * 8];
        #pragma unroll
        for (int p = 0; p < 4; ++p)
          acc1[tt][p] = __builtin_amdgcn_mfma_f32_16x16x32_bf16(a[p], b, acc1[tt][p], 0, 0, 0);
      }
    }
    #pragma unroll
    for (int tt = 0; tt < 4; ++tt) {
      int n = w * 64 + tt * 16 + col;
      float bb = b1[n];
      #pragma unroll
      for (int p = 0; p < 4; ++p)
        #pragma unroll
        for (int r = 0; r < 4; ++r)
          s1[(p * 16 + quad * 4 + r) * S1_LD + n] = f2bf(lrelu(acc1[tt][p][r] + bb));
    }
    __syncthreads();
    f32x4 acc2[2][4];
    #pragma unroll
    for (int tt = 0; tt < 2; ++tt)
      #pragma unroll
      for (int p = 0; p < 4; ++p) acc2[tt][p] = (f32x4){0.f, 0.f, 0.f, 0.f};
    for (int k0 = 0; k0 < 256; k0 += 32) {
      bf16x8 a[4];
      #pragma unroll
      for (int p = 0; p < 4; ++p)
        a[p] = *(const bf16x8*)&s1[(p * 16 + col) * S1_LD + k0 + quad * 8];
      #pragma unroll
      for (int tt = 0; tt < 2; ++tt) {
        int n = w * 32 + tt * 16 + col;
        bf16x8 b = *(const bf16x8*)&w2h[n * 256 + k0 + quad * 8];
        #pragma unroll
        for (int p = 0; p < 4; ++p)
          acc2[tt][p] = __builtin_amdgcn_mfma_f32_16x16x32_bf16(a[p], b, acc2[tt][p], 0, 0, 0);
      }
    }
    #pragma unroll
    for (int tt = 0; tt < 2; ++tt) {
      int n = w * 32 + tt * 16 + col;
      float bb = b2[n];
      #pragma unroll
      for (int p = 0; p < 4; ++p)
        #pragma unroll
        for (int r = 0; r < 4; ++r)
          ycf[(size_t)(pbase + p * 16 + quad * 4 + r) * 128 + n] =
              f2bf(acc2[tt][p][r] + bb);
    }
  } else {
    int pbase = (blockIdx.x - 256) * 64;
    ushort_t* nbi = nb;
    ushort_t* h1 = s1;
    {
      int row = t >> 2, c8 = (t & 3) << 3;
      *(uint4*)&nbi[row * NI_LD + c8] =
          *(const uint4*)&imfh[(size_t)(pbase + row) * 32 + c8];
    }
    __syncthreads();
    {
      f32x4 accA[4];
      #pragma unroll
      for (int p = 0; p < 4; ++p) accA[p] = (f32x4){0.f, 0.f, 0.f, 0.f};
      int n = w * 16 + col;
      bf16x8 b = *(const bf16x8*)&c1h[n * 32 + quad * 8];
      #pragma unroll
      for (int p = 0; p < 4; ++p) {
        bf16x8 a = *(const bf16x8*)&nbi[(p * 16 + col) * NI_LD + quad * 8];
        accA[p] = __builtin_amdgcn_mfma_f32_16x16x32_bf16(a, b, accA[p], 0, 0, 0);
      }
      __syncthreads();
      float bb = c1b[n];
      #pragma unroll
      for (int p = 0; p < 4; ++p)
        #pragma unroll
        for (int r = 0; r < 4; ++r)
          h1[(p * 16 + quad * 4 + r) * H1_LD + n] = f2bf(lrelu(accA[p][r] + bb));
    }
    __syncthreads();
    f32x4 acc2[2][4];
    #pragma unroll
    for (int tt = 0; tt < 2; ++tt)
      #pragma unroll
      for (int p = 0; p < 4; ++p) acc2[tt][p] = (f32x4){0.f, 0.f, 0.f, 0.f};
    for (int k0 = 0; k0 < 64; k0 += 32) {
      bf16x8 a[4];
      #pragma unroll
      for (int p = 0; p < 4; ++p)
        a[p] = *(const bf16x8*)&h1[(p * 16 + col) * H1_LD + k0 + quad * 8];
      #pragma unroll
      for (int tt = 0; tt < 2; ++tt) {
        int n = w * 32 + tt * 16 + col;
        bf16x8 b = *(const bf16x8*)&c2h[n * 64 + k0 + quad * 8];
        #pragma unroll
        for (int p = 0; p < 4; ++p)
          acc2[tt][p] = __builtin_amdgcn_mfma_f32_16x16x32_bf16(a[p], b, acc2[tt][p], 0, 0, 0);
      }
    }
    #pragma unroll
    for (int tt = 0; tt < 2; ++tt) {
      int n = w * 32 + tt * 16 + col;
      float bb = c2b[n];
      #pragma unroll
      for (int p = 0; p < 4; ++p)
        #pragma unroll
        for (int r = 0; r < 4; ++r)
          yimg[(size_t)(pbase + p * 16 + quad * 4 + r) * 128 + n] =
              f2bf(acc2[tt][p][r] + bb);
    }
  }
}

// ---------------------------------------------------------------------------
// knng: grid KNN (exact top-16) fused with gather-max + feat + final GEMV.
// A-priori pruning radius: tau starts at r_est^2 (boundary-clip-corrected
// radius holding ~35 expected points) instead of INF -> ring-1 inserts drop
// 161 -> ~35, mid-scan select never fires, final select runs at NS=1.
// Exact: if >=16 pass, pruned points all exceed the kept 16th (top-16 kept);
// if <16 pass (~1e-3, boundary tail), select's NaN sentinel sets tau=INF and
// the ring loop rescans unpruned -- self-healing through existing control.
// Select = 1-bit ballot radix (R5's 2-bit tripled ballot volume: reverted).
// ---------------------------------------------------------------------------
__device__ __forceinline__ float tadj(float tau, float qw) {
  float a = tau - qw;
  return a + fabsf(a) * 2e-7f + 1e-35f;
}

template <int NS>
__device__ __forceinline__ u64 selimpl(u64* buf, int cnt, int lane,
                                       float& tau) {
  u64 v[NS];
  unsigned k[NS];
  #pragma unroll
  for (int s = 0; s < NS; ++s) {
    int idx = s * 64 + lane;
    v[s] = (idx < cnt) ? buf[idx] : ~0ULL;
    k[s] = (unsigned)(v[s] >> 32);
  }
  // phase 1: m = 16th smallest d2-bits (sentinel 0xFFFFFFFF sorts last)
  unsigned m = 0u;
  #pragma unroll
  for (int b = 31; b >= 0; --b) {
    unsigned probe = m | (1u << b);
    int c = 0;
    #pragma unroll
    for (int s = 0; s < NS; ++s) c += __popcll(__ballot(k[s] < probe));
    if (c < KNN) m = probe;
  }
  // phase 2: tie-break on oid among keys equal to m (rare).
  int c_lt = 0, ne = 0;
  bool e[NS];
  #pragma unroll
  for (int s = 0; s < NS; ++s) {
    c_lt += __popcll(__ballot(k[s] < m));
    e[s] = (k[s] == m);
    ne += __popcll(__ballot(e[s]));
  }
  int need_eq = KNN - c_lt;
  unsigned m2 = 0xFFFFFFFFu;
  if (ne != need_eq) {
    m2 = 0u;
    #pragma unroll
    for (int b = 13; b >= 0; --b) {
      unsigned probe = m2 | (1u << b);
      int c = 0;
      #pragma unroll
      for (int s = 0; s < NS; ++s)
        c += __popcll(__ballot(e[s] && ((unsigned)v[s] < probe)));
      if (c < need_eq) m2 = probe;
    }
  }
  // compact the exact top-16 set to buf[0..15]
  int base = 0;
  #pragma unroll
  for (int s = 0; s < NS; ++s) {
    bool sel = (k[s] < m) || (e[s] && ((unsigned)v[s] <= m2));
    u64 msk = __ballot(sel);
    if (sel) buf[base + lanerank(msk)] = v[s];
    base += __popcll(msk);
  }
  tau = __uint_as_float(m);
  if (!(tau == tau)) tau = INFINITY;  // cnt<16: sentinel bits are NaN
  return buf[lane & 15];
}

__device__ __forceinline__ u64 select16(u64* buf, int& cnt, int lane,
                                        float& tau) {
  u64 r = (cnt <= 64) ? selimpl<1>(buf, cnt, lane, tau)
                      : selimpl<2>(buf, cnt, lane, tau);
  cnt = KNN;
  return r;
}

__global__ __launch_bounds__(256) void knng_kernel(
    const float4* __restrict__ pts4, const float4* __restrict__ spts,
    const int* __restrict__ cellStart,
    const ushort_t* __restrict__ ycf, const ushort_t* __restrict__ yimg,
    const ushort_t* __restrict__ cfh, const ushort_t* __restrict__ imfh,
    const float* __restrict__ fwp2, const float* __restrict__ fb,
    float* __restrict__ outT) {
  __shared__ u64 sbuf[4][128];                 // 4 KB
  __shared__ alignas(16) float feat[4][416];   // 6.5 KB
  int t = threadIdx.x;
  int wv = t >> 6, lane = t & 63;
  // XCD-chunked swizzle: each XCD's L2 holds one spatial slab.
  int sblk = (blockIdx.x & 7) * 512 + (blockIdx.x >> 3);
  int sid = sblk * 4 + wv;
  u64* buf = sbuf[wv];

  float4 q = spts[sid];                        // cell-sorted query
  int pid = __float_as_int(q.w);               // original point index
  float qw = fmaf(q.z, q.z, fmaf(q.y, q.y, q.x * q.x));
  float q2x = -2.f * q.x, q2y = -2.f * q.y, q2z = -2.f * q.z;
  int cx = cellof(q.x), cy = cellof(q.y), cz = cellof(q.z);

  // a-priori pruning radius: ~35 expected points in the clipped ball.
  float tau;
  {
    const float r0 = 0.0758f;  // (35*3/(4*pi*N))^(1/3) w/o clip
    float rr = r0;
    #pragma unroll
    for (int it = 0; it < 2; ++it) {
      float fx = (fminf(q.x + rr, 1.f) - fmaxf(q.x - rr, 0.f)) * (0.5f / rr);
      float fy = (fminf(q.y + rr, 1.f) - fmaxf(q.y - rr, 0.f)) * (0.5f / rr);
      float fz = (fminf(q.z + rr, 1.f) - fmaxf(q.z - rr, 0.f)) * (0.5f / rr);
      rr = r0 * __powf(fx * fy * fz, -0.333333f);
    }
    rr *= 1.05f;
    tau = rr * rr;
  }
  u64 vres;

  for (int r = 1;; ++r) {
    int lx = max(cx - r, 0), hx = min(cx + r, G - 1);
    int ly = max(cy - r, 0), hy = min(cy + r, G - 1);
    int lz = max(cz - r, 0), hz = min(cz + r, G - 1);
    int ny = hy - ly + 1, nz = hz - lz + 1, nruns = ny * nz;
    int cnt = 0;
    float ta = tadj(tau, qw);

    for (int rb = 0; rb < nruns; rb += 64) {
      int ln = rb + lane;
      int rs = 0, rc = 0;
      if (ln < nruns) {
        int z = lz + ln / ny, y = ly + ln % ny;
        int row = (z * G + y) * G;
        rs = cellStart[row + lx];
        rc = cellStart[row + hx + 1] - rs;
      }
      int nr = nruns - rb; nr = nr > 64 ? 64 : nr;
      int off = rc;
      #pragma unroll
      for (int d = 1; d < 64; d <<= 1) {
        int v = __shfl_up(off, d);
        if (lane >= d) off += v;
      }
      int T = __shfl(off, 63);
      off -= rc;

      for (int cb = 0; cb < T; cb += 64) {
        int rk = cb + lane;
        int j = 0;
        if (nr <= 16) {
          #pragma unroll
          for (int step = 8; step; step >>= 1) {
            int nj = j + step;
            if (__shfl(off, nj) <= rk) j = nj;
          }
        } else if (nr <= 32) {
          #pragma unroll
          for (int step = 16; step; step >>= 1) {
            int nj = j + step;
            if (__shfl(off, nj) <= rk) j = nj;
          }
        } else {
          #pragma unroll
          for (int step = 32; step; step >>= 1) {
            int nj = j + step;
            if (__shfl(off, nj) <= rk) j = nj;
          }
        }
        int src = __shfl(rs, j) + rk - __shfl(off, j);
        bool valid = rk < T;
        if (!valid) src = 0;
        float4 c = spts[src];
        float cw = fmaf(c.z, c.z, fmaf(c.y, c.y, c.x * c.x));
        float d2 = fmaf(q2x, c.x, fmaf(q2y, c.y, fmaf(q2z, c.z, cw)));
        bool pass = valid && (d2 <= ta);
        u64 mask = __ballot(pass);
        if (mask) {
          if (pass) {
            int oid = __float_as_int(c.w);
            u64 key = ((u64)__float_as_uint(fmaxf(d2 + qw, 0.f)) << 32) | (unsigned)oid;
            buf[cnt + lanerank(mask)] = key;
          }
          cnt += __popcll(mask);
          if (cnt > 64) {  // keep room for one more 64-append (buffer 128)
            select16(buf, cnt, lane, tau);
            ta = tadj(tau, qw);
          }
        }
      }
    }
    u64 v = select16(buf, cnt, lane, tau);
    float cl = INFINITY;
    if (lx > 0)     cl = fminf(cl, q.x - (float)lx / (float)G);
    if (hx < G - 1) cl = fminf(cl, (float)(hx + 1) / (float)G - q.x);
    if (ly > 0)     cl = fminf(cl, q.y - (float)ly / (float)G);
    if (hy < G - 1) cl = fminf(cl, (float)(hy + 1) / (float)G - q.y);
    if (lz > 0)     cl = fminf(cl, q.z - (float)lz / (float)G);
    if (hz < G - 1) cl = fminf(cl, (float)(hz + 1) / (float)G - q.z);
    bool full = (lx == 0 && hx == G - 1 && ly == 0 && hy == G - 1 &&
                 lz == 0 && hz == G - 1);
    if (full || tau * 1.00002f <= cl * cl) { vres = v; break; }
  }

  // ---- softmax weights (lanes 0-15 hold exact top-16, unordered) ----
  int myid = (lane < KNN) ? (int)(unsigned)(vres & 0xffffffffULL) : 0;
  float mywg = 0.f;
  {
    float4 c = pts4[myid];
    float dx = q.x - c.x, dy = q.y - c.y, dz = q.z - c.z;
    float dist = sqrtf(fmaxf(dx * dx + dy * dy + dz * dz, 1e-12f));
    float md = (lane < KNN) ? dist : INFINITY;
    #pragma unroll
    for (int off = 1; off < KNN; off <<= 1) md = fminf(md, __shfl_xor(md, off));
    float e = __expf(md - dist);
    float se = (lane < KNN) ? e : 0.f;
    #pragma unroll
    for (int off = 1; off < KNN; off <<= 1) se += __shfl_xor(se, off);
    mywg = e / se;  // valid on lanes < 16
  }

  // ---- gather-max over ycf / yimg rows ----
  int ksub = lane >> 4, c8 = lane & 15;
  float vimf = (lane < 32) ? bf2f(imfh[(size_t)pid * 32 + lane]) : 0.f;
  unsigned vcf = *(const unsigned*)&cfh[(size_t)pid * 128 + lane * 2];

  float a0[8], a1[8];
  #pragma unroll
  for (int j = 0; j < 8; ++j) { a0[j] = -INFINITY; a1[j] = -INFINITY; }
  #pragma unroll
  for (int kk = 0; kk < 4; ++kk) {
    int k = kk * 4 + ksub;
    int id = __shfl(myid, k);
    float wg = __shfl(mywg, k);
    uint4 v = *(const uint4*)&ycf[(size_t)id * 128 + c8 * 8];
    uint4 u = *(const uint4*)&yimg[(size_t)id * 128 + c8 * 8];
    unsigned vv[4] = {v.x, v.y, v.z, v.w};
    unsigned uu[4] = {u.x, u.y, u.z, u.w};
    #pragma unroll
    for (int h = 0; h < 4; ++h) {
      a0[h * 2]     = fmaxf(a0[h * 2],     bflo(vv[h]) * wg);
      a0[h * 2 + 1] = fmaxf(a0[h * 2 + 1], bfhi(vv[h]) * wg);
      a1[h * 2]     = fmaxf(a1[h * 2],     bflo(uu[h]) * wg);
      a1[h * 2 + 1] = fmaxf(a1[h * 2 + 1], bfhi(uu[h]) * wg);
    }
  }
  #pragma unroll
  for (int j = 0; j < 8; ++j) {
    a0[j] = fmaxf(a0[j], __shfl_xor(a0[j], 16));
    a0[j] = fmaxf(a0[j], __shfl_xor(a0[j], 32));
    a1[j] = fmaxf(a1[j], __shfl_xor(a1[j], 16));
    a1[j] = fmaxf(a1[j], __shfl_xor(a1[j], 32));
  }
  if (lane < 16) {
    #pragma unroll
    for (int j = 0; j < 8; ++j) {
      feat[wv][c8 * 8 + j] = lrelu(a0[j]);        // sfp -> [0,128)
      feat[wv][160 + c8 * 8 + j] = lrelu(a1[j]);  // sf  -> [160,288)
    }
  }
  if (lane < 32) feat[wv][128 + lane] = lrelu(vimf);
  feat[wv][288 + lane * 2] = lrelu(bflo(vcf));
  feat[wv][288 + lane * 2 + 1] = lrelu(bfhi(vcf));
  // same-wave LDS producer/consumer: no barrier needed

  // ---- final GEMV (coalesced fwp2) ----
  int ch = lane & 31, half = lane >> 5;
  float acc = half ? 0.f : fb[ch];
  const float* wr = fwp2 + (half * 52) * 128 + ch * 4;
  const float* fr = &feat[wv][half * 208];
  #pragma unroll 4
  for (int j4 = 0; j4 < 52; ++j4) {
    float4 w4 = *(const float4*)(wr + j4 * 128);
    float4 f4 = *(const float4*)(fr + j4 * 4);
    acc = fmaf(f4.x, w4.x, fmaf(f4.y, w4.y, fmaf(f4.z, w4.z, fmaf(f4.w, w4.w, acc))));
  }
  acc += __shfl_xor(acc, 32);
  if (lane < 32) outT[(size_t)pid * 32 + ch] = acc;  // coalesced 128B row
}

// ---------------------------------------------------------------------------
// tran: [N][32] -> [32][N] transpose (4 MB traffic, LDS-tiled, both sides
// coalesced, conflict-free via 129-stride).
// ---------------------------------------------------------------------------
__global__ __launch_bounds__(256) void tran_kernel(
    const float* __restrict__ outT, float* __restrict__ out) {
  __shared__ float tile[32][129];
  int t = threadIdx.x;
  int pbase = blockIdx.x * 128;
  #pragma unroll
  for (int i = 0; i < 16; ++i) {
    int e = i * 256 + t;
    int p = e >> 5, c = e & 31;
    tile[c][p] = outT[(size_t)(pbase + p) * 32 + c];
  }
  __syncthreads();
  #pragma unroll
  for (int i = 0; i < 16; ++i) {
    int e = i * 256 + t;
    int c = e >> 7, p = e & 127;
    out[(size_t)c * N + pbase + p] = tile[c][p];
  }
}

// ---------------------------------------------------------------------------
extern "C" void kernel_launch(void* const* d_in, const int* in_sizes, int n_in,
                              void* d_out, int out_size, void* d_ws, size_t ws_size,
                              hipStream_t stream) {
  const float* img   = (const float*)d_in[0];
  const float* cloud = (const float*)d_in[1];
  const float* c1w   = (const float*)d_in[2];
  const float* c1b   = (const float*)d_in[3];
  const float* c2w   = (const float*)d_in[4];
  const float* c2b   = (const float*)d_in[5];
  const float* ps1w  = (const float*)d_in[6];
  const float* ps1b  = (const float*)d_in[7];
  const float* ps2w  = (const float*)d_in[8];
  const float* ps2b  = (const float*)d_in[9];
  const float* p1w   = (const float*)d_in[10];
  const float* p1b   = (const float*)d_in[11];
  const float* p2w   = (const float*)d_in[12];
  const float* p2b   = (const float*)d_in[13];
  const float* fw    = (const float*)d_in[14];
  const float* fb    = (const float*)d_in[15];
  float* out = (float*)d_out;

  char* ws = (char*)d_ws;
  float4*   pts4  = (float4*)(ws + 0);             // 256 KB
  ushort_t* cfh   = (ushort_t*)(ws + 262144);      // 4 MB
  ushort_t* imfh  = (ushort_t*)(ws + 4456448);     // 1 MB
  ushort_t* w1h   = (ushort_t*)(ws + 7602176);     // 64 KB
  ushort_t* w2h   = (ushort_t*)(ws + 7667712);     // 64 KB
  ushort_t* c1h   = (ushort_t*)(ws + 7733248);     // 4 KB
  ushort_t* c2h   = (ushort_t*)(ws + 7737344);     // 16 KB
  ushort_t* ycf   = (ushort_t*)(ws + 7753472);     // 4 MB
  ushort_t* yimg  = (ushort_t*)(ws + 11947776);    // 4 MB
  float4*   spts  = (float4*)(ws + 16142080);      // 256 KB
  int*      cellStart = (int*)(ws + 16404224);     // 32 KB (2745 used)
  int*      cellofs   = (int*)(ws + 16436992);     // 16 KB
  int*      count     = (int*)(ws + 16453376);     // 16 KB
  float*    fwp2      = (float*)(ws + 16469760);   // 53 KB
  float*    outT      = (float*)(ws + 16523008);   // 2 MB

  hipMemsetAsync(count, 0, NCELL * sizeof(int), stream);
  prepw_kernel<<<604, 256, 0, stream>>>(img, cloud, p1w, p1b, p2w, p2b,
                                        ps1w, ps2w, c1w, c2w, fw,
                                        pts4, cfh, imfh, w1h, w2h, c1h, c2h,
                                        fwp2, count);
  scan_kernel<<<1, 256, 0, stream>>>(count, cellStart, cellofs);
  scatter_kernel<<<64, 256, 0, stream>>>(pts4, cellofs, spts);
  ymlp_kernel<<<512, 256, 0, stream>>>(cfh, imfh, w1h, ps1b, w2h, ps2b,
                                       c1h, c1b, c2h, c2b, ycf, yimg);
  knng_kernel<<<N / 4, 256, 0, stream>>>(pts4, spts, cellStart,
                                         ycf, yimg, cfh, imfh,
                                         fwp2, fb, outT);
  tran_kernel<<<N / 128, 256, 0, stream>>>(outT, out);
}

// Round 7
// 171.445 us; speedup vs baseline: 1.0482x; 1.0452x over previous
//
#include <hip/hip_runtime.h>
#include <math.h>

#define N 16384
#define KNN 16
#define G 14
#define NCELL (G * G * G)  // 2744

typedef __attribute__((ext_vector_type(8))) short bf16x8;
typedef __attribute__((ext_vector_type(4))) float f32x4;
typedef unsigned short ushort_t;
typedef unsigned long long u64;

__device__ __forceinline__ float lrelu(float a) { return a > 0.f ? a : 0.01f * a; }

__device__ __forceinline__ ushort_t f2bf(float f) {
  unsigned u = __float_as_uint(f);
  u += 0x7FFF + ((u >> 16) & 1);
  return (ushort_t)(u >> 16);
}
__device__ __forceinline__ float bf2f(ushort_t h) {
  return __uint_as_float((unsigned)h << 16);
}
__device__ __forceinline__ float bflo(unsigned u) {  // low bf16 of a pair
  return __uint_as_float(u << 16);
}
__device__ __forceinline__ float bfhi(unsigned u) {  // high bf16 of a pair
  return __uint_as_float(u & 0xffff0000u);
}
__device__ __forceinline__ int lanerank(u64 mask) {
  return __builtin_amdgcn_mbcnt_hi((unsigned)(mask >> 32),
         __builtin_amdgcn_mbcnt_lo((unsigned)mask, 0));
}
__device__ __forceinline__ int cellof(float x) {
  int c = (int)(x * (float)G);
  return c < 0 ? 0 : (c > G - 1 ? G - 1 : c);
}
__device__ __forceinline__ int cellid(float x, float y, float z) {
  return (cellof(z) * G + cellof(y)) * G + cellof(x);
}

// ---------------------------------------------------------------------------
// prepw: prep (blocks 0..255, + cell histogram) + weight conv (256..603).
// fwh: final weight as bf16 [32][416] row-major (straight convert of fw).
// ---------------------------------------------------------------------------
#define PPB 64
__global__ __launch_bounds__(256) void prepw_kernel(
    const float* __restrict__ img, const float* __restrict__ cloud,
    const float* __restrict__ p1w, const float* __restrict__ p1b,
    const float* __restrict__ p2w, const float* __restrict__ p2b,
    const float* __restrict__ ps1w, const float* __restrict__ ps2w,
    const float* __restrict__ c1w, const float* __restrict__ c2w,
    const float* __restrict__ fw,
    float4* __restrict__ pts4, ushort_t* __restrict__ cfh,
    ushort_t* __restrict__ imfh,
    ushort_t* __restrict__ w1h, ushort_t* __restrict__ w2h,
    ushort_t* __restrict__ c1h, ushort_t* __restrict__ c2h,
    ushort_t* __restrict__ fwh, int* __restrict__ count) {
  int t = threadIdx.x;
  if (blockIdx.x >= 256) {
    int e = (blockIdx.x - 256) * 256 + t;
    if (e < 32768) w1h[e] = f2bf(ps1w[e]);
    else if (e < 65536) w2h[e - 32768] = f2bf(ps2w[e - 32768]);
    else if (e < 67584) c1h[e - 65536] = f2bf(c1w[e - 65536]);
    else if (e < 75776) c2h[e - 67584] = f2bf(c2w[e - 67584]);
    else if (e < 89088) {
      int e2 = e - 75776;
      if (e2 < 13312) fwh[e2] = f2bf(fw[e2]);
    }
    return;
  }
  __shared__ alignas(16) float w2t[64 * 132];
  __shared__ alignas(16) float hs[PPB * 68];
  __shared__ alignas(16) float w1s[192];
  __shared__ alignas(16) float b1s[64];
  __shared__ alignas(16) float b2s[128];
  __shared__ float ptmp[PPB * 3];
  __shared__ float psx[PPB], psy[PPB], psz[PPB];
  int pb = blockIdx.x * PPB;

  for (int e = t; e < 128 * 64; e += 256) {
    int ch = e >> 6, k = e & 63;
    w2t[k * 132 + ch] = p2w[e];
  }
  if (t < 192) w1s[t] = p1w[t];
  if (t < 64) b1s[t] = p1b[t];
  if (t < 128) b2s[t] = p2b[t];
  if (t < PPB * 3) ptmp[t] = cloud[pb * 3 + t];
  __syncthreads();
  if (t < PPB) {
    float x = ptmp[t * 3], y = ptmp[t * 3 + 1], z = ptmp[t * 3 + 2];
    psx[t] = x; psy[t] = y; psz[t] = z;
    pts4[pb + t] = make_float4(x, y, z, x * x + y * y + z * z);
    atomicAdd(&count[cellid(x, y, z)], 1);
  }
  for (int e = t; e < 32 * PPB; e += 256) {
    int c = e >> 6, p = e & 63;
    imfh[(size_t)(pb + p) * 32 + c] = f2bf(img[(size_t)c * N + pb + p]);
  }
  __syncthreads();
  for (int e = t; e < PPB * 64; e += 256) {
    int pt_ = e >> 6, ch = e & 63;
    float a = b1s[ch] + psx[pt_] * w1s[ch * 3] + psy[pt_] * w1s[ch * 3 + 1] +
              psz[pt_] * w1s[ch * 3 + 2];
    hs[pt_ * 68 + ch] = lrelu(a);
  }
  __syncthreads();
  for (int e = t; e < PPB * 32; e += 256) {
    int pt_ = e >> 5, c4 = (e & 31) << 2;
    float4 acc = *(const float4*)&b2s[c4];
    const float* hrow = &hs[pt_ * 68];
    #pragma unroll
    for (int k = 0; k < 64; k += 4) {
      float4 h4 = *(const float4*)&hrow[k];
      float4 w0 = *(const float4*)&w2t[(k + 0) * 132 + c4];
      float4 w1_ = *(const float4*)&w2t[(k + 1) * 132 + c4];
      float4 w2_ = *(const float4*)&w2t[(k + 2) * 132 + c4];
      float4 w3 = *(const float4*)&w2t[(k + 3) * 132 + c4];
      acc.x = fmaf(h4.x, w0.x, fmaf(h4.y, w1_.x, fmaf(h4.z, w2_.x, fmaf(h4.w, w3.x, acc.x))));
      acc.y = fmaf(h4.x, w0.y, fmaf(h4.y, w1_.y, fmaf(h4.z, w2_.y, fmaf(h4.w, w3.y, acc.y))));
      acc.z = fmaf(h4.x, w0.z, fmaf(h4.y, w1_.z, fmaf(h4.z, w2_.z, fmaf(h4.w, w3.z, acc.z))));
      acc.w = fmaf(h4.x, w0.w, fmaf(h4.y, w1_.w, fmaf(h4.z, w2_.w, fmaf(h4.w, w3.w, acc.w))));
    }
    unsigned lo = (unsigned)f2bf(acc.x) | ((unsigned)f2bf(acc.y) << 16);
    unsigned hi = (unsigned)f2bf(acc.z) | ((unsigned)f2bf(acc.w) << 16);
    *(uint2*)&cfh[(size_t)(pb + pt_) * 128 + c4] = make_uint2(lo, hi);
  }
}

// ---------------------------------------------------------------------------
// scan: exclusive prefix over NCELL cell counts (1 block, 11 cells/thread).
// ---------------------------------------------------------------------------
__global__ __launch_bounds__(256) void scan_kernel(
    const int* __restrict__ count, int* __restrict__ cellStart,
    int* __restrict__ cellofs) {
  __shared__ int part[256];
  int t = threadIdx.x;
  int local[11];
  int s = 0;
  #pragma unroll
  for (int j = 0; j < 11; ++j) {
    int idx = t * 11 + j;
    local[j] = s;
    s += (idx < NCELL) ? count[idx] : 0;
  }
  part[t] = s;
  __syncthreads();
  for (int off = 1; off < 256; off <<= 1) {
    int v = (t >= off) ? part[t - off] : 0;
    __syncthreads();
    part[t] += v;
    __syncthreads();
  }
  int base = part[t] - s;
  #pragma unroll
  for (int j = 0; j < 11; ++j) {
    int idx = t * 11 + j;
    int v = base + local[j];
    if (idx < NCELL) { cellStart[idx] = v; cellofs[idx] = v; }
  }
  if (t == 255) cellStart[NCELL] = part[255];
}

// ---------------------------------------------------------------------------
// scatter: points into cell-sorted order; original index packed into .w.
// ---------------------------------------------------------------------------
__global__ __launch_bounds__(256) void scatter_kernel(
    const float4* __restrict__ pts4, int* __restrict__ cellofs,
    float4* __restrict__ spts) {
  int p = blockIdx.x * 256 + threadIdx.x;
  float4 v = pts4[p];
  int pos = atomicAdd(&cellofs[cellid(v.x, v.y, v.z)], 1);
  spts[pos] = make_float4(v.x, v.y, v.z, __int_as_float(p));
}

// ---------------------------------------------------------------------------
// ymlp: deduplicated dense MLPs (unchanged).
// ---------------------------------------------------------------------------
#define NB_LD 136
#define S1_LD 264
#define NI_LD 40
#define H1_LD 72
__global__ __launch_bounds__(256) void ymlp_kernel(
    const ushort_t* __restrict__ cfh, const ushort_t* __restrict__ imfh,
    const ushort_t* __restrict__ w1h, const float* __restrict__ b1,
    const ushort_t* __restrict__ w2h, const float* __restrict__ b2,
    const ushort_t* __restrict__ c1h, const float* __restrict__ c1b,
    const ushort_t* __restrict__ c2h, const float* __restrict__ c2b,
    ushort_t* __restrict__ ycf, ushort_t* __restrict__ yimg) {
  __shared__ ushort_t nb[64 * NB_LD];
  __shared__ ushort_t s1[64 * S1_LD];
  int t = threadIdx.x;
  int w = t >> 6, lane = t & 63;
  int col = lane & 15, quad = lane >> 4;

  if (blockIdx.x < 256) {
    int pbase = blockIdx.x * 64;
    for (int e = t; e < 1024; e += 256) {
      int row = e >> 4, c8 = (e & 15) << 3;
      *(uint4*)&nb[row * NB_LD + c8] =
          *(const uint4*)&cfh[(size_t)(pbase + row) * 128 + c8];
    }
    __syncthreads();
    f32x4 acc1[4][4];
    #pragma unroll
    for (int tt = 0; tt < 4; ++tt)
      #pragma unroll
      for (int p = 0; p < 4; ++p) acc1[tt][p] = (f32x4){0.f, 0.f, 0.f, 0.f};
    for (int k0 = 0; k0 < 128; k0 += 32) {
      bf16x8 a[4];
      #pragma unroll
      for (int p = 0; p < 4; ++p)
        a[p] = *(const bf16x8*)&nb[(p * 16 + col) * NB_LD + k0 + quad * 8];
      #pragma unroll
      for (int tt = 0; tt < 4; ++tt) {
        int n = w * 64 + tt * 16 + col;
        bf16x8 b = *(const bf16x8*)&w1h[n * 128 + k0 + quad * 8];
        #pragma unroll
        for (int p = 0; p < 4; ++p)
          acc1[tt][p] = __builtin_amdgcn_mfma_f32_16x16x32_bf16(a[p], b, acc1[tt][p], 0, 0, 0);
      }
    }
    #pragma unroll
    for (int tt = 0; tt < 4; ++tt) {
      int n = w * 64 + tt * 16 + col;
      float bb = b1[n];
      #pragma unroll
      for (int p = 0; p < 4; ++p)
        #pragma unroll
        for (int r = 0; r < 4; ++r)
          s1[(p * 16 + quad * 4 + r) * S1_LD + n] = f2bf(lrelu(acc1[tt][p][r] + bb));
    }
    __syncthreads();
    f32x4 acc2[2][4];
    #pragma unroll
    for (int tt = 0; tt < 2; ++tt)
      #pragma unroll
      for (int p = 0; p < 4; ++p) acc2[tt][p] = (f32x4){0.f, 0.f, 0.f, 0.f};
    for (int k0 = 0; k0 < 256; k0 += 32) {
      bf16x8 a[4];
      #pragma unroll
      for (int p = 0; p < 4; ++p)
        a[p] = *(const bf16x8*)&s1[(p * 16 + col) * S1_LD + k0 + quad * 8];
      #pragma unroll
      for (int tt = 0; tt < 2; ++tt) {
        int n = w * 32 + tt * 16 + col;
        bf16x8 b = *(const bf16x8*)&w2h[n * 256 + k0 + quad * 8];
        #pragma unroll
        for (int p = 0; p < 4; ++p)
          acc2[tt][p] = __builtin_amdgcn_mfma_f32_16x16x32_bf16(a[p], b, acc2[tt][p], 0, 0, 0);
      }
    }
    #pragma unroll
    for (int tt = 0; tt < 2; ++tt) {
      int n = w * 32 + tt * 16 + col;
      float bb = b2[n];
      #pragma unroll
      for (int p = 0; p < 4; ++p)
        #pragma unroll
        for (int r = 0; r < 4; ++r)
          ycf[(size_t)(pbase + p * 16 + quad * 4 + r) * 128 + n] =
              f2bf(acc2[tt][p][r] + bb);
    }
  } else {
    int pbase = (blockIdx.x - 256) * 64;
    ushort_t* nbi = nb;
    ushort_t* h1 = s1;
    {
      int row = t >> 2, c8 = (t & 3) << 3;
      *(uint4*)&nbi[row * NI_LD + c8] =
          *(const uint4*)&imfh[(size_t)(pbase + row) * 32 + c8];
    }
    __syncthreads();
    {
      f32x4 accA[4];
      #pragma unroll
      for (int p = 0; p < 4; ++p) accA[p] = (f32x4){0.f, 0.f, 0.f, 0.f};
      int n = w * 16 + col;
      bf16x8 b = *(const bf16x8*)&c1h[n * 32 + quad * 8];
      #pragma unroll
      for (int p = 0; p < 4; ++p) {
        bf16x8 a = *(const bf16x8*)&nbi[(p * 16 + col) * NI_LD + quad * 8];
        accA[p] = __builtin_amdgcn_mfma_f32_16x16x32_bf16(a, b, accA[p], 0, 0, 0);
      }
      __syncthreads();
      float bb = c1b[n];
      #pragma unroll
      for (int p = 0; p < 4; ++p)
        #pragma unroll
        for (int r = 0; r < 4; ++r)
          h1[(p * 16 + quad * 4 + r) * H1_LD + n] = f2bf(lrelu(accA[p][r] + bb));
    }
    __syncthreads();
    f32x4 acc2[2][4];
    #pragma unroll
    for (int tt = 0; tt < 2; ++tt)
      #pragma unroll
      for (int p = 0; p < 4; ++p) acc2[tt][p] = (f32x4){0.f, 0.f, 0.f, 0.f};
    for (int k0 = 0; k0 < 64; k0 += 32) {
      bf16x8 a[4];
      #pragma unroll
      for (int p = 0; p < 4; ++p)
        a[p] = *(const bf16x8*)&h1[(p * 16 + col) * H1_LD + k0 + quad * 8];
      #pragma unroll
      for (int tt = 0; tt < 2; ++tt) {
        int n = w * 32 + tt * 16 + col;
        bf16x8 b = *(const bf16x8*)&c2h[n * 64 + k0 + quad * 8];
        #pragma unroll
        for (int p = 0; p < 4; ++p)
          acc2[tt][p] = __builtin_amdgcn_mfma_f32_16x16x32_bf16(a[p], b, acc2[tt][p], 0, 0, 0);
      }
    }
    #pragma unroll
    for (int tt = 0; tt < 2; ++tt) {
      int n = w * 32 + tt * 16 + col;
      float bb = c2b[n];
      #pragma unroll
      for (int p = 0; p < 4; ++p)
        #pragma unroll
        for (int r = 0; r < 4; ++r)
          yimg[(size_t)(pbase + p * 16 + quad * 4 + r) * 128 + n] =
              f2bf(acc2[tt][p][r] + bb);
    }
  }
}

// ---------------------------------------------------------------------------
// knng: grid KNN (exact top-16) fused with gather-max + feat. Final GEMV
// OFFLOADED to fing_kernel (MFMA): knng packs lrelu(feat) to bf16 and writes
// one coalesced 832B row featb[pid][416]. Softmax dist comes from the stored
// key's high word (= |q-c|^2) -- no pts4 gather, pts4 removed from kernel.
// ---------------------------------------------------------------------------
__device__ __forceinline__ float tadj(float tau, float qw) {
  float a = tau - qw;
  return a + fabsf(a) * 2e-7f + 1e-35f;
}

template <int NS>
__device__ __forceinline__ u64 selimpl(u64* buf, int cnt, int lane,
                                       float& tau) {
  u64 v[NS];
  unsigned k[NS];
  #pragma unroll
  for (int s = 0; s < NS; ++s) {
    int idx = s * 64 + lane;
    v[s] = (idx < cnt) ? buf[idx] : ~0ULL;
    k[s] = (unsigned)(v[s] >> 32);
  }
  // phase 1: m = 16th smallest d2-bits (sentinel 0xFFFFFFFF sorts last)
  unsigned m = 0u;
  #pragma unroll
  for (int b = 31; b >= 0; --b) {
    unsigned probe = m | (1u << b);
    int c = 0;
    #pragma unroll
    for (int s = 0; s < NS; ++s) c += __popcll(__ballot(k[s] < probe));
    if (c < KNN) m = probe;
  }
  // phase 2: tie-break on oid among keys equal to m (rare).
  int c_lt = 0, ne = 0;
  bool e[NS];
  #pragma unroll
  for (int s = 0; s < NS; ++s) {
    c_lt += __popcll(__ballot(k[s] < m));
    e[s] = (k[s] == m);
    ne += __popcll(__ballot(e[s]));
  }
  int need_eq = KNN - c_lt;
  unsigned m2 = 0xFFFFFFFFu;
  if (ne != need_eq) {
    m2 = 0u;
    #pragma unroll
    for (int b = 13; b >= 0; --b) {
      unsigned probe = m2 | (1u << b);
      int c = 0;
      #pragma unroll
      for (int s = 0; s < NS; ++s)
        c += __popcll(__ballot(e[s] && ((unsigned)v[s] < probe)));
      if (c < need_eq) m2 = probe;
    }
  }
  // compact the exact top-16 set to buf[0..15]
  int base = 0;
  #pragma unroll
  for (int s = 0; s < NS; ++s) {
    bool sel = (k[s] < m) || (e[s] && ((unsigned)v[s] <= m2));
    u64 msk = __ballot(sel);
    if (sel) buf[base + lanerank(msk)] = v[s];
    base += __popcll(msk);
  }
  tau = __uint_as_float(m);
  if (!(tau == tau)) tau = INFINITY;  // cnt<16: sentinel bits are NaN
  return buf[lane & 15];
}

__device__ __forceinline__ u64 select16(u64* buf, int& cnt, int lane,
                                        float& tau) {
  u64 r = (cnt <= 64) ? selimpl<1>(buf, cnt, lane, tau)
                      : selimpl<2>(buf, cnt, lane, tau);
  cnt = KNN;
  return r;
}

__global__ __launch_bounds__(256) void knng_kernel(
    const float4* __restrict__ spts, const int* __restrict__ cellStart,
    const ushort_t* __restrict__ ycf, const ushort_t* __restrict__ yimg,
    const ushort_t* __restrict__ cfh, const ushort_t* __restrict__ imfh,
    ushort_t* __restrict__ featb) {
  __shared__ u64 sbuf[4][128];                 // 4 KB
  __shared__ alignas(16) float feat[4][416];   // 6.5 KB
  int t = threadIdx.x;
  int wv = t >> 6, lane = t & 63;
  // XCD-chunked swizzle: each XCD's L2 holds one spatial slab.
  int sblk = (blockIdx.x & 7) * 512 + (blockIdx.x >> 3);
  int sid = sblk * 4 + wv;
  u64* buf = sbuf[wv];

  float4 q = spts[sid];                        // cell-sorted query
  int pid = __float_as_int(q.w);               // original point index
  float qw = fmaf(q.z, q.z, fmaf(q.y, q.y, q.x * q.x));
  float q2x = -2.f * q.x, q2y = -2.f * q.y, q2z = -2.f * q.z;
  int cx = cellof(q.x), cy = cellof(q.y), cz = cellof(q.z);

  // a-priori pruning radius: ~35 expected points in the clipped ball.
  float tau;
  {
    const float r0 = 0.0758f;  // (35*3/(4*pi*N))^(1/3) w/o clip
    float rr = r0;
    #pragma unroll
    for (int it = 0; it < 2; ++it) {
      float fx = (fminf(q.x + rr, 1.f) - fmaxf(q.x - rr, 0.f)) * (0.5f / rr);
      float fy = (fminf(q.y + rr, 1.f) - fmaxf(q.y - rr, 0.f)) * (0.5f / rr);
      float fz = (fminf(q.z + rr, 1.f) - fmaxf(q.z - rr, 0.f)) * (0.5f / rr);
      rr = r0 * __powf(fx * fy * fz, -0.333333f);
    }
    rr *= 1.05f;
    tau = rr * rr;
  }
  u64 vres;

  for (int r = 1;; ++r) {
    int lx = max(cx - r, 0), hx = min(cx + r, G - 1);
    int ly = max(cy - r, 0), hy = min(cy + r, G - 1);
    int lz = max(cz - r, 0), hz = min(cz + r, G - 1);
    int ny = hy - ly + 1, nz = hz - lz + 1, nruns = ny * nz;
    int cnt = 0;
    float ta = tadj(tau, qw);

    for (int rb = 0; rb < nruns; rb += 64) {
      int ln = rb + lane;
      int rs = 0, rc = 0;
      if (ln < nruns) {
        int z = lz + ln / ny, y = ly + ln % ny;
        int row = (z * G + y) * G;
        rs = cellStart[row + lx];
        rc = cellStart[row + hx + 1] - rs;
      }
      int nr = nruns - rb; nr = nr > 64 ? 64 : nr;
      int off = rc;
      #pragma unroll
      for (int d = 1; d < 64; d <<= 1) {
        int v = __shfl_up(off, d);
        if (lane >= d) off += v;
      }
      int T = __shfl(off, 63);
      off -= rc;

      for (int cb = 0; cb < T; cb += 64) {
        int rk = cb + lane;
        int j = 0;
        if (nr <= 16) {
          #pragma unroll
          for (int step = 8; step; step >>= 1) {
            int nj = j + step;
            if (__shfl(off, nj) <= rk) j = nj;
          }
        } else if (nr <= 32) {
          #pragma unroll
          for (int step = 16; step; step >>= 1) {
            int nj = j + step;
            if (__shfl(off, nj) <= rk) j = nj;
          }
        } else {
          #pragma unroll
          for (int step = 32; step; step >>= 1) {
            int nj = j + step;
            if (__shfl(off, nj) <= rk) j = nj;
          }
        }
        int src = __shfl(rs, j) + rk - __shfl(off, j);
        bool valid = rk < T;
        if (!valid) src = 0;
        float4 c = spts[src];
        float cw = fmaf(c.z, c.z, fmaf(c.y, c.y, c.x * c.x));
        float d2 = fmaf(q2x, c.x, fmaf(q2y, c.y, fmaf(q2z, c.z, cw)));
        bool pass = valid && (d2 <= ta);
        u64 mask = __ballot(pass);
        if (mask) {
          if (pass) {
            int oid = __float_as_int(c.w);
            u64 key = ((u64)__float_as_uint(fmaxf(d2 + qw, 0.f)) << 32) | (unsigned)oid;
            buf[cnt + lanerank(mask)] = key;
          }
          cnt += __popcll(mask);
          if (cnt > 64) {  // keep room for one more 64-append (buffer 128)
            select16(buf, cnt, lane, tau);
            ta = tadj(tau, qw);
          }
        }
      }
    }
    u64 v = select16(buf, cnt, lane, tau);
    float cl = INFINITY;
    if (lx > 0)     cl = fminf(cl, q.x - (float)lx / (float)G);
    if (hx < G - 1) cl = fminf(cl, (float)(hx + 1) / (float)G - q.x);
    if (ly > 0)     cl = fminf(cl, q.y - (float)ly / (float)G);
    if (hy < G - 1) cl = fminf(cl, (float)(hy + 1) / (float)G - q.y);
    if (lz > 0)     cl = fminf(cl, q.z - (float)lz / (float)G);
    if (hz < G - 1) cl = fminf(cl, (float)(hz + 1) / (float)G - q.z);
    bool full = (lx == 0 && hx == G - 1 && ly == 0 && hy == G - 1 &&
                 lz == 0 && hz == G - 1);
    if (full || tau * 1.00002f <= cl * cl) { vres = v; break; }
  }

  // ---- softmax weights; dist recovered from key's high word (=|q-c|^2) ----
  int myid = (lane < KNN) ? (int)(unsigned)(vres & 0xffffffffULL) : 0;
  float mywg = 0.f;
  {
    float dd = __uint_as_float((unsigned)(vres >> 32));
    float dist = sqrtf(fmaxf(dd, 1e-12f));
    float md = (lane < KNN) ? dist : INFINITY;
    #pragma unroll
    for (int off = 1; off < KNN; off <<= 1) md = fminf(md, __shfl_xor(md, off));
    float e = __expf(md - dist);
    float se = (lane < KNN) ? e : 0.f;
    #pragma unroll
    for (int off = 1; off < KNN; off <<= 1) se += __shfl_xor(se, off);
    mywg = e / se;  // valid on lanes < 16
  }

  // ---- gather-max over ycf / yimg rows ----
  int ksub = lane >> 4, c8 = lane & 15;
  float vimf = (lane < 32) ? bf2f(imfh[(size_t)pid * 32 + lane]) : 0.f;
  unsigned vcf = *(const unsigned*)&cfh[(size_t)pid * 128 + lane * 2];

  float a0[8], a1[8];
  #pragma unroll
  for (int j = 0; j < 8; ++j) { a0[j] = -INFINITY; a1[j] = -INFINITY; }
  #pragma unroll
  for (int kk = 0; kk < 4; ++kk) {
    int k = kk * 4 + ksub;
    int id = __shfl(myid, k);
    float wg = __shfl(mywg, k);
    uint4 v = *(const uint4*)&ycf[(size_t)id * 128 + c8 * 8];
    uint4 u = *(const uint4*)&yimg[(size_t)id * 128 + c8 * 8];
    unsigned vv[4] = {v.x, v.y, v.z, v.w};
    unsigned uu[4] = {u.x, u.y, u.z, u.w};
    #pragma unroll
    for (int h = 0; h < 4; ++h) {
      a0[h * 2]     = fmaxf(a0[h * 2],     bflo(vv[h]) * wg);
      a0[h * 2 + 1] = fmaxf(a0[h * 2 + 1], bfhi(vv[h]) * wg);
      a1[h * 2]     = fmaxf(a1[h * 2],     bflo(uu[h]) * wg);
      a1[h * 2 + 1] = fmaxf(a1[h * 2 + 1], bfhi(uu[h]) * wg);
    }
  }
  #pragma unroll
  for (int j = 0; j < 8; ++j) {
    a0[j] = fmaxf(a0[j], __shfl_xor(a0[j], 16));
    a0[j] = fmaxf(a0[j], __shfl_xor(a0[j], 32));
    a1[j] = fmaxf(a1[j], __shfl_xor(a1[j], 16));
    a1[j] = fmaxf(a1[j], __shfl_xor(a1[j], 32));
  }
  if (lane < 16) {
    #pragma unroll
    for (int j = 0; j < 8; ++j) {
      feat[wv][c8 * 8 + j] = lrelu(a0[j]);        // sfp -> [0,128)
      feat[wv][160 + c8 * 8 + j] = lrelu(a1[j]);  // sf  -> [160,288)
    }
  }
  if (lane < 32) feat[wv][128 + lane] = lrelu(vimf);
  feat[wv][288 + lane * 2] = lrelu(bflo(vcf));
  feat[wv][288 + lane * 2 + 1] = lrelu(bfhi(vcf));
  // same-wave LDS producer/consumer: no barrier needed

  // ---- pack feat -> bf16, coalesced 832B row write ----
  unsigned* frow = (unsigned*)(featb + (size_t)pid * 416);
  #pragma unroll
  for (int it = 0; it < 4; ++it) {
    int pi = it * 64 + lane;  // pair index 0..207
    if (pi < 208) {
      float lo = feat[wv][pi * 2], hi = feat[wv][pi * 2 + 1];
      frow[pi] = (unsigned)f2bf(lo) | ((unsigned)f2bf(hi) << 16);
    }
  }
}

// ---------------------------------------------------------------------------
// fing: final GEMM on MFMA with fused transpose. C = fwh[32][416] x
// featb[pt][416]^T: A-operand = weights (C rows = ch), B-operand = feat
// (C cols = points) -> store directly to out[ch][N] (64B segments).
// ---------------------------------------------------------------------------
__global__ __launch_bounds__(256) void fing_kernel(
    const ushort_t* __restrict__ featb, const ushort_t* __restrict__ fwh,
    const float* __restrict__ fb, float* __restrict__ out) {
  int t = threadIdx.x;
  int wv = t >> 6, lane = t & 63;
  int col = lane & 15, quad = lane >> 4;
  int pbase = blockIdx.x * 64 + wv * 16;  // this wave's 16 points
  f32x4 acc[2];
  acc[0] = (f32x4){0.f, 0.f, 0.f, 0.f};
  acc[1] = (f32x4){0.f, 0.f, 0.f, 0.f};
  for (int k0 = 0; k0 < 416; k0 += 32) {
    bf16x8 b = *(const bf16x8*)&featb[(size_t)(pbase + col) * 416 + k0 + quad * 8];
    #pragma unroll
    for (int tt = 0; tt < 2; ++tt) {
      bf16x8 a = *(const bf16x8*)&fwh[(tt * 16 + col) * 416 + k0 + quad * 8];
      acc[tt] = __builtin_amdgcn_mfma_f32_16x16x32_bf16(a, b, acc[tt], 0, 0, 0);
    }
  }
  #pragma unroll
  for (int tt = 0; tt < 2; ++tt) {
    #pragma unroll
    for (int r = 0; r < 4; ++r) {
      int ch = tt * 16 + quad * 4 + r;
      out[(size_t)ch * N + pbase + col] = acc[tt][r] + fb[ch];
    }
  }
}

// ---------------------------------------------------------------------------
extern "C" void kernel_launch(void* const* d_in, const int* in_sizes, int n_in,
                              void* d_out, int out_size, void* d_ws, size_t ws_size,
                              hipStream_t stream) {
  const float* img   = (const float*)d_in[0];
  const float* cloud = (const float*)d_in[1];
  const float* c1w   = (const float*)d_in[2];
  const float* c1b   = (const float*)d_in[3];
  const float* c2w   = (const float*)d_in[4];
  const float* c2b   = (const float*)d_in[5];
  const float* ps1w  = (const float*)d_in[6];
  const float* ps1b  = (const float*)d_in[7];
  const float* ps2w  = (const float*)d_in[8];
  const float* ps2b  = (const float*)d_in[9];
  const float* p1w   = (const float*)d_in[10];
  const float* p1b   = (const float*)d_in[11];
  const float* p2w   = (const float*)d_in[12];
  const float* p2b   = (const float*)d_in[13];
  const float* fw    = (const float*)d_in[14];
  const float* fb    = (const float*)d_in[15];
  float* out = (float*)d_out;

  char* ws = (char*)d_ws;
  float4*   pts4  = (float4*)(ws + 0);             // 256 KB   -> 262144
  ushort_t* cfh   = (ushort_t*)(ws + 262144);      // 4 MB     -> 4456448
  ushort_t* imfh  = (ushort_t*)(ws + 4456448);     // 1 MB     -> 5505024
  ushort_t* w1h   = (ushort_t*)(ws + 5505024);     // 64 KB    -> 5570560
  ushort_t* w2h   = (ushort_t*)(ws + 5570560);     // 64 KB    -> 5636096
  ushort_t* c1h   = (ushort_t*)(ws + 5636096);     // 4 KB     -> 5640192
  ushort_t* c2h   = (ushort_t*)(ws + 5640192);     // 16 KB    -> 5656576
  ushort_t* ycf   = (ushort_t*)(ws + 5656576);     // 4 MB     -> 9850880
  ushort_t* yimg  = (ushort_t*)(ws + 9850880);     // 4 MB     -> 14045184
  float4*   spts  = (float4*)(ws + 14045184);      // 256 KB   -> 14307328
  int*      cellStart = (int*)(ws + 14307328);     // 16 KB    -> 14323712
  int*      cellofs   = (int*)(ws + 14323712);     // 16 KB    -> 14339840
  int*      count     = (int*)(ws + 14339840);     // 16 KB    -> 14356224
  ushort_t* fwh       = (ushort_t*)(ws + 14356224);// 32 KB    -> 14388992
  ushort_t* featb     = (ushort_t*)(ws + 14388992);// 13.6 MB  -> 28020480

  hipMemsetAsync(count, 0, NCELL * sizeof(int), stream);
  prepw_kernel<<<604, 256, 0, stream>>>(img, cloud, p1w, p1b, p2w, p2b,
                                        ps1w, ps2w, c1w, c2w, fw,
                                        pts4, cfh, imfh, w1h, w2h, c1h, c2h,
                                        fwh, count);
  scan_kernel<<<1, 256, 0, stream>>>(count, cellStart, cellofs);
  scatter_kernel<<<64, 256, 0, stream>>>(pts4, cellofs, spts);
  ymlp_kernel<<<512, 256, 0, stream>>>(cfh, imfh, w1h, ps1b, w2h, ps2b,
                                       c1h, c1b, c2h, c2b, ycf, yimg);
  knng_kernel<<<N / 4, 256, 0, stream>>>(spts, cellStart,
                                         ycf, yimg, cfh, imfh, featb);
  fing_kernel<<<N / 64, 256, 0, stream>>>(featb, fwh, fb, out);
}

// Round 8
// 170.472 us; speedup vs baseline: 1.0542x; 1.0057x over previous
//
#include <hip/hip_runtime.h>
#include <math.h>

#define N 16384
#define KNN 16
#define G 14
#define NCELL (G * G * G)  // 2744

typedef __attribute__((ext_vector_type(8))) short bf16x8;
typedef __attribute__((ext_vector_type(4))) float f32x4;
typedef unsigned short ushort_t;
typedef unsigned long long u64;

__device__ __forceinline__ float lrelu(float a) { return a > 0.f ? a : 0.01f * a; }

__device__ __forceinline__ ushort_t f2bf(float f) {
  unsigned u = __float_as_uint(f);
  u += 0x7FFF + ((u >> 16) & 1);
  return (ushort_t)(u >> 16);
}
__device__ __forceinline__ float bf2f(ushort_t h) {
  return __uint_as_float((unsigned)h << 16);
}
__device__ __forceinline__ float bflo(unsigned u) {  // low bf16 of a pair
  return __uint_as_float(u << 16);
}
__device__ __forceinline__ float bfhi(unsigned u) {  // high bf16 of a pair
  return __uint_as_float(u & 0xffff0000u);
}
__device__ __forceinline__ int lanerank(u64 mask) {
  return __builtin_amdgcn_mbcnt_hi((unsigned)(mask >> 32),
         __builtin_amdgcn_mbcnt_lo((unsigned)mask, 0));
}
__device__ __forceinline__ int cellof(float x) {
  int c = (int)(x * (float)G);
  return c < 0 ? 0 : (c > G - 1 ? G - 1 : c);
}
__device__ __forceinline__ int cellid(float x, float y, float z) {
  return (cellof(z) * G + cellof(y)) * G + cellof(x);
}

// ---------------------------------------------------------------------------
// prepw: prep (blocks 0..255, + cell histogram) + weight conv (256..603).
// fwh: final weight as bf16 [32][416] row-major (straight convert of fw).
// imfh writes now staged through LDS -> coalesced uint4 row stores.
// ---------------------------------------------------------------------------
#define PPB 64
__global__ __launch_bounds__(256) void prepw_kernel(
    const float* __restrict__ img, const float* __restrict__ cloud,
    const float* __restrict__ p1w, const float* __restrict__ p1b,
    const float* __restrict__ p2w, const float* __restrict__ p2b,
    const float* __restrict__ ps1w, const float* __restrict__ ps2w,
    const float* __restrict__ c1w, const float* __restrict__ c2w,
    const float* __restrict__ fw,
    float4* __restrict__ pts4, ushort_t* __restrict__ cfh,
    ushort_t* __restrict__ imfh,
    ushort_t* __restrict__ w1h, ushort_t* __restrict__ w2h,
    ushort_t* __restrict__ c1h, ushort_t* __restrict__ c2h,
    ushort_t* __restrict__ fwh, int* __restrict__ count) {
  int t = threadIdx.x;
  if (blockIdx.x >= 256) {
    int e = (blockIdx.x - 256) * 256 + t;
    if (e < 32768) w1h[e] = f2bf(ps1w[e]);
    else if (e < 65536) w2h[e - 32768] = f2bf(ps2w[e - 32768]);
    else if (e < 67584) c1h[e - 65536] = f2bf(c1w[e - 65536]);
    else if (e < 75776) c2h[e - 67584] = f2bf(c2w[e - 67584]);
    else if (e < 89088) {
      int e2 = e - 75776;
      if (e2 < 13312) fwh[e2] = f2bf(fw[e2]);
    }
    return;
  }
  __shared__ alignas(16) float w2t[64 * 132];
  __shared__ alignas(16) float hs[PPB * 68];
  __shared__ alignas(16) float w1s[192];
  __shared__ alignas(16) float b1s[64];
  __shared__ alignas(16) float b2s[128];
  __shared__ alignas(16) ushort_t imt[PPB * 40];  // imfh staging (5 KB)
  __shared__ float ptmp[PPB * 3];
  __shared__ float psx[PPB], psy[PPB], psz[PPB];
  int pb = blockIdx.x * PPB;

  for (int e = t; e < 128 * 64; e += 256) {
    int ch = e >> 6, k = e & 63;
    w2t[k * 132 + ch] = p2w[e];
  }
  if (t < 192) w1s[t] = p1w[t];
  if (t < 64) b1s[t] = p1b[t];
  if (t < 128) b2s[t] = p2b[t];
  if (t < PPB * 3) ptmp[t] = cloud[pb * 3 + t];
  __syncthreads();
  if (t < PPB) {
    float x = ptmp[t * 3], y = ptmp[t * 3 + 1], z = ptmp[t * 3 + 2];
    psx[t] = x; psy[t] = y; psz[t] = z;
    pts4[pb + t] = make_float4(x, y, z, x * x + y * y + z * z);
    atomicAdd(&count[cellid(x, y, z)], 1);
  }
  for (int e = t; e < 32 * PPB; e += 256) {
    int c = e >> 6, p = e & 63;
    imt[p * 40 + c] = f2bf(img[(size_t)c * N + pb + p]);
  }
  __syncthreads();
  {  // coalesced imfh store: 4 lanes x uint4 = one 64B point-row
    int p = t >> 2, c8 = (t & 3) << 3;
    *(uint4*)&imfh[(size_t)(pb + p) * 32 + c8] =
        *(const uint4*)&imt[p * 40 + c8];
  }
  for (int e = t; e < PPB * 64; e += 256) {
    int pt_ = e >> 6, ch = e & 63;
    float a = b1s[ch] + psx[pt_] * w1s[ch * 3] + psy[pt_] * w1s[ch * 3 + 1] +
              psz[pt_] * w1s[ch * 3 + 2];
    hs[pt_ * 68 + ch] = lrelu(a);
  }
  __syncthreads();
  for (int e = t; e < PPB * 32; e += 256) {
    int pt_ = e >> 5, c4 = (e & 31) << 2;
    float4 acc = *(const float4*)&b2s[c4];
    const float* hrow = &hs[pt_ * 68];
    #pragma unroll
    for (int k = 0; k < 64; k += 4) {
      float4 h4 = *(const float4*)&hrow[k];
      float4 w0 = *(const float4*)&w2t[(k + 0) * 132 + c4];
      float4 w1_ = *(const float4*)&w2t[(k + 1) * 132 + c4];
      float4 w2_ = *(const float4*)&w2t[(k + 2) * 132 + c4];
      float4 w3 = *(const float4*)&w2t[(k + 3) * 132 + c4];
      acc.x = fmaf(h4.x, w0.x, fmaf(h4.y, w1_.x, fmaf(h4.z, w2_.x, fmaf(h4.w, w3.x, acc.x))));
      acc.y = fmaf(h4.x, w0.y, fmaf(h4.y, w1_.y, fmaf(h4.z, w2_.y, fmaf(h4.w, w3.y, acc.y))));
      acc.z = fmaf(h4.x, w0.z, fmaf(h4.y, w1_.z, fmaf(h4.z, w2_.z, fmaf(h4.w, w3.z, acc.z))));
      acc.w = fmaf(h4.x, w0.w, fmaf(h4.y, w1_.w, fmaf(h4.z, w2_.w, fmaf(h4.w, w3.w, acc.w))));
    }
    unsigned lo = (unsigned)f2bf(acc.x) | ((unsigned)f2bf(acc.y) << 16);
    unsigned hi = (unsigned)f2bf(acc.z) | ((unsigned)f2bf(acc.w) << 16);
    *(uint2*)&cfh[(size_t)(pb + pt_) * 128 + c4] = make_uint2(lo, hi);
  }
}

// ---------------------------------------------------------------------------
// scan: exclusive prefix over NCELL cell counts (1 block, 11 cells/thread).
// ---------------------------------------------------------------------------
__global__ __launch_bounds__(256) void scan_kernel(
    const int* __restrict__ count, int* __restrict__ cellStart,
    int* __restrict__ cellofs) {
  __shared__ int part[256];
  int t = threadIdx.x;
  int local[11];
  int s = 0;
  #pragma unroll
  for (int j = 0; j < 11; ++j) {
    int idx = t * 11 + j;
    local[j] = s;
    s += (idx < NCELL) ? count[idx] : 0;
  }
  part[t] = s;
  __syncthreads();
  for (int off = 1; off < 256; off <<= 1) {
    int v = (t >= off) ? part[t - off] : 0;
    __syncthreads();
    part[t] += v;
    __syncthreads();
  }
  int base = part[t] - s;
  #pragma unroll
  for (int j = 0; j < 11; ++j) {
    int idx = t * 11 + j;
    int v = base + local[j];
    if (idx < NCELL) { cellStart[idx] = v; cellofs[idx] = v; }
  }
  if (t == 255) cellStart[NCELL] = part[255];
}

// ---------------------------------------------------------------------------
// scatter: points into cell-sorted order; original index packed into .w.
// ---------------------------------------------------------------------------
__global__ __launch_bounds__(256) void scatter_kernel(
    const float4* __restrict__ pts4, int* __restrict__ cellofs,
    float4* __restrict__ spts) {
  int p = blockIdx.x * 256 + threadIdx.x;
  float4 v = pts4[p];
  int pos = atomicAdd(&cellofs[cellid(v.x, v.y, v.z)], 1);
  spts[pos] = make_float4(v.x, v.y, v.z, __int_as_float(p));
}

// ---------------------------------------------------------------------------
// ymlp: deduplicated dense MLPs. Output writes now staged through LDS
// (reusing nb, stride 136 for 16B alignment) -> coalesced uint4 stores.
// ---------------------------------------------------------------------------
#define NB_LD 136
#define S1_LD 264
#define NI_LD 40
#define H1_LD 72
__global__ __launch_bounds__(256) void ymlp_kernel(
    const ushort_t* __restrict__ cfh, const ushort_t* __restrict__ imfh,
    const ushort_t* __restrict__ w1h, const float* __restrict__ b1,
    const ushort_t* __restrict__ w2h, const float* __restrict__ b2,
    const ushort_t* __restrict__ c1h, const float* __restrict__ c1b,
    const ushort_t* __restrict__ c2h, const float* __restrict__ c2b,
    ushort_t* __restrict__ ycf, ushort_t* __restrict__ yimg) {
  __shared__ alignas(16) ushort_t nb[64 * NB_LD];
  __shared__ alignas(16) ushort_t s1[64 * S1_LD];
  int t = threadIdx.x;
  int w = t >> 6, lane = t & 63;
  int col = lane & 15, quad = lane >> 4;

  if (blockIdx.x < 256) {
    int pbase = blockIdx.x * 64;
    for (int e = t; e < 1024; e += 256) {
      int row = e >> 4, c8 = (e & 15) << 3;
      *(uint4*)&nb[row * NB_LD + c8] =
          *(const uint4*)&cfh[(size_t)(pbase + row) * 128 + c8];
    }
    __syncthreads();
    f32x4 acc1[4][4];
    #pragma unroll
    for (int tt = 0; tt < 4; ++tt)
      #pragma unroll
      for (int p = 0; p < 4; ++p) acc1[tt][p] = (f32x4){0.f, 0.f, 0.f, 0.f};
    for (int k0 = 0; k0 < 128; k0 += 32) {
      bf16x8 a[4];
      #pragma unroll
      for (int p = 0; p < 4; ++p)
        a[p] = *(const bf16x8*)&nb[(p * 16 + col) * NB_LD + k0 + quad * 8];
      #pragma unroll
      for (int tt = 0; tt < 4; ++tt) {
        int n = w * 64 + tt * 16 + col;
        bf16x8 b = *(const bf16x8*)&w1h[n * 128 + k0 + quad * 8];
        #pragma unroll
        for (int p = 0; p < 4; ++p)
          acc1[tt][p] = __builtin_amdgcn_mfma_f32_16x16x32_bf16(a[p], b, acc1[tt][p], 0, 0, 0);
      }
    }
    #pragma unroll
    for (int tt = 0; tt < 4; ++tt) {
      int n = w * 64 + tt * 16 + col;
      float bb = b1[n];
      #pragma unroll
      for (int p = 0; p < 4; ++p)
        #pragma unroll
        for (int r = 0; r < 4; ++r)
          s1[(p * 16 + quad * 4 + r) * S1_LD + n] = f2bf(lrelu(acc1[tt][p][r] + bb));
    }
    __syncthreads();   // all nb reads done; nb reusable as output staging
    f32x4 acc2[2][4];
    #pragma unroll
    for (int tt = 0; tt < 2; ++tt)
      #pragma unroll
      for (int p = 0; p < 4; ++p) acc2[tt][p] = (f32x4){0.f, 0.f, 0.f, 0.f};
    for (int k0 = 0; k0 < 256; k0 += 32) {
      bf16x8 a[4];
      #pragma unroll
      for (int p = 0; p < 4; ++p)
        a[p] = *(const bf16x8*)&s1[(p * 16 + col) * S1_LD + k0 + quad * 8];
      #pragma unroll
      for (int tt = 0; tt < 2; ++tt) {
        int n = w * 32 + tt * 16 + col;
        bf16x8 b = *(const bf16x8*)&w2h[n * 256 + k0 + quad * 8];
        #pragma unroll
        for (int p = 0; p < 4; ++p)
          acc2[tt][p] = __builtin_amdgcn_mfma_f32_16x16x32_bf16(a[p], b, acc2[tt][p], 0, 0, 0);
      }
    }
    // stage output tile in nb (LDS scatter), then coalesced global store
    #pragma unroll
    for (int tt = 0; tt < 2; ++tt) {
      int n = w * 32 + tt * 16 + col;
      float bb = b2[n];
      #pragma unroll
      for (int p = 0; p < 4; ++p)
        #pragma unroll
        for (int r = 0; r < 4; ++r)
          nb[(p * 16 + quad * 4 + r) * NB_LD + n] = f2bf(acc2[tt][p][r] + bb);
    }
    __syncthreads();
    for (int e = t; e < 1024; e += 256) {
      int row = e >> 4, c8 = (e & 15) << 3;
      *(uint4*)&ycf[(size_t)(pbase + row) * 128 + c8] =
          *(const uint4*)&nb[row * NB_LD + c8];
    }
  } else {
    int pbase = (blockIdx.x - 256) * 64;
    ushort_t* nbi = nb;
    ushort_t* h1 = s1;
    {
      int row = t >> 2, c8 = (t & 3) << 3;
      *(uint4*)&nbi[row * NI_LD + c8] =
          *(const uint4*)&imfh[(size_t)(pbase + row) * 32 + c8];
    }
    __syncthreads();
    {
      f32x4 accA[4];
      #pragma unroll
      for (int p = 0; p < 4; ++p) accA[p] = (f32x4){0.f, 0.f, 0.f, 0.f};
      int n = w * 16 + col;
      bf16x8 b = *(const bf16x8*)&c1h[n * 32 + quad * 8];
      #pragma unroll
      for (int p = 0; p < 4; ++p) {
        bf16x8 a = *(const bf16x8*)&nbi[(p * 16 + col) * NI_LD + quad * 8];
        accA[p] = __builtin_amdgcn_mfma_f32_16x16x32_bf16(a, b, accA[p], 0, 0, 0);
      }
      __syncthreads();   // all nbi reads done; nb reusable for output staging
      float bb = c1b[n];
      #pragma unroll
      for (int p = 0; p < 4; ++p)
        #pragma unroll
        for (int r = 0; r < 4; ++r)
          h1[(p * 16 + quad * 4 + r) * H1_LD + n] = f2bf(lrelu(accA[p][r] + bb));
    }
    __syncthreads();
    f32x4 acc2[2][4];
    #pragma unroll
    for (int tt = 0; tt < 2; ++tt)
      #pragma unroll
      for (int p = 0; p < 4; ++p) acc2[tt][p] = (f32x4){0.f, 0.f, 0.f, 0.f};
    for (int k0 = 0; k0 < 64; k0 += 32) {
      bf16x8 a[4];
      #pragma unroll
      for (int p = 0; p < 4; ++p)
        a[p] = *(const bf16x8*)&h1[(p * 16 + col) * H1_LD + k0 + quad * 8];
      #pragma unroll
      for (int tt = 0; tt < 2; ++tt) {
        int n = w * 32 + tt * 16 + col;
        bf16x8 b = *(const bf16x8*)&c2h[n * 64 + k0 + quad * 8];
        #pragma unroll
        for (int p = 0; p < 4; ++p)
          acc2[tt][p] = __builtin_amdgcn_mfma_f32_16x16x32_bf16(a[p], b, acc2[tt][p], 0, 0, 0);
      }
    }
    #pragma unroll
    for (int tt = 0; tt < 2; ++tt) {
      int n = w * 32 + tt * 16 + col;
      float bb = c2b[n];
      #pragma unroll
      for (int p = 0; p < 4; ++p)
        #pragma unroll
        for (int r = 0; r < 4; ++r)
          nb[(p * 16 + quad * 4 + r) * NB_LD + n] = f2bf(acc2[tt][p][r] + bb);
    }
    __syncthreads();
    for (int e = t; e < 1024; e += 256) {
      int row = e >> 4, c8 = (e & 15) << 3;
      *(uint4*)&yimg[(size_t)(pbase + row) * 128 + c8] =
          *(const uint4*)&nb[row * NB_LD + c8];
    }
  }
}

// ---------------------------------------------------------------------------
// knng: grid KNN (exact top-16) fused with gather-max + feat. Final GEMV
// offloaded to fing_kernel (MFMA); knng packs lrelu(feat) to bf16 rows.
// ---------------------------------------------------------------------------
__device__ __forceinline__ float tadj(float tau, float qw) {
  float a = tau - qw;
  return a + fabsf(a) * 2e-7f + 1e-35f;
}

template <int NS>
__device__ __forceinline__ u64 selimpl(u64* buf, int cnt, int lane,
                                       float& tau) {
  u64 v[NS];
  unsigned k[NS];
  #pragma unroll
  for (int s = 0; s < NS; ++s) {
    int idx = s * 64 + lane;
    v[s] = (idx < cnt) ? buf[idx] : ~0ULL;
    k[s] = (unsigned)(v[s] >> 32);
  }
  // phase 1: m = 16th smallest d2-bits (sentinel 0xFFFFFFFF sorts last)
  unsigned m = 0u;
  #pragma unroll
  for (int b = 31; b >= 0; --b) {
    unsigned probe = m | (1u << b);
    int c = 0;
    #pragma unroll
    for (int s = 0; s < NS; ++s) c += __popcll(__ballot(k[s] < probe));
    if (c < KNN) m = probe;
  }
  // phase 2: tie-break on oid among keys equal to m (rare).
  int c_lt = 0, ne = 0;
  bool e[NS];
  #pragma unroll
  for (int s = 0; s < NS; ++s) {
    c_lt += __popcll(__ballot(k[s] < m));
    e[s] = (k[s] == m);
    ne += __popcll(__ballot(e[s]));
  }
  int need_eq = KNN - c_lt;
  unsigned m2 = 0xFFFFFFFFu;
  if (ne != need_eq) {
    m2 = 0u;
    #pragma unroll
    for (int b = 13; b >= 0; --b) {
      unsigned probe = m2 | (1u << b);
      int c = 0;
      #pragma unroll
      for (int s = 0; s < NS; ++s)
        c += __popcll(__ballot(e[s] && ((unsigned)v[s] < probe)));
      if (c < need_eq) m2 = probe;
    }
  }
  // compact the exact top-16 set to buf[0..15]
  int base = 0;
  #pragma unroll
  for (int s = 0; s < NS; ++s) {
    bool sel = (k[s] < m) || (e[s] && ((unsigned)v[s] <= m2));
    u64 msk = __ballot(sel);
    if (sel) buf[base + lanerank(msk)] = v[s];
    base += __popcll(msk);
  }
  tau = __uint_as_float(m);
  if (!(tau == tau)) tau = INFINITY;  // cnt<16: sentinel bits are NaN
  return buf[lane & 15];
}

__device__ __forceinline__ u64 select16(u64* buf, int& cnt, int lane,
                                        float& tau) {
  u64 r = (cnt <= 64) ? selimpl<1>(buf, cnt, lane, tau)
                      : selimpl<2>(buf, cnt, lane, tau);
  cnt = KNN;
  return r;
}

__global__ __launch_bounds__(256) void knng_kernel(
    const float4* __restrict__ spts, const int* __restrict__ cellStart,
    const ushort_t* __restrict__ ycf, const ushort_t* __restrict__ yimg,
    const ushort_t* __restrict__ cfh, const ushort_t* __restrict__ imfh,
    ushort_t* __restrict__ featb) {
  __shared__ u64 sbuf[4][128];                 // 4 KB
  __shared__ alignas(16) float feat[4][416];   // 6.5 KB
  int t = threadIdx.x;
  int wv = t >> 6, lane = t & 63;
  // XCD-chunked swizzle: each XCD's L2 holds one spatial slab.
  int sblk = (blockIdx.x & 7) * 512 + (blockIdx.x >> 3);
  int sid = sblk * 4 + wv;
  u64* buf = sbuf[wv];

  float4 q = spts[sid];                        // cell-sorted query
  int pid = __float_as_int(q.w);               // original point index
  float qw = fmaf(q.z, q.z, fmaf(q.y, q.y, q.x * q.x));
  float q2x = -2.f * q.x, q2y = -2.f * q.y, q2z = -2.f * q.z;
  int cx = cellof(q.x), cy = cellof(q.y), cz = cellof(q.z);

  // a-priori pruning radius: ~35 expected points in the clipped ball.
  float tau;
  {
    const float r0 = 0.0758f;  // (35*3/(4*pi*N))^(1/3) w/o clip
    float rr = r0;
    #pragma unroll
    for (int it = 0; it < 2; ++it) {
      float fx = (fminf(q.x + rr, 1.f) - fmaxf(q.x - rr, 0.f)) * (0.5f / rr);
      float fy = (fminf(q.y + rr, 1.f) - fmaxf(q.y - rr, 0.f)) * (0.5f / rr);
      float fz = (fminf(q.z + rr, 1.f) - fmaxf(q.z - rr, 0.f)) * (0.5f / rr);
      rr = r0 * __powf(fx * fy * fz, -0.333333f);
    }
    rr *= 1.05f;
    tau = rr * rr;
  }
  u64 vres;

  for (int r = 1;; ++r) {
    int lx = max(cx - r, 0), hx = min(cx + r, G - 1);
    int ly = max(cy - r, 0), hy = min(cy + r, G - 1);
    int lz = max(cz - r, 0), hz = min(cz + r, G - 1);
    int ny = hy - ly + 1, nz = hz - lz + 1, nruns = ny * nz;
    int cnt = 0;
    float ta = tadj(tau, qw);

    for (int rb = 0; rb < nruns; rb += 64) {
      int ln = rb + lane;
      int rs = 0, rc = 0;
      if (ln < nruns) {
        int z = lz + ln / ny, y = ly + ln % ny;
        int row = (z * G + y) * G;
        rs = cellStart[row + lx];
        rc = cellStart[row + hx + 1] - rs;
      }
      int nr = nruns - rb; nr = nr > 64 ? 64 : nr;
      int off = rc;
      #pragma unroll
      for (int d = 1; d < 64; d <<= 1) {
        int v = __shfl_up(off, d);
        if (lane >= d) off += v;
      }
      int T = __shfl(off, 63);
      off -= rc;

      for (int cb = 0; cb < T; cb += 64) {
        int rk = cb + lane;
        int j = 0;
        if (nr <= 16) {
          #pragma unroll
          for (int step = 8; step; step >>= 1) {
            int nj = j + step;
            if (__shfl(off, nj) <= rk) j = nj;
          }
        } else if (nr <= 32) {
          #pragma unroll
          for (int step = 16; step; step >>= 1) {
            int nj = j + step;
            if (__shfl(off, nj) <= rk) j = nj;
          }
        } else {
          #pragma unroll
          for (int step = 32; step; step >>= 1) {
            int nj = j + step;
            if (__shfl(off, nj) <= rk) j = nj;
          }
        }
        int src = __shfl(rs, j) + rk - __shfl(off, j);
        bool valid = rk < T;
        if (!valid) src = 0;
        float4 c = spts[src];
        float cw = fmaf(c.z, c.z, fmaf(c.y, c.y, c.x * c.x));
        float d2 = fmaf(q2x, c.x, fmaf(q2y, c.y, fmaf(q2z, c.z, cw)));
        bool pass = valid && (d2 <= ta);
        u64 mask = __ballot(pass);
        if (mask) {
          if (pass) {
            int oid = __float_as_int(c.w);
            u64 key = ((u64)__float_as_uint(fmaxf(d2 + qw, 0.f)) << 32) | (unsigned)oid;
            buf[cnt + lanerank(mask)] = key;
          }
          cnt += __popcll(mask);
          if (cnt > 64) {  // keep room for one more 64-append (buffer 128)
            select16(buf, cnt, lane, tau);
            ta = tadj(tau, qw);
          }
        }
      }
    }
    u64 v = select16(buf, cnt, lane, tau);
    float cl = INFINITY;
    if (lx > 0)     cl = fminf(cl, q.x - (float)lx / (float)G);
    if (hx < G - 1) cl = fminf(cl, (float)(hx + 1) / (float)G - q.x);
    if (ly > 0)     cl = fminf(cl, q.y - (float)ly / (float)G);
    if (hy < G - 1) cl = fminf(cl, (float)(hy + 1) / (float)G - q.y);
    if (lz > 0)     cl = fminf(cl, q.z - (float)lz / (float)G);
    if (hz < G - 1) cl = fminf(cl, (float)(hz + 1) / (float)G - q.z);
    bool full = (lx == 0 && hx == G - 1 && ly == 0 && hy == G - 1 &&
                 lz == 0 && hz == G - 1);
    if (full || tau * 1.00002f <= cl * cl) { vres = v; break; }
  }

  // ---- softmax weights; dist recovered from key's high word (=|q-c|^2) ----
  int myid = (lane < KNN) ? (int)(unsigned)(vres & 0xffffffffULL) : 0;
  float mywg = 0.f;
  {
    float dd = __uint_as_float((unsigned)(vres >> 32));
    float dist = sqrtf(fmaxf(dd, 1e-12f));
    float md = (lane < KNN) ? dist : INFINITY;
    #pragma unroll
    for (int off = 1; off < KNN; off <<= 1) md = fminf(md, __shfl_xor(md, off));
    float e = __expf(md - dist);
    float se = (lane < KNN) ? e : 0.f;
    #pragma unroll
    for (int off = 1; off < KNN; off <<= 1) se += __shfl_xor(se, off);
    mywg = e / se;  // valid on lanes < 16
  }

  // ---- gather-max over ycf / yimg rows ----
  int ksub = lane >> 4, c8 = lane & 15;
  float vimf = (lane < 32) ? bf2f(imfh[(size_t)pid * 32 + lane]) : 0.f;
  unsigned vcf = *(const unsigned*)&cfh[(size_t)pid * 128 + lane * 2];

  float a0[8], a1[8];
  #pragma unroll
  for (int j = 0; j < 8; ++j) { a0[j] = -INFINITY; a1[j] = -INFINITY; }
  #pragma unroll
  for (int kk = 0; kk < 4; ++kk) {
    int k = kk * 4 + ksub;
    int id = __shfl(myid, k);
    float wg = __shfl(mywg, k);
    uint4 v = *(const uint4*)&ycf[(size_t)id * 128 + c8 * 8];
    uint4 u = *(const uint4*)&yimg[(size_t)id * 128 + c8 * 8];
    unsigned vv[4] = {v.x, v.y, v.z, v.w};
    unsigned uu[4] = {u.x, u.y, u.z, u.w};
    #pragma unroll
    for (int h = 0; h < 4; ++h) {
      a0[h * 2]     = fmaxf(a0[h * 2],     bflo(vv[h]) * wg);
      a0[h * 2 + 1] = fmaxf(a0[h * 2 + 1], bfhi(vv[h]) * wg);
      a1[h * 2]     = fmaxf(a1[h * 2],     bflo(uu[h]) * wg);
      a1[h * 2 + 1] = fmaxf(a1[h * 2 + 1], bfhi(uu[h]) * wg);
    }
  }
  #pragma unroll
  for (int j = 0; j < 8; ++j) {
    a0[j] = fmaxf(a0[j], __shfl_xor(a0[j], 16));
    a0[j] = fmaxf(a0[j], __shfl_xor(a0[j], 32));
    a1[j] = fmaxf(a1[j], __shfl_xor(a1[j], 16));
    a1[j] = fmaxf(a1[j], __shfl_xor(a1[j], 32));
  }
  if (lane < 16) {
    #pragma unroll
    for (int j = 0; j < 8; ++j) {
      feat[wv][c8 * 8 + j] = lrelu(a0[j]);        // sfp -> [0,128)
      feat[wv][160 + c8 * 8 + j] = lrelu(a1[j]);  // sf  -> [160,288)
    }
  }
  if (lane < 32) feat[wv][128 + lane] = lrelu(vimf);
  feat[wv][288 + lane * 2] = lrelu(bflo(vcf));
  feat[wv][288 + lane * 2 + 1] = lrelu(bfhi(vcf));
  // same-wave LDS producer/consumer: no barrier needed

  // ---- pack feat -> bf16, coalesced 832B row write ----
  unsigned* frow = (unsigned*)(featb + (size_t)pid * 416);
  #pragma unroll
  for (int it = 0; it < 4; ++it) {
    int pi = it * 64 + lane;  // pair index 0..207
    if (pi < 208) {
      float lo = feat[wv][pi * 2], hi = feat[wv][pi * 2 + 1];
      frow[pi] = (unsigned)f2bf(lo) | ((unsigned)f2bf(hi) << 16);
    }
  }
}

// ---------------------------------------------------------------------------
// fing: final GEMM on MFMA with fused transpose. C = fwh[32][416] x
// featb[pt][416]^T -> store directly to out[ch][N] (64B segments).
// ---------------------------------------------------------------------------
__global__ __launch_bounds__(256) void fing_kernel(
    const ushort_t* __restrict__ featb, const ushort_t* __restrict__ fwh,
    const float* __restrict__ fb, float* __restrict__ out) {
  int t = threadIdx.x;
  int wv = t >> 6, lane = t & 63;
  int col = lane & 15, quad = lane >> 4;
  int pbase = blockIdx.x * 64 + wv * 16;  // this wave's 16 points
  f32x4 acc[2];
  acc[0] = (f32x4){0.f, 0.f, 0.f, 0.f};
  acc[1] = (f32x4){0.f, 0.f, 0.f, 0.f};
  for (int k0 = 0; k0 < 416; k0 += 32) {
    bf16x8 b = *(const bf16x8*)&featb[(size_t)(pbase + col) * 416 + k0 + quad * 8];
    #pragma unroll
    for (int tt = 0; tt < 2; ++tt) {
      bf16x8 a = *(const bf16x8*)&fwh[(tt * 16 + col) * 416 + k0 + quad * 8];
      acc[tt] = __builtin_amdgcn_mfma_f32_16x16x32_bf16(a, b, acc[tt], 0, 0, 0);
    }
  }
  #pragma unroll
  for (int tt = 0; tt < 2; ++tt) {
    #pragma unroll
    for (int r = 0; r < 4; ++r) {
      int ch = tt * 16 + quad * 4 + r;
      out[(size_t)ch * N + pbase + col] = acc[tt][r] + fb[ch];
    }
  }
}

// ---------------------------------------------------------------------------
extern "C" void kernel_launch(void* const* d_in, const int* in_sizes, int n_in,
                              void* d_out, int out_size, void* d_ws, size_t ws_size,
                              hipStream_t stream) {
  const float* img   = (const float*)d_in[0];
  const float* cloud = (const float*)d_in[1];
  const float* c1w   = (const float*)d_in[2];
  const float* c1b   = (const float*)d_in[3];
  const float* c2w   = (const float*)d_in[4];
  const float* c2b   = (const float*)d_in[5];
  const float* ps1w  = (const float*)d_in[6];
  const float* ps1b  = (const float*)d_in[7];
  const float* ps2w  = (const float*)d_in[8];
  const float* ps2b  = (const float*)d_in[9];
  const float* p1w   = (const float*)d_in[10];
  const float* p1b   = (const float*)d_in[11];
  const float* p2w   = (const float*)d_in[12];
  const float* p2b   = (const float*)d_in[13];
  const float* fw    = (const float*)d_in[14];
  const float* fb    = (const float*)d_in[15];
  float* out = (float*)d_out;

  char* ws = (char*)d_ws;
  float4*   pts4  = (float4*)(ws + 0);             // 256 KB   -> 262144
  ushort_t* cfh   = (ushort_t*)(ws + 262144);      // 4 MB     -> 4456448
  ushort_t* imfh  = (ushort_t*)(ws + 4456448);     // 1 MB     -> 5505024
  ushort_t* w1h   = (ushort_t*)(ws + 5505024);     // 64 KB    -> 5570560
  ushort_t* w2h   = (ushort_t*)(ws + 5570560);     // 64 KB    -> 5636096
  ushort_t* c1h   = (ushort_t*)(ws + 5636096);     // 4 KB     -> 5640192
  ushort_t* c2h   = (ushort_t*)(ws + 5640192);     // 16 KB    -> 5656576
  ushort_t* ycf   = (ushort_t*)(ws + 5656576);     // 4 MB     -> 9850880
  ushort_t* yimg  = (ushort_t*)(ws + 9850880);     // 4 MB     -> 14045184
  float4*   spts  = (float4*)(ws + 14045184);      // 256 KB   -> 14307328
  int*      cellStart = (int*)(ws + 14307328);     // 16 KB    -> 14323712
  int*      cellofs   = (int*)(ws + 14323712);     // 16 KB    -> 14339840
  int*      count     = (int*)(ws + 14339840);     // 16 KB    -> 14356224
  ushort_t* fwh       = (ushort_t*)(ws + 14356224);// 32 KB    -> 14388992
  ushort_t* featb     = (ushort_t*)(ws + 14388992);// 13.6 MB  -> 28020480

  hipMemsetAsync(count, 0, NCELL * sizeof(int), stream);
  prepw_kernel<<<604, 256, 0, stream>>>(img, cloud, p1w, p1b, p2w, p2b,
                                        ps1w, ps2w, c1w, c2w, fw,
                                        pts4, cfh, imfh, w1h, w2h, c1h, c2h,
                                        fwh, count);
  scan_kernel<<<1, 256, 0, stream>>>(count, cellStart, cellofs);
  scatter_kernel<<<64, 256, 0, stream>>>(pts4, cellofs, spts);
  ymlp_kernel<<<512, 256, 0, stream>>>(cfh, imfh, w1h, ps1b, w2h, ps2b,
                                       c1h, c1b, c2h, c2b, ycf, yimg);
  knng_kernel<<<N / 4, 256, 0, stream>>>(spts, cellStart,
                                         ycf, yimg, cfh, imfh, featb);
  fing_kernel<<<N / 64, 256, 0, stream>>>(featb, fwh, fb, out);
}

// Round 9
// 166.272 us; speedup vs baseline: 1.0808x; 1.0253x over previous
//
#include <hip/hip_runtime.h>
#include <math.h>

#define N 16384
#define KNN 16
#define G 14
#define NCELL (G * G * G)  // 2744

typedef __attribute__((ext_vector_type(8))) short bf16x8;
typedef __attribute__((ext_vector_type(4))) float f32x4;
typedef unsigned short ushort_t;
typedef unsigned long long u64;

__device__ __forceinline__ float lrelu(float a) { return a > 0.f ? a : 0.01f * a; }

__device__ __forceinline__ ushort_t f2bf(float f) {
  unsigned u = __float_as_uint(f);
  u += 0x7FFF + ((u >> 16) & 1);
  return (ushort_t)(u >> 16);
}
__device__ __forceinline__ float bf2f(ushort_t h) {
  return __uint_as_float((unsigned)h << 16);
}
__device__ __forceinline__ float bflo(unsigned u) {  // low bf16 of a pair
  return __uint_as_float(u << 16);
}
__device__ __forceinline__ float bfhi(unsigned u) {  // high bf16 of a pair
  return __uint_as_float(u & 0xffff0000u);
}
__device__ __forceinline__ int lanerank(u64 mask) {
  return __builtin_amdgcn_mbcnt_hi((unsigned)(mask >> 32),
         __builtin_amdgcn_mbcnt_lo((unsigned)mask, 0));
}
__device__ __forceinline__ int cellof(float x) {
  int c = (int)(x * (float)G);
  return c < 0 ? 0 : (c > G - 1 ? G - 1 : c);
}
__device__ __forceinline__ int cellid(float x, float y, float z) {
  return (cellof(z) * G + cellof(y)) * G + cellof(x);
}

// ---------------------------------------------------------------------------
// prepw: prep (blocks 0..255, + cell histogram) + weight conv (256..603).
// fwh: final weight as bf16 [32][416] row-major (straight convert of fw).
// ---------------------------------------------------------------------------
#define PPB 64
__global__ __launch_bounds__(256) void prepw_kernel(
    const float* __restrict__ img, const float* __restrict__ cloud,
    const float* __restrict__ p1w, const float* __restrict__ p1b,
    const float* __restrict__ p2w, const float* __restrict__ p2b,
    const float* __restrict__ ps1w, const float* __restrict__ ps2w,
    const float* __restrict__ c1w, const float* __restrict__ c2w,
    const float* __restrict__ fw,
    float4* __restrict__ pts4, ushort_t* __restrict__ cfh,
    ushort_t* __restrict__ imfh,
    ushort_t* __restrict__ w1h, ushort_t* __restrict__ w2h,
    ushort_t* __restrict__ c1h, ushort_t* __restrict__ c2h,
    ushort_t* __restrict__ fwh, int* __restrict__ count) {
  int t = threadIdx.x;
  if (blockIdx.x >= 256) {
    int e = (blockIdx.x - 256) * 256 + t;
    if (e < 32768) w1h[e] = f2bf(ps1w[e]);
    else if (e < 65536) w2h[e - 32768] = f2bf(ps2w[e - 32768]);
    else if (e < 67584) c1h[e - 65536] = f2bf(c1w[e - 65536]);
    else if (e < 75776) c2h[e - 67584] = f2bf(c2w[e - 67584]);
    else if (e < 89088) {
      int e2 = e - 75776;
      if (e2 < 13312) fwh[e2] = f2bf(fw[e2]);
    }
    return;
  }
  __shared__ alignas(16) float w2t[64 * 132];
  __shared__ alignas(16) float hs[PPB * 68];
  __shared__ alignas(16) float w1s[192];
  __shared__ alignas(16) float b1s[64];
  __shared__ alignas(16) float b2s[128];
  __shared__ alignas(16) ushort_t imt[PPB * 40];  // imfh staging (5 KB)
  __shared__ float ptmp[PPB * 3];
  __shared__ float psx[PPB], psy[PPB], psz[PPB];
  int pb = blockIdx.x * PPB;

  for (int e = t; e < 128 * 64; e += 256) {
    int ch = e >> 6, k = e & 63;
    w2t[k * 132 + ch] = p2w[e];
  }
  if (t < 192) w1s[t] = p1w[t];
  if (t < 64) b1s[t] = p1b[t];
  if (t < 128) b2s[t] = p2b[t];
  if (t < PPB * 3) ptmp[t] = cloud[pb * 3 + t];
  __syncthreads();
  if (t < PPB) {
    float x = ptmp[t * 3], y = ptmp[t * 3 + 1], z = ptmp[t * 3 + 2];
    psx[t] = x; psy[t] = y; psz[t] = z;
    pts4[pb + t] = make_float4(x, y, z, x * x + y * y + z * z);
    atomicAdd(&count[cellid(x, y, z)], 1);
  }
  for (int e = t; e < 32 * PPB; e += 256) {
    int c = e >> 6, p = e & 63;
    imt[p * 40 + c] = f2bf(img[(size_t)c * N + pb + p]);
  }
  __syncthreads();
  {  // coalesced imfh store: 4 lanes x uint4 = one 64B point-row
    int p = t >> 2, c8 = (t & 3) << 3;
    *(uint4*)&imfh[(size_t)(pb + p) * 32 + c8] =
        *(const uint4*)&imt[p * 40 + c8];
  }
  for (int e = t; e < PPB * 64; e += 256) {
    int pt_ = e >> 6, ch = e & 63;
    float a = b1s[ch] + psx[pt_] * w1s[ch * 3] + psy[pt_] * w1s[ch * 3 + 1] +
              psz[pt_] * w1s[ch * 3 + 2];
    hs[pt_ * 68 + ch] = lrelu(a);
  }
  __syncthreads();
  for (int e = t; e < PPB * 32; e += 256) {
    int pt_ = e >> 5, c4 = (e & 31) << 2;
    float4 acc = *(const float4*)&b2s[c4];
    const float* hrow = &hs[pt_ * 68];
    #pragma unroll
    for (int k = 0; k < 64; k += 4) {
      float4 h4 = *(const float4*)&hrow[k];
      float4 w0 = *(const float4*)&w2t[(k + 0) * 132 + c4];
      float4 w1_ = *(const float4*)&w2t[(k + 1) * 132 + c4];
      float4 w2_ = *(const float4*)&w2t[(k + 2) * 132 + c4];
      float4 w3 = *(const float4*)&w2t[(k + 3) * 132 + c4];
      acc.x = fmaf(h4.x, w0.x, fmaf(h4.y, w1_.x, fmaf(h4.z, w2_.x, fmaf(h4.w, w3.x, acc.x))));
      acc.y = fmaf(h4.x, w0.y, fmaf(h4.y, w1_.y, fmaf(h4.z, w2_.y, fmaf(h4.w, w3.y, acc.y))));
      acc.z = fmaf(h4.x, w0.z, fmaf(h4.y, w1_.z, fmaf(h4.z, w2_.z, fmaf(h4.w, w3.z, acc.z))));
      acc.w = fmaf(h4.x, w0.w, fmaf(h4.y, w1_.w, fmaf(h4.z, w2_.w, fmaf(h4.w, w3.w, acc.w))));
    }
    unsigned lo = (unsigned)f2bf(acc.x) | ((unsigned)f2bf(acc.y) << 16);
    unsigned hi = (unsigned)f2bf(acc.z) | ((unsigned)f2bf(acc.w) << 16);
    *(uint2*)&cfh[(size_t)(pb + pt_) * 128 + c4] = make_uint2(lo, hi);
  }
}

// ---------------------------------------------------------------------------
// scan: exclusive prefix over NCELL cell counts (1 block, 11 cells/thread).
// ---------------------------------------------------------------------------
__global__ __launch_bounds__(256) void scan_kernel(
    const int* __restrict__ count, int* __restrict__ cellStart,
    int* __restrict__ cellofs) {
  __shared__ int part[256];
  int t = threadIdx.x;
  int local[11];
  int s = 0;
  #pragma unroll
  for (int j = 0; j < 11; ++j) {
    int idx = t * 11 + j;
    local[j] = s;
    s += (idx < NCELL) ? count[idx] : 0;
  }
  part[t] = s;
  __syncthreads();
  for (int off = 1; off < 256; off <<= 1) {
    int v = (t >= off) ? part[t - off] : 0;
    __syncthreads();
    part[t] += v;
    __syncthreads();
  }
  int base = part[t] - s;
  #pragma unroll
  for (int j = 0; j < 11; ++j) {
    int idx = t * 11 + j;
    int v = base + local[j];
    if (idx < NCELL) { cellStart[idx] = v; cellofs[idx] = v; }
  }
  if (t == 255) cellStart[NCELL] = part[255];
}

// ---------------------------------------------------------------------------
// scatter: points into cell-sorted order; original index packed into .w.
// ---------------------------------------------------------------------------
__global__ __launch_bounds__(256) void scatter_kernel(
    const float4* __restrict__ pts4, int* __restrict__ cellofs,
    float4* __restrict__ spts) {
  int p = blockIdx.x * 256 + threadIdx.x;
  float4 v = pts4[p];
  int pos = atomicAdd(&cellofs[cellid(v.x, v.y, v.z)], 1);
  spts[pos] = make_float4(v.x, v.y, v.z, __int_as_float(p));
}

// ---------------------------------------------------------------------------
// ymlp: deduplicated dense MLPs (LDS-staged coalesced output stores).
// ---------------------------------------------------------------------------
#define NB_LD 136
#define S1_LD 264
#define NI_LD 40
#define H1_LD 72
__global__ __launch_bounds__(256) void ymlp_kernel(
    const ushort_t* __restrict__ cfh, const ushort_t* __restrict__ imfh,
    const ushort_t* __restrict__ w1h, const float* __restrict__ b1,
    const ushort_t* __restrict__ w2h, const float* __restrict__ b2,
    const ushort_t* __restrict__ c1h, const float* __restrict__ c1b,
    const ushort_t* __restrict__ c2h, const float* __restrict__ c2b,
    ushort_t* __restrict__ ycf, ushort_t* __restrict__ yimg) {
  __shared__ alignas(16) ushort_t nb[64 * NB_LD];
  __shared__ alignas(16) ushort_t s1[64 * S1_LD];
  int t = threadIdx.x;
  int w = t >> 6, lane = t & 63;
  int col = lane & 15, quad = lane >> 4;

  if (blockIdx.x < 256) {
    int pbase = blockIdx.x * 64;
    for (int e = t; e < 1024; e += 256) {
      int row = e >> 4, c8 = (e & 15) << 3;
      *(uint4*)&nb[row * NB_LD + c8] =
          *(const uint4*)&cfh[(size_t)(pbase + row) * 128 + c8];
    }
    __syncthreads();
    f32x4 acc1[4][4];
    #pragma unroll
    for (int tt = 0; tt < 4; ++tt)
      #pragma unroll
      for (int p = 0; p < 4; ++p) acc1[tt][p] = (f32x4){0.f, 0.f, 0.f, 0.f};
    for (int k0 = 0; k0 < 128; k0 += 32) {
      bf16x8 a[4];
      #pragma unroll
      for (int p = 0; p < 4; ++p)
        a[p] = *(const bf16x8*)&nb[(p * 16 + col) * NB_LD + k0 + quad * 8];
      #pragma unroll
      for (int tt = 0; tt < 4; ++tt) {
        int n = w * 64 + tt * 16 + col;
        bf16x8 b = *(const bf16x8*)&w1h[n * 128 + k0 + quad * 8];
        #pragma unroll
        for (int p = 0; p < 4; ++p)
          acc1[tt][p] = __builtin_amdgcn_mfma_f32_16x16x32_bf16(a[p], b, acc1[tt][p], 0, 0, 0);
      }
    }
    #pragma unroll
    for (int tt = 0; tt < 4; ++tt) {
      int n = w * 64 + tt * 16 + col;
      float bb = b1[n];
      #pragma unroll
      for (int p = 0; p < 4; ++p)
        #pragma unroll
        for (int r = 0; r < 4; ++r)
          s1[(p * 16 + quad * 4 + r) * S1_LD + n] = f2bf(lrelu(acc1[tt][p][r] + bb));
    }
    __syncthreads();   // all nb reads done; nb reusable as output staging
    f32x4 acc2[2][4];
    #pragma unroll
    for (int tt = 0; tt < 2; ++tt)
      #pragma unroll
      for (int p = 0; p < 4; ++p) acc2[tt][p] = (f32x4){0.f, 0.f, 0.f, 0.f};
    for (int k0 = 0; k0 < 256; k0 += 32) {
      bf16x8 a[4];
      #pragma unroll
      for (int p = 0; p < 4; ++p)
        a[p] = *(const bf16x8*)&s1[(p * 16 + col) * S1_LD + k0 + quad * 8];
      #pragma unroll
      for (int tt = 0; tt < 2; ++tt) {
        int n = w * 32 + tt * 16 + col;
        bf16x8 b = *(const bf16x8*)&w2h[n * 256 + k0 + quad * 8];
        #pragma unroll
        for (int p = 0; p < 4; ++p)
          acc2[tt][p] = __builtin_amdgcn_mfma_f32_16x16x32_bf16(a[p], b, acc2[tt][p], 0, 0, 0);
      }
    }
    #pragma unroll
    for (int tt = 0; tt < 2; ++tt) {
      int n = w * 32 + tt * 16 + col;
      float bb = b2[n];
      #pragma unroll
      for (int p = 0; p < 4; ++p)
        #pragma unroll
        for (int r = 0; r < 4; ++r)
          nb[(p * 16 + quad * 4 + r) * NB_LD + n] = f2bf(acc2[tt][p][r] + bb);
    }
    __syncthreads();
    for (int e = t; e < 1024; e += 256) {
      int row = e >> 4, c8 = (e & 15) << 3;
      *(uint4*)&ycf[(size_t)(pbase + row) * 128 + c8] =
          *(const uint4*)&nb[row * NB_LD + c8];
    }
  } else {
    int pbase = (blockIdx.x - 256) * 64;
    ushort_t* nbi = nb;
    ushort_t* h1 = s1;
    {
      int row = t >> 2, c8 = (t & 3) << 3;
      *(uint4*)&nbi[row * NI_LD + c8] =
          *(const uint4*)&imfh[(size_t)(pbase + row) * 32 + c8];
    }
    __syncthreads();
    {
      f32x4 accA[4];
      #pragma unroll
      for (int p = 0; p < 4; ++p) accA[p] = (f32x4){0.f, 0.f, 0.f, 0.f};
      int n = w * 16 + col;
      bf16x8 b = *(const bf16x8*)&c1h[n * 32 + quad * 8];
      #pragma unroll
      for (int p = 0; p < 4; ++p) {
        bf16x8 a = *(const bf16x8*)&nbi[(p * 16 + col) * NI_LD + quad * 8];
        accA[p] = __builtin_amdgcn_mfma_f32_16x16x32_bf16(a, b, accA[p], 0, 0, 0);
      }
      __syncthreads();   // all nbi reads done; nb reusable for output staging
      float bb = c1b[n];
      #pragma unroll
      for (int p = 0; p < 4; ++p)
        #pragma unroll
        for (int r = 0; r < 4; ++r)
          h1[(p * 16 + quad * 4 + r) * H1_LD + n] = f2bf(lrelu(accA[p][r] + bb));
    }
    __syncthreads();
    f32x4 acc2[2][4];
    #pragma unroll
    for (int tt = 0; tt < 2; ++tt)
      #pragma unroll
      for (int p = 0; p < 4; ++p) acc2[tt][p] = (f32x4){0.f, 0.f, 0.f, 0.f};
    for (int k0 = 0; k0 < 64; k0 += 32) {
      bf16x8 a[4];
      #pragma unroll
      for (int p = 0; p < 4; ++p)
        a[p] = *(const bf16x8*)&h1[(p * 16 + col) * H1_LD + k0 + quad * 8];
      #pragma unroll
      for (int tt = 0; tt < 2; ++tt) {
        int n = w * 32 + tt * 16 + col;
        bf16x8 b = *(const bf16x8*)&c2h[n * 64 + k0 + quad * 8];
        #pragma unroll
        for (int p = 0; p < 4; ++p)
          acc2[tt][p] = __builtin_amdgcn_mfma_f32_16x16x32_bf16(a[p], b, acc2[tt][p], 0, 0, 0);
      }
    }
    #pragma unroll
    for (int tt = 0; tt < 2; ++tt) {
      int n = w * 32 + tt * 16 + col;
      float bb = c2b[n];
      #pragma unroll
      for (int p = 0; p < 4; ++p)
        #pragma unroll
        for (int r = 0; r < 4; ++r)
          nb[(p * 16 + quad * 4 + r) * NB_LD + n] = f2bf(acc2[tt][p][r] + bb);
    }
    __syncthreads();
    for (int e = t; e < 1024; e += 256) {
      int row = e >> 4, c8 = (e & 15) << 3;
      *(uint4*)&yimg[(size_t)(pbase + row) * 128 + c8] =
          *(const uint4*)&nb[row * NB_LD + c8];
    }
  }
}

// ---------------------------------------------------------------------------
// knng: grid KNN (exact top-16) fused with gather-max + feat pack.
// NEW: (1) cell-level trim -- per run (y,z), skip if slab min-dist^2 > tau
// (strictly conservative: excluded points would fail the pass check), and
// shrink the x-range to cellof(q.x +- sqrt(tau - dy^2 - dz^2)). Candidates
// scanned drop ~161 -> ~70. (2) in-lane gather-max: lane owns 2 channels
// across all 16 neighbors (readlane broadcast of id/wg) -- no shfl_xor
// reduces, no feat LDS, featb row built by 4 direct u32 stores.
// ---------------------------------------------------------------------------
__device__ __forceinline__ float tadj(float tau, float qw) {
  float a = tau - qw;
  return a + fabsf(a) * 2e-7f + 1e-35f;
}

template <int NS>
__device__ __forceinline__ u64 selimpl(u64* buf, int cnt, int lane,
                                       float& tau) {
  u64 v[NS];
  unsigned k[NS];
  #pragma unroll
  for (int s = 0; s < NS; ++s) {
    int idx = s * 64 + lane;
    v[s] = (idx < cnt) ? buf[idx] : ~0ULL;
    k[s] = (unsigned)(v[s] >> 32);
  }
  // phase 1: m = 16th smallest d2-bits (sentinel 0xFFFFFFFF sorts last)
  unsigned m = 0u;
  #pragma unroll
  for (int b = 31; b >= 0; --b) {
    unsigned probe = m | (1u << b);
    int c = 0;
    #pragma unroll
    for (int s = 0; s < NS; ++s) c += __popcll(__ballot(k[s] < probe));
    if (c < KNN) m = probe;
  }
  // phase 2: tie-break on oid among keys equal to m (rare).
  int c_lt = 0, ne = 0;
  bool e[NS];
  #pragma unroll
  for (int s = 0; s < NS; ++s) {
    c_lt += __popcll(__ballot(k[s] < m));
    e[s] = (k[s] == m);
    ne += __popcll(__ballot(e[s]));
  }
  int need_eq = KNN - c_lt;
  unsigned m2 = 0xFFFFFFFFu;
  if (ne != need_eq) {
    m2 = 0u;
    #pragma unroll
    for (int b = 13; b >= 0; --b) {
      unsigned probe = m2 | (1u << b);
      int c = 0;
      #pragma unroll
      for (int s = 0; s < NS; ++s)
        c += __popcll(__ballot(e[s] && ((unsigned)v[s] < probe)));
      if (c < need_eq) m2 = probe;
    }
  }
  // compact the exact top-16 set to buf[0..15]
  int base = 0;
  #pragma unroll
  for (int s = 0; s < NS; ++s) {
    bool sel = (k[s] < m) || (e[s] && ((unsigned)v[s] <= m2));
    u64 msk = __ballot(sel);
    if (sel) buf[base + lanerank(msk)] = v[s];
    base += __popcll(msk);
  }
  tau = __uint_as_float(m);
  if (!(tau == tau)) tau = INFINITY;  // cnt<16: sentinel bits are NaN
  return buf[lane & 15];
}

__device__ __forceinline__ u64 select16(u64* buf, int& cnt, int lane,
                                        float& tau) {
  u64 r = (cnt <= 64) ? selimpl<1>(buf, cnt, lane, tau)
                      : selimpl<2>(buf, cnt, lane, tau);
  cnt = KNN;
  return r;
}

__device__ __forceinline__ float truethr(float tau, float qw) {
  // conservative true-distance^2 threshold matching tadj's slack
  return tau + (tau + qw) * 3e-7f + 1e-30f;
}

__global__ __launch_bounds__(256) void knng_kernel(
    const float4* __restrict__ spts, const int* __restrict__ cellStart,
    const ushort_t* __restrict__ ycf, const ushort_t* __restrict__ yimg,
    const ushort_t* __restrict__ cfh, const ushort_t* __restrict__ imfh,
    ushort_t* __restrict__ featb) {
  __shared__ u64 sbuf[4][128];                 // 4 KB (only LDS left)
  int t = threadIdx.x;
  int wv = t >> 6, lane = t & 63;
  // XCD-chunked swizzle: each XCD's L2 holds one spatial slab.
  int sblk = (blockIdx.x & 7) * 512 + (blockIdx.x >> 3);
  int sid = sblk * 4 + wv;
  u64* buf = sbuf[wv];

  float4 q = spts[sid];                        // cell-sorted query
  int pid = __float_as_int(q.w);               // original point index
  float qw = fmaf(q.z, q.z, fmaf(q.y, q.y, q.x * q.x));
  float q2x = -2.f * q.x, q2y = -2.f * q.y, q2z = -2.f * q.z;
  int cx = cellof(q.x), cy = cellof(q.y), cz = cellof(q.z);

  // a-priori pruning radius: ~35 expected points in the clipped ball.
  float tau;
  {
    const float r0 = 0.0758f;  // (35*3/(4*pi*N))^(1/3) w/o clip
    float rr = r0;
    #pragma unroll
    for (int it = 0; it < 2; ++it) {
      float fx = (fminf(q.x + rr, 1.f) - fmaxf(q.x - rr, 0.f)) * (0.5f / rr);
      float fy = (fminf(q.y + rr, 1.f) - fmaxf(q.y - rr, 0.f)) * (0.5f / rr);
      float fz = (fminf(q.z + rr, 1.f) - fmaxf(q.z - rr, 0.f)) * (0.5f / rr);
      rr = r0 * __powf(fx * fy * fz, -0.333333f);
    }
    rr *= 1.05f;
    tau = rr * rr;
  }
  u64 vres;

  for (int r = 1;; ++r) {
    int lx = max(cx - r, 0), hx = min(cx + r, G - 1);
    int ly = max(cy - r, 0), hy = min(cy + r, G - 1);
    int lz = max(cz - r, 0), hz = min(cz + r, G - 1);
    int ny = hy - ly + 1, nz = hz - lz + 1, nruns = ny * nz;
    int cnt = 0;
    float ta = tadj(tau, qw);
    float tt = truethr(tau, qw);

    for (int rb = 0; rb < nruns; rb += 64) {
      int ln = rb + lane;
      int rs = 0, rc = 0;
      if (ln < nruns) {
        int z = lz + ln / ny, y = ly + ln % ny;
        // slab min-dist^2 trim (conservative: 1e-6 boundary shave)
        float loY = (float)y * (1.f / G), hiY = loY + (1.f / G);
        float loZ = (float)z * (1.f / G), hiZ = loZ + (1.f / G);
        float dy = fmaxf(fmaxf(loY - q.y, q.y - hiY) - 1e-6f, 0.f);
        float dz = fmaxf(fmaxf(loZ - q.z, q.z - hiZ) - 1e-6f, 0.f);
        float rem = tt - dy * dy - dz * dz;
        if (rem >= 0.f) {
          float rad = fminf(sqrtf(rem) + 1e-6f, 2.f);
          int xlo = max(lx, cellof(q.x - rad));
          int xhi = min(hx, cellof(q.x + rad));
          int row = (z * G + y) * G;
          rs = cellStart[row + xlo];
          rc = cellStart[row + xhi + 1] - rs;
        }
      }
      int nr = nruns - rb; nr = nr > 64 ? 64 : nr;
      int off = rc;
      #pragma unroll
      for (int d = 1; d < 64; d <<= 1) {
        int v = __shfl_up(off, d);
        if (lane >= d) off += v;
      }
      int T = __shfl(off, 63);
      off -= rc;

      for (int cb = 0; cb < T; cb += 64) {
        int rk = cb + lane;
        int j = 0;
        if (nr <= 16) {
          #pragma unroll
          for (int step = 8; step; step >>= 1) {
            int nj = j + step;
            if (__shfl(off, nj) <= rk) j = nj;
          }
        } else if (nr <= 32) {
          #pragma unroll
          for (int step = 16; step; step >>= 1) {
            int nj = j + step;
            if (__shfl(off, nj) <= rk) j = nj;
          }
        } else {
          #pragma unroll
          for (int step = 32; step; step >>= 1) {
            int nj = j + step;
            if (__shfl(off, nj) <= rk) j = nj;
          }
        }
        int src = __shfl(rs, j) + rk - __shfl(off, j);
        bool valid = rk < T;
        if (!valid) src = 0;
        float4 c = spts[src];
        float cw = fmaf(c.z, c.z, fmaf(c.y, c.y, c.x * c.x));
        float d2 = fmaf(q2x, c.x, fmaf(q2y, c.y, fmaf(q2z, c.z, cw)));
        bool pass = valid && (d2 <= ta);
        u64 mask = __ballot(pass);
        if (mask) {
          if (pass) {
            int oid = __float_as_int(c.w);
            u64 key = ((u64)__float_as_uint(fmaxf(d2 + qw, 0.f)) << 32) | (unsigned)oid;
            buf[cnt + lanerank(mask)] = key;
          }
          cnt += __popcll(mask);
          if (cnt > 64) {  // keep room for one more 64-append (buffer 128)
            select16(buf, cnt, lane, tau);
            ta = tadj(tau, qw);
            tt = truethr(tau, qw);
          }
        }
      }
    }
    u64 v = select16(buf, cnt, lane, tau);
    float cl = INFINITY;
    if (lx > 0)     cl = fminf(cl, q.x - (float)lx / (float)G);
    if (hx < G - 1) cl = fminf(cl, (float)(hx + 1) / (float)G - q.x);
    if (ly > 0)     cl = fminf(cl, q.y - (float)ly / (float)G);
    if (hy < G - 1) cl = fminf(cl, (float)(hy + 1) / (float)G - q.y);
    if (lz > 0)     cl = fminf(cl, q.z - (float)lz / (float)G);
    if (hz < G - 1) cl = fminf(cl, (float)(hz + 1) / (float)G - q.z);
    bool full = (lx == 0 && hx == G - 1 && ly == 0 && hy == G - 1 &&
                 lz == 0 && hz == G - 1);
    if (full || tau * 1.00002f <= cl * cl) { vres = v; break; }
  }

  // ---- softmax weights; dist recovered from key's high word (=|q-c|^2) ----
  int myid = (lane < KNN) ? (int)(unsigned)(vres & 0xffffffffULL) : 0;
  float mywg = 0.f;
  {
    float dd = __uint_as_float((unsigned)(vres >> 32));
    float dist = sqrtf(fmaxf(dd, 1e-12f));
    float md = (lane < KNN) ? dist : INFINITY;
    #pragma unroll
    for (int off = 1; off < KNN; off <<= 1) md = fminf(md, __shfl_xor(md, off));
    float e = __expf(md - dist);
    float se = (lane < KNN) ? e : 0.f;
    #pragma unroll
    for (int off = 1; off < KNN; off <<= 1) se += __shfl_xor(se, off);
    mywg = e / se;  // valid on lanes < 16
  }

  // ---- in-lane gather-max: lane owns channels (2*lane, 2*lane+1) ----
  float A0 = -INFINITY, A1 = -INFINITY, B0 = -INFINITY, B1 = -INFINITY;
  size_t coff = (size_t)(lane * 2);
  #pragma unroll
  for (int k = 0; k < KNN; ++k) {
    int id = __shfl(myid, k);      // constant lane -> v_readlane
    float wg = __shfl(mywg, k);
    unsigned v = *(const unsigned*)&ycf[(size_t)id * 128 + coff];
    unsigned u = *(const unsigned*)&yimg[(size_t)id * 128 + coff];
    A0 = fmaxf(A0, bflo(v) * wg);
    A1 = fmaxf(A1, bfhi(v) * wg);
    B0 = fmaxf(B0, bflo(u) * wg);
    B1 = fmaxf(B1, bfhi(u) * wg);
  }
  // ---- featb row: 4 direct u32 stores build the 832B bf16 row ----
  unsigned* frow = (unsigned*)(featb + (size_t)pid * 416);
  frow[lane] = (unsigned)f2bf(lrelu(A0)) | ((unsigned)f2bf(lrelu(A1)) << 16);
  frow[80 + lane] = (unsigned)f2bf(lrelu(B0)) | ((unsigned)f2bf(lrelu(B1)) << 16);
  if (lane < 16) {  // imf pairs 64..79 (channels 0..31)
    unsigned vi = *(const unsigned*)&imfh[(size_t)pid * 32 + lane * 2];
    frow[64 + lane] =
        (unsigned)f2bf(lrelu(bflo(vi))) | ((unsigned)f2bf(lrelu(bfhi(vi))) << 16);
  }
  unsigned vcf = *(const unsigned*)&cfh[(size_t)pid * 128 + coff];
  frow[144 + lane] =
      (unsigned)f2bf(lrelu(bflo(vcf))) | ((unsigned)f2bf(lrelu(bfhi(vcf))) << 16);
}

// ---------------------------------------------------------------------------
// fing: final GEMM on MFMA with fused transpose. C = fwh[32][416] x
// featb[pt][416]^T -> store directly to out[ch][N] (64B segments).
// ---------------------------------------------------------------------------
__global__ __launch_bounds__(256) void fing_kernel(
    const ushort_t* __restrict__ featb, const ushort_t* __restrict__ fwh,
    const float* __restrict__ fb, float* __restrict__ out) {
  int t = threadIdx.x;
  int wv = t >> 6, lane = t & 63;
  int col = lane & 15, quad = lane >> 4;
  int pbase = blockIdx.x * 64 + wv * 16;  // this wave's 16 points
  f32x4 acc[2];
  acc[0] = (f32x4){0.f, 0.f, 0.f, 0.f};
  acc[1] = (f32x4){0.f, 0.f, 0.f, 0.f};
  for (int k0 = 0; k0 < 416; k0 += 32) {
    bf16x8 b = *(const bf16x8*)&featb[(size_t)(pbase + col) * 416 + k0 + quad * 8];
    #pragma unroll
    for (int tt = 0; tt < 2; ++tt) {
      bf16x8 a = *(const bf16x8*)&fwh[(tt * 16 + col) * 416 + k0 + quad * 8];
      acc[tt] = __builtin_amdgcn_mfma_f32_16x16x32_bf16(a, b, acc[tt], 0, 0, 0);
    }
  }
  #pragma unroll
  for (int tt = 0; tt < 2; ++tt) {
    #pragma unroll
    for (int r = 0; r < 4; ++r) {
      int ch = tt * 16 + quad * 4 + r;
      out[(size_t)ch * N + pbase + col] = acc[tt][r] + fb[ch];
    }
  }
}

// ---------------------------------------------------------------------------
extern "C" void kernel_launch(void* const* d_in, const int* in_sizes, int n_in,
                              void* d_out, int out_size, void* d_ws, size_t ws_size,
                              hipStream_t stream) {
  const float* img   = (const float*)d_in[0];
  const float* cloud = (const float*)d_in[1];
  const float* c1w   = (const float*)d_in[2];
  const float* c1b   = (const float*)d_in[3];
  const float* c2w   = (const float*)d_in[4];
  const float* c2b   = (const float*)d_in[5];
  const float* ps1w  = (const float*)d_in[6];
  const float* ps1b  = (const float*)d_in[7];
  const float* ps2w  = (const float*)d_in[8];
  const float* ps2b  = (const float*)d_in[9];
  const float* p1w   = (const float*)d_in[10];
  const float* p1b   = (const float*)d_in[11];
  const float* p2w   = (const float*)d_in[12];
  const float* p2b   = (const float*)d_in[13];
  const float* fw    = (const float*)d_in[14];
  const float* fb    = (const float*)d_in[15];
  float* out = (float*)d_out;

  char* ws = (char*)d_ws;
  float4*   pts4  = (float4*)(ws + 0);             // 256 KB   -> 262144
  ushort_t* cfh   = (ushort_t*)(ws + 262144);      // 4 MB     -> 4456448
  ushort_t* imfh  = (ushort_t*)(ws + 4456448);     // 1 MB     -> 5505024
  ushort_t* w1h   = (ushort_t*)(ws + 5505024);     // 64 KB    -> 5570560
  ushort_t* w2h   = (ushort_t*)(ws + 5570560);     // 64 KB    -> 5636096
  ushort_t* c1h   = (ushort_t*)(ws + 5636096);     // 4 KB     -> 5640192
  ushort_t* c2h   = (ushort_t*)(ws + 5640192);     // 16 KB    -> 5656576
  ushort_t* ycf   = (ushort_t*)(ws + 5656576);     // 4 MB     -> 9850880
  ushort_t* yimg  = (ushort_t*)(ws + 9850880);     // 4 MB     -> 14045184
  float4*   spts  = (float4*)(ws + 14045184);      // 256 KB   -> 14307328
  int*      cellStart = (int*)(ws + 14307328);     // 16 KB    -> 14323712
  int*      cellofs   = (int*)(ws + 14323712);     // 16 KB    -> 14339840
  int*      count     = (int*)(ws + 14339840);     // 16 KB    -> 14356224
  ushort_t* fwh       = (ushort_t*)(ws + 14356224);// 32 KB    -> 14388992
  ushort_t* featb     = (ushort_t*)(ws + 14388992);// 13.6 MB  -> 28020480

  hipMemsetAsync(count, 0, NCELL * sizeof(int), stream);
  prepw_kernel<<<604, 256, 0, stream>>>(img, cloud, p1w, p1b, p2w, p2b,
                                        ps1w, ps2w, c1w, c2w, fw,
                                        pts4, cfh, imfh, w1h, w2h, c1h, c2h,
                                        fwh, count);
  scan_kernel<<<1, 256, 0, stream>>>(count, cellStart, cellofs);
  scatter_kernel<<<64, 256, 0, stream>>>(pts4, cellofs, spts);
  ymlp_kernel<<<512, 256, 0, stream>>>(cfh, imfh, w1h, ps1b, w2h, ps2b,
                                       c1h, c1b, c2h, c2b, ycf, yimg);
  knng_kernel<<<N / 4, 256, 0, stream>>>(spts, cellStart,
                                         ycf, yimg, cfh, imfh, featb);
  fing_kernel<<<N / 64, 256, 0, stream>>>(featb, fwh, fb, out);
}

// Round 10
// 161.772 us; speedup vs baseline: 1.1108x; 1.0278x over previous
//
#include <hip/hip_runtime.h>
#include <math.h>

#define N 16384
#define KNN 16
#define G 14
#define NCELL (G * G * G)  // 2744

typedef __attribute__((ext_vector_type(8))) short bf16x8;
typedef __attribute__((ext_vector_type(4))) float f32x4;
typedef unsigned short ushort_t;
typedef unsigned long long u64;

__device__ __forceinline__ float lrelu(float a) { return a > 0.f ? a : 0.01f * a; }

__device__ __forceinline__ ushort_t f2bf(float f) {
  unsigned u = __float_as_uint(f);
  u += 0x7FFF + ((u >> 16) & 1);
  return (ushort_t)(u >> 16);
}
__device__ __forceinline__ float bf2f(ushort_t h) {
  return __uint_as_float((unsigned)h << 16);
}
__device__ __forceinline__ float bflo(unsigned u) {  // low bf16 of a pair
  return __uint_as_float(u << 16);
}
__device__ __forceinline__ float bfhi(unsigned u) {  // high bf16 of a pair
  return __uint_as_float(u & 0xffff0000u);
}
__device__ __forceinline__ int lanerank(u64 mask) {
  return __builtin_amdgcn_mbcnt_hi((unsigned)(mask >> 32),
         __builtin_amdgcn_mbcnt_lo((unsigned)mask, 0));
}
__device__ __forceinline__ int cellof(float x) {
  int c = (int)(x * (float)G);
  return c < 0 ? 0 : (c > G - 1 ? G - 1 : c);
}
__device__ __forceinline__ int cellid(float x, float y, float z) {
  return (cellof(z) * G + cellof(y)) * G + cellof(x);
}

// ---------------------------------------------------------------------------
// prepw: prep (blocks 0..255, + cell histogram) + weight conv (256..603).
// NEW: point-MLP layer 2 (64->128) runs on MFMA with bf16 h/w (fp32 accum,
// fp32 bias). Removes the fp32 w2t LDS tile (34 KB) and its ~2 MB/block of
// ds_read_b128 traffic; LDS 55 -> ~35 KB (2 -> 4 blocks/CU).
// ---------------------------------------------------------------------------
#define PPB 64
#define HB_LD 72
__global__ __launch_bounds__(256) void prepw_kernel(
    const float* __restrict__ img, const float* __restrict__ cloud,
    const float* __restrict__ p1w, const float* __restrict__ p1b,
    const float* __restrict__ p2w, const float* __restrict__ p2b,
    const float* __restrict__ ps1w, const float* __restrict__ ps2w,
    const float* __restrict__ c1w, const float* __restrict__ c2w,
    const float* __restrict__ fw,
    float4* __restrict__ pts4, ushort_t* __restrict__ cfh,
    ushort_t* __restrict__ imfh,
    ushort_t* __restrict__ w1h, ushort_t* __restrict__ w2h,
    ushort_t* __restrict__ c1h, ushort_t* __restrict__ c2h,
    ushort_t* __restrict__ fwh, int* __restrict__ count) {
  int t = threadIdx.x;
  if (blockIdx.x >= 256) {
    int e = (blockIdx.x - 256) * 256 + t;
    if (e < 32768) w1h[e] = f2bf(ps1w[e]);
    else if (e < 65536) w2h[e - 32768] = f2bf(ps2w[e - 32768]);
    else if (e < 67584) c1h[e - 65536] = f2bf(c1w[e - 65536]);
    else if (e < 75776) c2h[e - 67584] = f2bf(c2w[e - 67584]);
    else if (e < 89088) {
      int e2 = e - 75776;
      if (e2 < 13312) fwh[e2] = f2bf(fw[e2]);
    }
    return;
  }
  __shared__ alignas(16) ushort_t w2b[128 * HB_LD];  // 18.4 KB bf16 weights
  __shared__ alignas(16) ushort_t hb[PPB * HB_LD];   // 9.2 KB bf16 hidden
  __shared__ alignas(16) float w1s[192];
  __shared__ alignas(16) float b1s[64];
  __shared__ alignas(16) float b2s[128];
  __shared__ alignas(16) ushort_t imt[PPB * 40];     // imfh staging (5 KB)
  __shared__ float ptmp[PPB * 3];
  __shared__ float psx[PPB], psy[PPB], psz[PPB];
  int pb = blockIdx.x * PPB;

  for (int e = t; e < 128 * 64; e += 256) {
    int ch = e >> 6, k = e & 63;
    w2b[ch * HB_LD + k] = f2bf(p2w[e]);
  }
  if (t < 192) w1s[t] = p1w[t];
  if (t < 64) b1s[t] = p1b[t];
  if (t < 128) b2s[t] = p2b[t];
  if (t < PPB * 3) ptmp[t] = cloud[pb * 3 + t];
  __syncthreads();
  if (t < PPB) {
    float x = ptmp[t * 3], y = ptmp[t * 3 + 1], z = ptmp[t * 3 + 2];
    psx[t] = x; psy[t] = y; psz[t] = z;
    pts4[pb + t] = make_float4(x, y, z, x * x + y * y + z * z);
    atomicAdd(&count[cellid(x, y, z)], 1);
  }
  for (int e = t; e < 32 * PPB; e += 256) {
    int c = e >> 6, p = e & 63;
    imt[p * 40 + c] = f2bf(img[(size_t)c * N + pb + p]);
  }
  __syncthreads();
  {  // coalesced imfh store: 4 lanes x uint4 = one 64B point-row
    int p = t >> 2, c8 = (t & 3) << 3;
    *(uint4*)&imfh[(size_t)(pb + p) * 32 + c8] =
        *(const uint4*)&imt[p * 40 + c8];
  }
  // layer 1 (3 -> 64), fp32 VALU, bf16 output rows [pt][k]
  for (int e = t; e < PPB * 64; e += 256) {
    int pt_ = e >> 6, ch = e & 63;
    float a = b1s[ch] + psx[pt_] * w1s[ch * 3] + psy[pt_] * w1s[ch * 3 + 1] +
              psz[pt_] * w1s[ch * 3 + 2];
    hb[pt_ * HB_LD + ch] = f2bf(lrelu(a));
  }
  __syncthreads();
  // layer 2 (64 -> 128) on MFMA: C[point][ch] = hb x w2b^T, fp32 accum+bias
  {
    int w = t >> 6, lane = t & 63;
    int col = lane & 15, quad = lane >> 4;
    f32x4 acc[2];
    acc[0] = (f32x4){0.f, 0.f, 0.f, 0.f};
    acc[1] = (f32x4){0.f, 0.f, 0.f, 0.f};
    for (int k0 = 0; k0 < 64; k0 += 32) {
      bf16x8 a[4];
      #pragma unroll
      for (int p = 0; p < 4; ++p)
        a[p] = *(const bf16x8*)&hb[(p * 16 + col) * HB_LD + k0 + quad * 8];
      // note: acc index must be [tt]; p-loop accumulates separate C rows
      #pragma unroll
      for (int tt = 0; tt < 2; ++tt) {
        int n = w * 32 + tt * 16 + col;
        bf16x8 b = *(const bf16x8*)&w2b[n * HB_LD + k0 + quad * 8];
        // 4 point-groups share acc? NO -- need acc per (tt,p).
        (void)n; (void)b;
      }
      (void)a;
      break;  // replaced below by full version
    }
    // full version with acc[tt][p]
    f32x4 accf[2][4];
    #pragma unroll
    for (int tt = 0; tt < 2; ++tt)
      #pragma unroll
      for (int p = 0; p < 4; ++p) accf[tt][p] = (f32x4){0.f, 0.f, 0.f, 0.f};
    for (int k0 = 0; k0 < 64; k0 += 32) {
      bf16x8 a[4];
      #pragma unroll
      for (int p = 0; p < 4; ++p)
        a[p] = *(const bf16x8*)&hb[(p * 16 + col) * HB_LD + k0 + quad * 8];
      #pragma unroll
      for (int tt = 0; tt < 2; ++tt) {
        int n = w * 32 + tt * 16 + col;
        bf16x8 b = *(const bf16x8*)&w2b[n * HB_LD + k0 + quad * 8];
        #pragma unroll
        for (int p = 0; p < 4; ++p)
          accf[tt][p] = __builtin_amdgcn_mfma_f32_16x16x32_bf16(a[p], b, accf[tt][p], 0, 0, 0);
      }
    }
    #pragma unroll
    for (int tt = 0; tt < 2; ++tt) {
      int n = w * 32 + tt * 16 + col;
      float bb = b2s[n];
      #pragma unroll
      for (int p = 0; p < 4; ++p)
        #pragma unroll
        for (int r = 0; r < 4; ++r)
          cfh[(size_t)(pb + p * 16 + quad * 4 + r) * 128 + n] =
              f2bf(accf[tt][p][r] + bb);
    }
  }
}

// ---------------------------------------------------------------------------
// scan: exclusive prefix over NCELL cell counts (1 block, 11 cells/thread).
// ---------------------------------------------------------------------------
__global__ __launch_bounds__(256) void scan_kernel(
    const int* __restrict__ count, int* __restrict__ cellStart,
    int* __restrict__ cellofs) {
  __shared__ int part[256];
  int t = threadIdx.x;
  int local[11];
  int s = 0;
  #pragma unroll
  for (int j = 0; j < 11; ++j) {
    int idx = t * 11 + j;
    local[j] = s;
    s += (idx < NCELL) ? count[idx] : 0;
  }
  part[t] = s;
  __syncthreads();
  for (int off = 1; off < 256; off <<= 1) {
    int v = (t >= off) ? part[t - off] : 0;
    __syncthreads();
    part[t] += v;
    __syncthreads();
  }
  int base = part[t] - s;
  #pragma unroll
  for (int j = 0; j < 11; ++j) {
    int idx = t * 11 + j;
    int v = base + local[j];
    if (idx < NCELL) { cellStart[idx] = v; cellofs[idx] = v; }
  }
  if (t == 255) cellStart[NCELL] = part[255];
}

// ---------------------------------------------------------------------------
// scatter: points into cell-sorted order; original index packed into .w.
// ---------------------------------------------------------------------------
__global__ __launch_bounds__(256) void scatter_kernel(
    const float4* __restrict__ pts4, int* __restrict__ cellofs,
    float4* __restrict__ spts) {
  int p = blockIdx.x * 256 + threadIdx.x;
  float4 v = pts4[p];
  int pos = atomicAdd(&cellofs[cellid(v.x, v.y, v.z)], 1);
  spts[pos] = make_float4(v.x, v.y, v.z, __int_as_float(p));
}

// ---------------------------------------------------------------------------
// ymlp: deduplicated dense MLPs (LDS-staged coalesced output stores).
// ---------------------------------------------------------------------------
#define NB_LD 136
#define S1_LD 264
#define NI_LD 40
#define H1_LD 72
__global__ __launch_bounds__(256) void ymlp_kernel(
    const ushort_t* __restrict__ cfh, const ushort_t* __restrict__ imfh,
    const ushort_t* __restrict__ w1h, const float* __restrict__ b1,
    const ushort_t* __restrict__ w2h, const float* __restrict__ b2,
    const ushort_t* __restrict__ c1h, const float* __restrict__ c1b,
    const ushort_t* __restrict__ c2h, const float* __restrict__ c2b,
    ushort_t* __restrict__ ycf, ushort_t* __restrict__ yimg) {
  __shared__ alignas(16) ushort_t nb[64 * NB_LD];
  __shared__ alignas(16) ushort_t s1[64 * S1_LD];
  int t = threadIdx.x;
  int w = t >> 6, lane = t & 63;
  int col = lane & 15, quad = lane >> 4;

  if (blockIdx.x < 256) {
    int pbase = blockIdx.x * 64;
    for (int e = t; e < 1024; e += 256) {
      int row = e >> 4, c8 = (e & 15) << 3;
      *(uint4*)&nb[row * NB_LD + c8] =
          *(const uint4*)&cfh[(size_t)(pbase + row) * 128 + c8];
    }
    __syncthreads();
    f32x4 acc1[4][4];
    #pragma unroll
    for (int tt = 0; tt < 4; ++tt)
      #pragma unroll
      for (int p = 0; p < 4; ++p) acc1[tt][p] = (f32x4){0.f, 0.f, 0.f, 0.f};
    for (int k0 = 0; k0 < 128; k0 += 32) {
      bf16x8 a[4];
      #pragma unroll
      for (int p = 0; p < 4; ++p)
        a[p] = *(const bf16x8*)&nb[(p * 16 + col) * NB_LD + k0 + quad * 8];
      #pragma unroll
      for (int tt = 0; tt < 4; ++tt) {
        int n = w * 64 + tt * 16 + col;
        bf16x8 b = *(const bf16x8*)&w1h[n * 128 + k0 + quad * 8];
        #pragma unroll
        for (int p = 0; p < 4; ++p)
          acc1[tt][p] = __builtin_amdgcn_mfma_f32_16x16x32_bf16(a[p], b, acc1[tt][p], 0, 0, 0);
      }
    }
    #pragma unroll
    for (int tt = 0; tt < 4; ++tt) {
      int n = w * 64 + tt * 16 + col;
      float bb = b1[n];
      #pragma unroll
      for (int p = 0; p < 4; ++p)
        #pragma unroll
        for (int r = 0; r < 4; ++r)
          s1[(p * 16 + quad * 4 + r) * S1_LD + n] = f2bf(lrelu(acc1[tt][p][r] + bb));
    }
    __syncthreads();   // all nb reads done; nb reusable as output staging
    f32x4 acc2[2][4];
    #pragma unroll
    for (int tt = 0; tt < 2; ++tt)
      #pragma unroll
      for (int p = 0; p < 4; ++p) acc2[tt][p] = (f32x4){0.f, 0.f, 0.f, 0.f};
    for (int k0 = 0; k0 < 256; k0 += 32) {
      bf16x8 a[4];
      #pragma unroll
      for (int p = 0; p < 4; ++p)
        a[p] = *(const bf16x8*)&s1[(p * 16 + col) * S1_LD + k0 + quad * 8];
      #pragma unroll
      for (int tt = 0; tt < 2; ++tt) {
        int n = w * 32 + tt * 16 + col;
        bf16x8 b = *(const bf16x8*)&w2h[n * 256 + k0 + quad * 8];
        #pragma unroll
        for (int p = 0; p < 4; ++p)
          acc2[tt][p] = __builtin_amdgcn_mfma_f32_16x16x32_bf16(a[p], b, acc2[tt][p], 0, 0, 0);
      }
    }
    #pragma unroll
    for (int tt = 0; tt < 2; ++tt) {
      int n = w * 32 + tt * 16 + col;
      float bb = b2[n];
      #pragma unroll
      for (int p = 0; p < 4; ++p)
        #pragma unroll
        for (int r = 0; r < 4; ++r)
          nb[(p * 16 + quad * 4 + r) * NB_LD + n] = f2bf(acc2[tt][p][r] + bb);
    }
    __syncthreads();
    for (int e = t; e < 1024; e += 256) {
      int row = e >> 4, c8 = (e & 15) << 3;
      *(uint4*)&ycf[(size_t)(pbase + row) * 128 + c8] =
          *(const uint4*)&nb[row * NB_LD + c8];
    }
  } else {
    int pbase = (blockIdx.x - 256) * 64;
    ushort_t* nbi = nb;
    ushort_t* h1 = s1;
    {
      int row = t >> 2, c8 = (t & 3) << 3;
      *(uint4*)&nbi[row * NI_LD + c8] =
          *(const uint4*)&imfh[(size_t)(pbase + row) * 32 + c8];
    }
    __syncthreads();
    {
      f32x4 accA[4];
      #pragma unroll
      for (int p = 0; p < 4; ++p) accA[p] = (f32x4){0.f, 0.f, 0.f, 0.f};
      int n = w * 16 + col;
      bf16x8 b = *(const bf16x8*)&c1h[n * 32 + quad * 8];
      #pragma unroll
      for (int p = 0; p < 4; ++p) {
        bf16x8 a = *(const bf16x8*)&nbi[(p * 16 + col) * NI_LD + quad * 8];
        accA[p] = __builtin_amdgcn_mfma_f32_16x16x32_bf16(a, b, accA[p], 0, 0, 0);
      }
      __syncthreads();   // all nbi reads done; nb reusable for output staging
      float bb = c1b[n];
      #pragma unroll
      for (int p = 0; p < 4; ++p)
        #pragma unroll
        for (int r = 0; r < 4; ++r)
          h1[(p * 16 + quad * 4 + r) * H1_LD + n] = f2bf(lrelu(accA[p][r] + bb));
    }
    __syncthreads();
    f32x4 acc2[2][4];
    #pragma unroll
    for (int tt = 0; tt < 2; ++tt)
      #pragma unroll
      for (int p = 0; p < 4; ++p) acc2[tt][p] = (f32x4){0.f, 0.f, 0.f, 0.f};
    for (int k0 = 0; k0 < 64; k0 += 32) {
      bf16x8 a[4];
      #pragma unroll
      for (int p = 0; p < 4; ++p)
        a[p] = *(const bf16x8*)&h1[(p * 16 + col) * H1_LD + k0 + quad * 8];
      #pragma unroll
      for (int tt = 0; tt < 2; ++tt) {
        int n = w * 32 + tt * 16 + col;
        bf16x8 b = *(const bf16x8*)&c2h[n * 64 + k0 + quad * 8];
        #pragma unroll
        for (int p = 0; p < 4; ++p)
          acc2[tt][p] = __builtin_amdgcn_mfma_f32_16x16x32_bf16(a[p], b, acc2[tt][p], 0, 0, 0);
      }
    }
    #pragma unroll
    for (int tt = 0; tt < 2; ++tt) {
      int n = w * 32 + tt * 16 + col;
      float bb = c2b[n];
      #pragma unroll
      for (int p = 0; p < 4; ++p)
        #pragma unroll
        for (int r = 0; r < 4; ++r)
          nb[(p * 16 + quad * 4 + r) * NB_LD + n] = f2bf(acc2[tt][p][r] + bb);
    }
    __syncthreads();
    for (int e = t; e < 1024; e += 256) {
      int row = e >> 4, c8 = (e & 15) << 3;
      *(uint4*)&yimg[(size_t)(pbase + row) * 128 + c8] =
          *(const uint4*)&nb[row * NB_LD + c8];
    }
  }
}

// ---------------------------------------------------------------------------
// knng: grid KNN (exact top-16) fused with gather-max + feat pack.
// Cell-level trim + in-lane gather-max (R9).
// ---------------------------------------------------------------------------
__device__ __forceinline__ float tadj(float tau, float qw) {
  float a = tau - qw;
  return a + fabsf(a) * 2e-7f + 1e-35f;
}

template <int NS>
__device__ __forceinline__ u64 selimpl(u64* buf, int cnt, int lane,
                                       float& tau) {
  u64 v[NS];
  unsigned k[NS];
  #pragma unroll
  for (int s = 0; s < NS; ++s) {
    int idx = s * 64 + lane;
    v[s] = (idx < cnt) ? buf[idx] : ~0ULL;
    k[s] = (unsigned)(v[s] >> 32);
  }
  // phase 1: m = 16th smallest d2-bits (sentinel 0xFFFFFFFF sorts last)
  unsigned m = 0u;
  #pragma unroll
  for (int b = 31; b >= 0; --b) {
    unsigned probe = m | (1u << b);
    int c = 0;
    #pragma unroll
    for (int s = 0; s < NS; ++s) c += __popcll(__ballot(k[s] < probe));
    if (c < KNN) m = probe;
  }
  // phase 2: tie-break on oid among keys equal to m (rare).
  int c_lt = 0, ne = 0;
  bool e[NS];
  #pragma unroll
  for (int s = 0; s < NS; ++s) {
    c_lt += __popcll(__ballot(k[s] < m));
    e[s] = (k[s] == m);
    ne += __popcll(__ballot(e[s]));
  }
  int need_eq = KNN - c_lt;
  unsigned m2 = 0xFFFFFFFFu;
  if (ne != need_eq) {
    m2 = 0u;
    #pragma unroll
    for (int b = 13; b >= 0; --b) {
      unsigned probe = m2 | (1u << b);
      int c = 0;
      #pragma unroll
      for (int s = 0; s < NS; ++s)
        c += __popcll(__ballot(e[s] && ((unsigned)v[s] < probe)));
      if (c < need_eq) m2 = probe;
    }
  }
  // compact the exact top-16 set to buf[0..15]
  int base = 0;
  #pragma unroll
  for (int s = 0; s < NS; ++s) {
    bool sel = (k[s] < m) || (e[s] && ((unsigned)v[s] <= m2));
    u64 msk = __ballot(sel);
    if (sel) buf[base + lanerank(msk)] = v[s];
    base += __popcll(msk);
  }
  tau = __uint_as_float(m);
  if (!(tau == tau)) tau = INFINITY;  // cnt<16: sentinel bits are NaN
  return buf[lane & 15];
}

__device__ __forceinline__ u64 select16(u64* buf, int& cnt, int lane,
                                        float& tau) {
  u64 r = (cnt <= 64) ? selimpl<1>(buf, cnt, lane, tau)
                      : selimpl<2>(buf, cnt, lane, tau);
  cnt = KNN;
  return r;
}

__device__ __forceinline__ float truethr(float tau, float qw) {
  // conservative true-distance^2 threshold matching tadj's slack
  return tau + (tau + qw) * 3e-7f + 1e-30f;
}

__global__ __launch_bounds__(256) void knng_kernel(
    const float4* __restrict__ spts, const int* __restrict__ cellStart,
    const ushort_t* __restrict__ ycf, const ushort_t* __restrict__ yimg,
    const ushort_t* __restrict__ cfh, const ushort_t* __restrict__ imfh,
    ushort_t* __restrict__ featb) {
  __shared__ u64 sbuf[4][128];                 // 4 KB (only LDS left)
  int t = threadIdx.x;
  int wv = t >> 6, lane = t & 63;
  // XCD-chunked swizzle: each XCD's L2 holds one spatial slab.
  int sblk = (blockIdx.x & 7) * 512 + (blockIdx.x >> 3);
  int sid = sblk * 4 + wv;
  u64* buf = sbuf[wv];

  float4 q = spts[sid];                        // cell-sorted query
  int pid = __float_as_int(q.w);               // original point index
  float qw = fmaf(q.z, q.z, fmaf(q.y, q.y, q.x * q.x));
  float q2x = -2.f * q.x, q2y = -2.f * q.y, q2z = -2.f * q.z;
  int cx = cellof(q.x), cy = cellof(q.y), cz = cellof(q.z);

  // a-priori pruning radius: ~35 expected points in the clipped ball.
  float tau;
  {
    const float r0 = 0.0758f;  // (35*3/(4*pi*N))^(1/3) w/o clip
    float rr = r0;
    #pragma unroll
    for (int it = 0; it < 2; ++it) {
      float fx = (fminf(q.x + rr, 1.f) - fmaxf(q.x - rr, 0.f)) * (0.5f / rr);
      float fy = (fminf(q.y + rr, 1.f) - fmaxf(q.y - rr, 0.f)) * (0.5f / rr);
      float fz = (fminf(q.z + rr, 1.f) - fmaxf(q.z - rr, 0.f)) * (0.5f / rr);
      rr = r0 * __powf(fx * fy * fz, -0.333333f);
    }
    rr *= 1.05f;
    tau = rr * rr;
  }
  u64 vres;

  for (int r = 1;; ++r) {
    int lx = max(cx - r, 0), hx = min(cx + r, G - 1);
    int ly = max(cy - r, 0), hy = min(cy + r, G - 1);
    int lz = max(cz - r, 0), hz = min(cz + r, G - 1);
    int ny = hy - ly + 1, nz = hz - lz + 1, nruns = ny * nz;
    int cnt = 0;
    float ta = tadj(tau, qw);
    float tt = truethr(tau, qw);

    for (int rb = 0; rb < nruns; rb += 64) {
      int ln = rb + lane;
      int rs = 0, rc = 0;
      if (ln < nruns) {
        int z = lz + ln / ny, y = ly + ln % ny;
        // slab min-dist^2 trim (conservative: 1e-6 boundary shave)
        float loY = (float)y * (1.f / G), hiY = loY + (1.f / G);
        float loZ = (float)z * (1.f / G), hiZ = loZ + (1.f / G);
        float dy = fmaxf(fmaxf(loY - q.y, q.y - hiY) - 1e-6f, 0.f);
        float dz = fmaxf(fmaxf(loZ - q.z, q.z - hiZ) - 1e-6f, 0.f);
        float rem = tt - dy * dy - dz * dz;
        if (rem >= 0.f) {
          float rad = fminf(sqrtf(rem) + 1e-6f, 2.f);
          int xlo = max(lx, cellof(q.x - rad));
          int xhi = min(hx, cellof(q.x + rad));
          int row = (z * G + y) * G;
          rs = cellStart[row + xlo];
          rc = cellStart[row + xhi + 1] - rs;
        }
      }
      int nr = nruns - rb; nr = nr > 64 ? 64 : nr;
      int off = rc;
      #pragma unroll
      for (int d = 1; d < 64; d <<= 1) {
        int v = __shfl_up(off, d);
        if (lane >= d) off += v;
      }
      int T = __shfl(off, 63);
      off -= rc;

      for (int cb = 0; cb < T; cb += 64) {
        int rk = cb + lane;
        int j = 0;
        if (nr <= 16) {
          #pragma unroll
          for (int step = 8; step; step >>= 1) {
            int nj = j + step;
            if (__shfl(off, nj) <= rk) j = nj;
          }
        } else if (nr <= 32) {
          #pragma unroll
          for (int step = 16; step; step >>= 1) {
            int nj = j + step;
            if (__shfl(off, nj) <= rk) j = nj;
          }
        } else {
          #pragma unroll
          for (int step = 32; step; step >>= 1) {
            int nj = j + step;
            if (__shfl(off, nj) <= rk) j = nj;
          }
        }
        int src = __shfl(rs, j) + rk - __shfl(off, j);
        bool valid = rk < T;
        if (!valid) src = 0;
        float4 c = spts[src];
        float cw = fmaf(c.z, c.z, fmaf(c.y, c.y, c.x * c.x));
        float d2 = fmaf(q2x, c.x, fmaf(q2y, c.y, fmaf(q2z, c.z, cw)));
        bool pass = valid && (d2 <= ta);
        u64 mask = __ballot(pass);
        if (mask) {
          if (pass) {
            int oid = __float_as_int(c.w);
            u64 key = ((u64)__float_as_uint(fmaxf(d2 + qw, 0.f)) << 32) | (unsigned)oid;
            buf[cnt + lanerank(mask)] = key;
          }
          cnt += __popcll(mask);
          if (cnt > 64) {  // keep room for one more 64-append (buffer 128)
            select16(buf, cnt, lane, tau);
            ta = tadj(tau, qw);
            tt = truethr(tau, qw);
          }
        }
      }
    }
    u64 v = select16(buf, cnt, lane, tau);
    float cl = INFINITY;
    if (lx > 0)     cl = fminf(cl, q.x - (float)lx / (float)G);
    if (hx < G - 1) cl = fminf(cl, (float)(hx + 1) / (float)G - q.x);
    if (ly > 0)     cl = fminf(cl, q.y - (float)ly / (float)G);
    if (hy < G - 1) cl = fminf(cl, (float)(hy + 1) / (float)G - q.y);
    if (lz > 0)     cl = fminf(cl, q.z - (float)lz / (float)G);
    if (hz < G - 1) cl = fminf(cl, (float)(hz + 1) / (float)G - q.z);
    bool full = (lx == 0 && hx == G - 1 && ly == 0 && hy == G - 1 &&
                 lz == 0 && hz == G - 1);
    if (full || tau * 1.00002f <= cl * cl) { vres = v; break; }
  }

  // ---- softmax weights; dist recovered from key's high word (=|q-c|^2) ----
  int myid = (lane < KNN) ? (int)(unsigned)(vres & 0xffffffffULL) : 0;
  float mywg = 0.f;
  {
    float dd = __uint_as_float((unsigned)(vres >> 32));
    float dist = sqrtf(fmaxf(dd, 1e-12f));
    float md = (lane < KNN) ? dist : INFINITY;
    #pragma unroll
    for (int off = 1; off < KNN; off <<= 1) md = fminf(md, __shfl_xor(md, off));
    float e = __expf(md - dist);
    float se = (lane < KNN) ? e : 0.f;
    #pragma unroll
    for (int off = 1; off < KNN; off <<= 1) se += __shfl_xor(se, off);
    mywg = e / se;  // valid on lanes < 16
  }

  // ---- in-lane gather-max: lane owns channels (2*lane, 2*lane+1) ----
  float A0 = -INFINITY, A1 = -INFINITY, B0 = -INFINITY, B1 = -INFINITY;
  size_t coff = (size_t)(lane * 2);
  #pragma unroll
  for (int k = 0; k < KNN; ++k) {
    int id = __shfl(myid, k);      // constant lane -> v_readlane
    float wg = __shfl(mywg, k);
    unsigned v = *(const unsigned*)&ycf[(size_t)id * 128 + coff];
    unsigned u = *(const unsigned*)&yimg[(size_t)id * 128 + coff];
    A0 = fmaxf(A0, bflo(v) * wg);
    A1 = fmaxf(A1, bfhi(v) * wg);
    B0 = fmaxf(B0, bflo(u) * wg);
    B1 = fmaxf(B1, bfhi(u) * wg);
  }
  // ---- featb row: 4 direct u32 stores build the 832B bf16 row ----
  unsigned* frow = (unsigned*)(featb + (size_t)pid * 416);
  frow[lane] = (unsigned)f2bf(lrelu(A0)) | ((unsigned)f2bf(lrelu(A1)) << 16);
  frow[80 + lane] = (unsigned)f2bf(lrelu(B0)) | ((unsigned)f2bf(lrelu(B1)) << 16);
  if (lane < 16) {  // imf pairs 64..79 (channels 0..31)
    unsigned vi = *(const unsigned*)&imfh[(size_t)pid * 32 + lane * 2];
    frow[64 + lane] =
        (unsigned)f2bf(lrelu(bflo(vi))) | ((unsigned)f2bf(lrelu(bfhi(vi))) << 16);
  }
  unsigned vcf = *(const unsigned*)&cfh[(size_t)pid * 128 + coff];
  frow[144 + lane] =
      (unsigned)f2bf(lrelu(bflo(vcf))) | ((unsigned)f2bf(lrelu(bfhi(vcf))) << 16);
}

// ---------------------------------------------------------------------------
// fing: final GEMM on MFMA with fused transpose. C = fwh[32][416] x
// featb[pt][416]^T -> store directly to out[ch][N] (64B segments).
// ---------------------------------------------------------------------------
__global__ __launch_bounds__(256) void fing_kernel(
    const ushort_t* __restrict__ featb, const ushort_t* __restrict__ fwh,
    const float* __restrict__ fb, float* __restrict__ out) {
  int t = threadIdx.x;
  int wv = t >> 6, lane = t & 63;
  int col = lane & 15, quad = lane >> 4;
  int pbase = blockIdx.x * 64 + wv * 16;  // this wave's 16 points
  f32x4 acc[2];
  acc[0] = (f32x4){0.f, 0.f, 0.f, 0.f};
  acc[1] = (f32x4){0.f, 0.f, 0.f, 0.f};
  for (int k0 = 0; k0 < 416; k0 += 32) {
    bf16x8 b = *(const bf16x8*)&featb[(size_t)(pbase + col) * 416 + k0 + quad * 8];
    #pragma unroll
    for (int tt = 0; tt < 2; ++tt) {
      bf16x8 a = *(const bf16x8*)&fwh[(tt * 16 + col) * 416 + k0 + quad * 8];
      acc[tt] = __builtin_amdgcn_mfma_f32_16x16x32_bf16(a, b, acc[tt], 0, 0, 0);
    }
  }
  #pragma unroll
  for (int tt = 0; tt < 2; ++tt) {
    #pragma unroll
    for (int r = 0; r < 4; ++r) {
      int ch = tt * 16 + quad * 4 + r;
      out[(size_t)ch * N + pbase + col] = acc[tt][r] + fb[ch];
    }
  }
}

// ---------------------------------------------------------------------------
extern "C" void kernel_launch(void* const* d_in, const int* in_sizes, int n_in,
                              void* d_out, int out_size, void* d_ws, size_t ws_size,
                              hipStream_t stream) {
  const float* img   = (const float*)d_in[0];
  const float* cloud = (const float*)d_in[1];
  const float* c1w   = (const float*)d_in[2];
  const float* c1b   = (const float*)d_in[3];
  const float* c2w   = (const float*)d_in[4];
  const float* c2b   = (const float*)d_in[5];
  const float* ps1w  = (const float*)d_in[6];
  const float* ps1b  = (const float*)d_in[7];
  const float* ps2w  = (const float*)d_in[8];
  const float* ps2b  = (const float*)d_in[9];
  const float* p1w   = (const float*)d_in[10];
  const float* p1b   = (const float*)d_in[11];
  const float* p2w   = (const float*)d_in[12];
  const float* p2b   = (const float*)d_in[13];
  const float* fw    = (const float*)d_in[14];
  const float* fb    = (const float*)d_in[15];
  float* out = (float*)d_out;

  char* ws = (char*)d_ws;
  float4*   pts4  = (float4*)(ws + 0);             // 256 KB   -> 262144
  ushort_t* cfh   = (ushort_t*)(ws + 262144);      // 4 MB     -> 4456448
  ushort_t* imfh  = (ushort_t*)(ws + 4456448);     // 1 MB     -> 5505024
  ushort_t* w1h   = (ushort_t*)(ws + 5505024);     // 64 KB    -> 5570560
  ushort_t* w2h   = (ushort_t*)(ws + 5570560);     // 64 KB    -> 5636096
  ushort_t* c1h   = (ushort_t*)(ws + 5636096);     // 4 KB     -> 5640192
  ushort_t* c2h   = (ushort_t*)(ws + 5640192);     // 16 KB    -> 5656576
  ushort_t* ycf   = (ushort_t*)(ws + 5656576);     // 4 MB     -> 9850880
  ushort_t* yimg  = (ushort_t*)(ws + 9850880);     // 4 MB     -> 14045184
  float4*   spts  = (float4*)(ws + 14045184);      // 256 KB   -> 14307328
  int*      cellStart = (int*)(ws + 14307328);     // 16 KB    -> 14323712
  int*      cellofs   = (int*)(ws + 14323712);     // 16 KB    -> 14339840
  int*      count     = (int*)(ws + 14339840);     // 16 KB    -> 14356224
  ushort_t* fwh       = (ushort_t*)(ws + 14356224);// 32 KB    -> 14388992
  ushort_t* featb     = (ushort_t*)(ws + 14388992);// 13.6 MB  -> 28020480

  hipMemsetAsync(count, 0, NCELL * sizeof(int), stream);
  prepw_kernel<<<604, 256, 0, stream>>>(img, cloud, p1w, p1b, p2w, p2b,
                                        ps1w, ps2w, c1w, c2w, fw,
                                        pts4, cfh, imfh, w1h, w2h, c1h, c2h,
                                        fwh, count);
  scan_kernel<<<1, 256, 0, stream>>>(count, cellStart, cellofs);
  scatter_kernel<<<64, 256, 0, stream>>>(pts4, cellofs, spts);
  ymlp_kernel<<<512, 256, 0, stream>>>(cfh, imfh, w1h, ps1b, w2h, ps2b,
                                       c1h, c1b, c2h, c2b, ycf, yimg);
  knng_kernel<<<N / 4, 256, 0, stream>>>(spts, cellStart,
                                         ycf, yimg, cfh, imfh, featb);
  fing_kernel<<<N / 64, 256, 0, stream>>>(featb, fwh, fb, out);
}

// Round 11
// 158.658 us; speedup vs baseline: 1.1326x; 1.0196x over previous
//
#include <hip/hip_runtime.h>
#include <math.h>

#define N 16384
#define KNN 16
#define G 14
#define NCELL (G * G * G)  // 2744

typedef __attribute__((ext_vector_type(8))) short bf16x8;
typedef __attribute__((ext_vector_type(4))) float f32x4;
typedef unsigned short ushort_t;
typedef unsigned long long u64;

__device__ __forceinline__ float lrelu(float a) { return a > 0.f ? a : 0.01f * a; }

__device__ __forceinline__ ushort_t f2bf(float f) {
  unsigned u = __float_as_uint(f);
  u += 0x7FFF + ((u >> 16) & 1);
  return (ushort_t)(u >> 16);
}
__device__ __forceinline__ float bf2f(ushort_t h) {
  return __uint_as_float((unsigned)h << 16);
}
__device__ __forceinline__ float bflo(unsigned u) {  // low bf16 of a pair
  return __uint_as_float(u << 16);
}
__device__ __forceinline__ float bfhi(unsigned u) {  // high bf16 of a pair
  return __uint_as_float(u & 0xffff0000u);
}
__device__ __forceinline__ int lanerank(u64 mask) {
  return __builtin_amdgcn_mbcnt_hi((unsigned)(mask >> 32),
         __builtin_amdgcn_mbcnt_lo((unsigned)mask, 0));
}
__device__ __forceinline__ int cellof(float x) {
  int c = (int)(x * (float)G);
  return c < 0 ? 0 : (c > G - 1 ? G - 1 : c);
}
__device__ __forceinline__ int cellid(float x, float y, float z) {
  return (cellof(z) * G + cellof(y)) * G + cellof(x);
}

// ---------------------------------------------------------------------------
// wconv: weight conversions to bf16 (no deps; runs before prepf).
// ---------------------------------------------------------------------------
__global__ __launch_bounds__(256) void wconv_kernel(
    const float* __restrict__ ps1w, const float* __restrict__ ps2w,
    const float* __restrict__ c1w, const float* __restrict__ c2w,
    const float* __restrict__ fw,
    ushort_t* __restrict__ w1h, ushort_t* __restrict__ w2h,
    ushort_t* __restrict__ c1h, ushort_t* __restrict__ c2h,
    ushort_t* __restrict__ fwh) {
  int e = blockIdx.x * 256 + threadIdx.x;
  if (e < 32768) w1h[e] = f2bf(ps1w[e]);
  else if (e < 65536) w2h[e - 32768] = f2bf(ps2w[e - 32768]);
  else if (e < 67584) c1h[e - 65536] = f2bf(c1w[e - 65536]);
  else if (e < 75776) c2h[e - 67584] = f2bf(c2w[e - 67584]);
  else if (e < 89088) {
    int e2 = e - 75776;
    if (e2 < 13312) fwh[e2] = f2bf(fw[e2]);
  }
}

// ---------------------------------------------------------------------------
// prepf: FUSED prep + point-MLP (MFMA) + ymlp (both branches). Per block:
// 64 points -> pts4/hist/imfh, layer1+layer2 (cfh into LDS nb + coalesced
// global store), then ycf = MLP(cfh) and yimg = MLP(imfh) consumed from LDS.
// s1 (33.8 KB) aliases {w2b+hb} (dead after layer-2 MFMA; barrier-separated).
// ---------------------------------------------------------------------------
#define PPB 64
#define HB_LD 72
#define NB_LD 136
#define S1_LD 264
#define H1_LD 72
__global__ __launch_bounds__(256) void prepf_kernel(
    const float* __restrict__ img, const float* __restrict__ cloud,
    const float* __restrict__ p1w, const float* __restrict__ p1b,
    const float* __restrict__ p2w, const float* __restrict__ p2b,
    const ushort_t* __restrict__ w1h, const float* __restrict__ b1,
    const ushort_t* __restrict__ w2h, const float* __restrict__ b2,
    const ushort_t* __restrict__ c1h, const float* __restrict__ c1b,
    const ushort_t* __restrict__ c2h, const float* __restrict__ c2b,
    float4* __restrict__ pts4, ushort_t* __restrict__ cfh,
    ushort_t* __restrict__ imfh,
    ushort_t* __restrict__ ycf, ushort_t* __restrict__ yimg,
    int* __restrict__ count) {
  __shared__ alignas(16) char pool[64 * S1_LD * 2];     // 33792 B
  ushort_t* s1  = (ushort_t*)pool;                      // 64 x S1_LD
  ushort_t* w2b = (ushort_t*)pool;                      // 128 x HB_LD (18432 B)
  ushort_t* hb  = (ushort_t*)(pool + 128 * HB_LD * 2);  // 64 x HB_LD (9216 B)
  __shared__ alignas(16) ushort_t nb[64 * NB_LD];       // 17408 B
  __shared__ alignas(16) ushort_t imt[64 * 40];         // 5120 B
  __shared__ alignas(16) float w1s[192];
  __shared__ alignas(16) float b1s[64];
  __shared__ alignas(16) float b2s[128];
  __shared__ float ptmp[PPB * 3];
  __shared__ float psx[PPB], psy[PPB], psz[PPB];
  int t = threadIdx.x;
  int w = t >> 6, lane = t & 63;
  int col = lane & 15, quad = lane >> 4;
  int pb = blockIdx.x * PPB;

  // ---- phase A: prep + layer1 + layer2 (MFMA) ----
  for (int e = t; e < 128 * 64; e += 256) {
    int ch = e >> 6, k = e & 63;
    w2b[ch * HB_LD + k] = f2bf(p2w[e]);
  }
  if (t < 192) w1s[t] = p1w[t];
  if (t < 64) b1s[t] = p1b[t];
  if (t < 128) b2s[t] = p2b[t];
  if (t < PPB * 3) ptmp[t] = cloud[pb * 3 + t];
  __syncthreads();
  if (t < PPB) {
    float x = ptmp[t * 3], y = ptmp[t * 3 + 1], z = ptmp[t * 3 + 2];
    psx[t] = x; psy[t] = y; psz[t] = z;
    pts4[pb + t] = make_float4(x, y, z, x * x + y * y + z * z);
    atomicAdd(&count[cellid(x, y, z)], 1);
  }
  for (int e = t; e < 32 * PPB; e += 256) {
    int c = e >> 6, p = e & 63;
    imt[p * 40 + c] = f2bf(img[(size_t)c * N + pb + p]);
  }
  for (int e = t; e < PPB * 64; e += 256) {
    int pt_ = e >> 6, ch = e & 63;
    // depends only on this thread's earlier ptmp? no -- psx written by t<64.
    // ensure psx/psy/psz visible:
    (void)0;
  }
  __syncthreads();
  {  // coalesced imfh store: 4 lanes x uint4 = one 64B point-row
    int p = t >> 2, c8 = (t & 3) << 3;
    *(uint4*)&imfh[(size_t)(pb + p) * 32 + c8] =
        *(const uint4*)&imt[p * 40 + c8];
  }
  // layer 1 (3 -> 64), fp32 VALU, bf16 rows [pt][k]
  for (int e = t; e < PPB * 64; e += 256) {
    int pt_ = e >> 6, ch = e & 63;
    float a = b1s[ch] + psx[pt_] * w1s[ch * 3] + psy[pt_] * w1s[ch * 3 + 1] +
              psz[pt_] * w1s[ch * 3 + 2];
    hb[pt_ * HB_LD + ch] = f2bf(lrelu(a));
  }
  __syncthreads();
  // layer 2 (64 -> 128) on MFMA -> nb staging (ymlp layout)
  {
    f32x4 accf[2][4];
    #pragma unroll
    for (int tt = 0; tt < 2; ++tt)
      #pragma unroll
      for (int p = 0; p < 4; ++p) accf[tt][p] = (f32x4){0.f, 0.f, 0.f, 0.f};
    for (int k0 = 0; k0 < 64; k0 += 32) {
      bf16x8 a[4];
      #pragma unroll
      for (int p = 0; p < 4; ++p)
        a[p] = *(const bf16x8*)&hb[(p * 16 + col) * HB_LD + k0 + quad * 8];
      #pragma unroll
      for (int tt = 0; tt < 2; ++tt) {
        int n = w * 32 + tt * 16 + col;
        bf16x8 b = *(const bf16x8*)&w2b[n * HB_LD + k0 + quad * 8];
        #pragma unroll
        for (int p = 0; p < 4; ++p)
          accf[tt][p] = __builtin_amdgcn_mfma_f32_16x16x32_bf16(a[p], b, accf[tt][p], 0, 0, 0);
      }
    }
    #pragma unroll
    for (int tt = 0; tt < 2; ++tt) {
      int n = w * 32 + tt * 16 + col;
      float bb = b2s[n];
      #pragma unroll
      for (int p = 0; p < 4; ++p)
        #pragma unroll
        for (int r = 0; r < 4; ++r)
          nb[(p * 16 + quad * 4 + r) * NB_LD + n] = f2bf(accf[tt][p][r] + bb);
    }
  }
  __syncthreads();   // nb complete; hb/w2b dead -> s1 region reusable
  // coalesced cfh store from nb
  for (int e = t; e < 1024; e += 256) {
    int row = e >> 4, c8 = (e & 15) << 3;
    *(uint4*)&cfh[(size_t)(pb + row) * 128 + c8] =
        *(const uint4*)&nb[row * NB_LD + c8];
  }

  // ---- phase B: ycf = MLP(cfh tile in nb): 128 -> 256 lrelu -> 128 ----
  {
    f32x4 acc1[4][4];
    #pragma unroll
    for (int tt = 0; tt < 4; ++tt)
      #pragma unroll
      for (int p = 0; p < 4; ++p) acc1[tt][p] = (f32x4){0.f, 0.f, 0.f, 0.f};
    for (int k0 = 0; k0 < 128; k0 += 32) {
      bf16x8 a[4];
      #pragma unroll
      for (int p = 0; p < 4; ++p)
        a[p] = *(const bf16x8*)&nb[(p * 16 + col) * NB_LD + k0 + quad * 8];
      #pragma unroll
      for (int tt = 0; tt < 4; ++tt) {
        int n = w * 64 + tt * 16 + col;
        bf16x8 b = *(const bf16x8*)&w1h[n * 128 + k0 + quad * 8];
        #pragma unroll
        for (int p = 0; p < 4; ++p)
          acc1[tt][p] = __builtin_amdgcn_mfma_f32_16x16x32_bf16(a[p], b, acc1[tt][p], 0, 0, 0);
      }
    }
    #pragma unroll
    for (int tt = 0; tt < 4; ++tt) {
      int n = w * 64 + tt * 16 + col;
      float bb = b1[n];
      #pragma unroll
      for (int p = 0; p < 4; ++p)
        #pragma unroll
        for (int r = 0; r < 4; ++r)
          s1[(p * 16 + quad * 4 + r) * S1_LD + n] = f2bf(lrelu(acc1[tt][p][r] + bb));
    }
    __syncthreads();
    f32x4 acc2[2][4];
    #pragma unroll
    for (int tt = 0; tt < 2; ++tt)
      #pragma unroll
      for (int p = 0; p < 4; ++p) acc2[tt][p] = (f32x4){0.f, 0.f, 0.f, 0.f};
    for (int k0 = 0; k0 < 256; k0 += 32) {
      bf16x8 a[4];
      #pragma unroll
      for (int p = 0; p < 4; ++p)
        a[p] = *(const bf16x8*)&s1[(p * 16 + col) * S1_LD + k0 + quad * 8];
      #pragma unroll
      for (int tt = 0; tt < 2; ++tt) {
        int n = w * 32 + tt * 16 + col;
        bf16x8 b = *(const bf16x8*)&w2h[n * 256 + k0 + quad * 8];
        #pragma unroll
        for (int p = 0; p < 4; ++p)
          acc2[tt][p] = __builtin_amdgcn_mfma_f32_16x16x32_bf16(a[p], b, acc2[tt][p], 0, 0, 0);
      }
    }
    __syncthreads();   // nb reads (cfh store + layer1) done -> nb reusable
    #pragma unroll
    for (int tt = 0; tt < 2; ++tt) {
      int n = w * 32 + tt * 16 + col;
      float bb = b2[n];
      #pragma unroll
      for (int p = 0; p < 4; ++p)
        #pragma unroll
        for (int r = 0; r < 4; ++r)
          nb[(p * 16 + quad * 4 + r) * NB_LD + n] = f2bf(acc2[tt][p][r] + bb);
    }
    __syncthreads();
    for (int e = t; e < 1024; e += 256) {
      int row = e >> 4, c8 = (e & 15) << 3;
      *(uint4*)&ycf[(size_t)(pb + row) * 128 + c8] =
          *(const uint4*)&nb[row * NB_LD + c8];
    }
  }

  // ---- phase C: yimg = MLP(imfh tile in imt): 32 -> 64 lrelu -> 128 ----
  {
    ushort_t* h1 = s1;  // reuse s1 region with H1_LD stride
    f32x4 accA[4];
    #pragma unroll
    for (int p = 0; p < 4; ++p) accA[p] = (f32x4){0.f, 0.f, 0.f, 0.f};
    int n1 = w * 16 + col;
    bf16x8 bA = *(const bf16x8*)&c1h[n1 * 32 + quad * 8];
    #pragma unroll
    for (int p = 0; p < 4; ++p) {
      bf16x8 a = *(const bf16x8*)&imt[(p * 16 + col) * 40 + quad * 8];
      accA[p] = __builtin_amdgcn_mfma_f32_16x16x32_bf16(a, bA, accA[p], 0, 0, 0);
    }
    __syncthreads();   // s1 reads (phase B acc2) done -> h1 writes safe
    float bbA = c1b[n1];
    #pragma unroll
    for (int p = 0; p < 4; ++p)
      #pragma unroll
      for (int r = 0; r < 4; ++r)
        h1[(p * 16 + quad * 4 + r) * H1_LD + n1] = f2bf(lrelu(accA[p][r] + bbA));
    __syncthreads();
    f32x4 acc2[2][4];
    #pragma unroll
    for (int tt = 0; tt < 2; ++tt)
      #pragma unroll
      for (int p = 0; p < 4; ++p) acc2[tt][p] = (f32x4){0.f, 0.f, 0.f, 0.f};
    for (int k0 = 0; k0 < 64; k0 += 32) {
      bf16x8 a[4];
      #pragma unroll
      for (int p = 0; p < 4; ++p)
        a[p] = *(const bf16x8*)&h1[(p * 16 + col) * H1_LD + k0 + quad * 8];
      #pragma unroll
      for (int tt = 0; tt < 2; ++tt) {
        int n = w * 32 + tt * 16 + col;
        bf16x8 b = *(const bf16x8*)&c2h[n * 64 + k0 + quad * 8];
        #pragma unroll
        for (int p = 0; p < 4; ++p)
          acc2[tt][p] = __builtin_amdgcn_mfma_f32_16x16x32_bf16(a[p], b, acc2[tt][p], 0, 0, 0);
      }
    }
    __syncthreads();   // nb reads (ycf store) done -> nb reusable
    #pragma unroll
    for (int tt = 0; tt < 2; ++tt) {
      int n = w * 32 + tt * 16 + col;
      float bb = c2b[n];
      #pragma unroll
      for (int p = 0; p < 4; ++p)
        #pragma unroll
        for (int r = 0; r < 4; ++r)
          nb[(p * 16 + quad * 4 + r) * NB_LD + n] = f2bf(acc2[tt][p][r] + bb);
    }
    __syncthreads();
    for (int e = t; e < 1024; e += 256) {
      int row = e >> 4, c8 = (e & 15) << 3;
      *(uint4*)&yimg[(size_t)(pb + row) * 128 + c8] =
          *(const uint4*)&nb[row * NB_LD + c8];
    }
  }
}

// ---------------------------------------------------------------------------
// scan: exclusive prefix over NCELL cell counts (1 block, 11 cells/thread).
// ---------------------------------------------------------------------------
__global__ __launch_bounds__(256) void scan_kernel(
    const int* __restrict__ count, int* __restrict__ cellStart,
    int* __restrict__ cellofs) {
  __shared__ int part[256];
  int t = threadIdx.x;
  int local[11];
  int s = 0;
  #pragma unroll
  for (int j = 0; j < 11; ++j) {
    int idx = t * 11 + j;
    local[j] = s;
    s += (idx < NCELL) ? count[idx] : 0;
  }
  part[t] = s;
  __syncthreads();
  for (int off = 1; off < 256; off <<= 1) {
    int v = (t >= off) ? part[t - off] : 0;
    __syncthreads();
    part[t] += v;
    __syncthreads();
  }
  int base = part[t] - s;
  #pragma unroll
  for (int j = 0; j < 11; ++j) {
    int idx = t * 11 + j;
    int v = base + local[j];
    if (idx < NCELL) { cellStart[idx] = v; cellofs[idx] = v; }
  }
  if (t == 255) cellStart[NCELL] = part[255];
}

// ---------------------------------------------------------------------------
// scatter: points into cell-sorted order; original index packed into .w.
// ---------------------------------------------------------------------------
__global__ __launch_bounds__(256) void scatter_kernel(
    const float4* __restrict__ pts4, int* __restrict__ cellofs,
    float4* __restrict__ spts) {
  int p = blockIdx.x * 256 + threadIdx.x;
  float4 v = pts4[p];
  int pos = atomicAdd(&cellofs[cellid(v.x, v.y, v.z)], 1);
  spts[pos] = make_float4(v.x, v.y, v.z, __int_as_float(p));
}

// ---------------------------------------------------------------------------
// knng: grid KNN (exact top-16) fused with gather-max + feat pack.
// Cell-level trim + in-lane gather-max (R9).
// ---------------------------------------------------------------------------
__device__ __forceinline__ float tadj(float tau, float qw) {
  float a = tau - qw;
  return a + fabsf(a) * 2e-7f + 1e-35f;
}

template <int NS>
__device__ __forceinline__ u64 selimpl(u64* buf, int cnt, int lane,
                                       float& tau) {
  u64 v[NS];
  unsigned k[NS];
  #pragma unroll
  for (int s = 0; s < NS; ++s) {
    int idx = s * 64 + lane;
    v[s] = (idx < cnt) ? buf[idx] : ~0ULL;
    k[s] = (unsigned)(v[s] >> 32);
  }
  // phase 1: m = 16th smallest d2-bits (sentinel 0xFFFFFFFF sorts last)
  unsigned m = 0u;
  #pragma unroll
  for (int b = 31; b >= 0; --b) {
    unsigned probe = m | (1u << b);
    int c = 0;
    #pragma unroll
    for (int s = 0; s < NS; ++s) c += __popcll(__ballot(k[s] < probe));
    if (c < KNN) m = probe;
  }
  // phase 2: tie-break on oid among keys equal to m (rare).
  int c_lt = 0, ne = 0;
  bool e[NS];
  #pragma unroll
  for (int s = 0; s < NS; ++s) {
    c_lt += __popcll(__ballot(k[s] < m));
    e[s] = (k[s] == m);
    ne += __popcll(__ballot(e[s]));
  }
  int need_eq = KNN - c_lt;
  unsigned m2 = 0xFFFFFFFFu;
  if (ne != need_eq) {
    m2 = 0u;
    #pragma unroll
    for (int b = 13; b >= 0; --b) {
      unsigned probe = m2 | (1u << b);
      int c = 0;
      #pragma unroll
      for (int s = 0; s < NS; ++s)
        c += __popcll(__ballot(e[s] && ((unsigned)v[s] < probe)));
      if (c < need_eq) m2 = probe;
    }
  }
  // compact the exact top-16 set to buf[0..15]
  int base = 0;
  #pragma unroll
  for (int s = 0; s < NS; ++s) {
    bool sel = (k[s] < m) || (e[s] && ((unsigned)v[s] <= m2));
    u64 msk = __ballot(sel);
    if (sel) buf[base + lanerank(msk)] = v[s];
    base += __popcll(msk);
  }
  tau = __uint_as_float(m);
  if (!(tau == tau)) tau = INFINITY;  // cnt<16: sentinel bits are NaN
  return buf[lane & 15];
}

__device__ __forceinline__ u64 select16(u64* buf, int& cnt, int lane,
                                        float& tau) {
  u64 r = (cnt <= 64) ? selimpl<1>(buf, cnt, lane, tau)
                      : selimpl<2>(buf, cnt, lane, tau);
  cnt = KNN;
  return r;
}

__device__ __forceinline__ float truethr(float tau, float qw) {
  // conservative true-distance^2 threshold matching tadj's slack
  return tau + (tau + qw) * 3e-7f + 1e-30f;
}

__global__ __launch_bounds__(256) void knng_kernel(
    const float4* __restrict__ spts, const int* __restrict__ cellStart,
    const ushort_t* __restrict__ ycf, const ushort_t* __restrict__ yimg,
    const ushort_t* __restrict__ cfh, const ushort_t* __restrict__ imfh,
    ushort_t* __restrict__ featb) {
  __shared__ u64 sbuf[4][128];                 // 4 KB (only LDS left)
  int t = threadIdx.x;
  int wv = t >> 6, lane = t & 63;
  // XCD-chunked swizzle: each XCD's L2 holds one spatial slab.
  int sblk = (blockIdx.x & 7) * 512 + (blockIdx.x >> 3);
  int sid = sblk * 4 + wv;
  u64* buf = sbuf[wv];

  float4 q = spts[sid];                        // cell-sorted query
  int pid = __float_as_int(q.w);               // original point index
  float qw = fmaf(q.z, q.z, fmaf(q.y, q.y, q.x * q.x));
  float q2x = -2.f * q.x, q2y = -2.f * q.y, q2z = -2.f * q.z;
  int cx = cellof(q.x), cy = cellof(q.y), cz = cellof(q.z);

  // a-priori pruning radius: ~35 expected points in the clipped ball.
  float tau;
  {
    const float r0 = 0.0758f;  // (35*3/(4*pi*N))^(1/3) w/o clip
    float rr = r0;
    #pragma unroll
    for (int it = 0; it < 2; ++it) {
      float fx = (fminf(q.x + rr, 1.f) - fmaxf(q.x - rr, 0.f)) * (0.5f / rr);
      float fy = (fminf(q.y + rr, 1.f) - fmaxf(q.y - rr, 0.f)) * (0.5f / rr);
      float fz = (fminf(q.z + rr, 1.f) - fmaxf(q.z - rr, 0.f)) * (0.5f / rr);
      rr = r0 * __powf(fx * fy * fz, -0.333333f);
    }
    rr *= 1.05f;
    tau = rr * rr;
  }
  u64 vres;

  for (int r = 1;; ++r) {
    int lx = max(cx - r, 0), hx = min(cx + r, G - 1);
    int ly = max(cy - r, 0), hy = min(cy + r, G - 1);
    int lz = max(cz - r, 0), hz = min(cz + r, G - 1);
    int ny = hy - ly + 1, nz = hz - lz + 1, nruns = ny * nz;
    int cnt = 0;
    float ta = tadj(tau, qw);
    float tt = truethr(tau, qw);

    for (int rb = 0; rb < nruns; rb += 64) {
      int ln = rb + lane;
      int rs = 0, rc = 0;
      if (ln < nruns) {
        int z = lz + ln / ny, y = ly + ln % ny;
        // slab min-dist^2 trim (conservative: 1e-6 boundary shave)
        float loY = (float)y * (1.f / G), hiY = loY + (1.f / G);
        float loZ = (float)z * (1.f / G), hiZ = loZ + (1.f / G);
        float dy = fmaxf(fmaxf(loY - q.y, q.y - hiY) - 1e-6f, 0.f);
        float dz = fmaxf(fmaxf(loZ - q.z, q.z - hiZ) - 1e-6f, 0.f);
        float rem = tt - dy * dy - dz * dz;
        if (rem >= 0.f) {
          float rad = fminf(sqrtf(rem) + 1e-6f, 2.f);
          int xlo = max(lx, cellof(q.x - rad));
          int xhi = min(hx, cellof(q.x + rad));
          int row = (z * G + y) * G;
          rs = cellStart[row + xlo];
          rc = cellStart[row + xhi + 1] - rs;
        }
      }
      int nr = nruns - rb; nr = nr > 64 ? 64 : nr;
      int off = rc;
      #pragma unroll
      for (int d = 1; d < 64; d <<= 1) {
        int v = __shfl_up(off, d);
        if (lane >= d) off += v;
      }
      int T = __shfl(off, 63);
      off -= rc;

      for (int cb = 0; cb < T; cb += 64) {
        int rk = cb + lane;
        int j = 0;
        if (nr <= 16) {
          #pragma unroll
          for (int step = 8; step; step >>= 1) {
            int nj = j + step;
            if (__shfl(off, nj) <= rk) j = nj;
          }
        } else if (nr <= 32) {
          #pragma unroll
          for (int step = 16; step; step >>= 1) {
            int nj = j + step;
            if (__shfl(off, nj) <= rk) j = nj;
          }
        } else {
          #pragma unroll
          for (int step = 32; step; step >>= 1) {
            int nj = j + step;
            if (__shfl(off, nj) <= rk) j = nj;
          }
        }
        int src = __shfl(rs, j) + rk - __shfl(off, j);
        bool valid = rk < T;
        if (!valid) src = 0;
        float4 c = spts[src];
        float cw = fmaf(c.z, c.z, fmaf(c.y, c.y, c.x * c.x));
        float d2 = fmaf(q2x, c.x, fmaf(q2y, c.y, fmaf(q2z, c.z, cw)));
        bool pass = valid && (d2 <= ta);
        u64 mask = __ballot(pass);
        if (mask) {
          if (pass) {
            int oid = __float_as_int(c.w);
            u64 key = ((u64)__float_as_uint(fmaxf(d2 + qw, 0.f)) << 32) | (unsigned)oid;
            buf[cnt + lanerank(mask)] = key;
          }
          cnt += __popcll(mask);
          if (cnt > 64) {  // keep room for one more 64-append (buffer 128)
            select16(buf, cnt, lane, tau);
            ta = tadj(tau, qw);
            tt = truethr(tau, qw);
          }
        }
      }
    }
    u64 v = select16(buf, cnt, lane, tau);
    float cl = INFINITY;
    if (lx > 0)     cl = fminf(cl, q.x - (float)lx / (float)G);
    if (hx < G - 1) cl = fminf(cl, (float)(hx + 1) / (float)G - q.x);
    if (ly > 0)     cl = fminf(cl, q.y - (float)ly / (float)G);
    if (hy < G - 1) cl = fminf(cl, (float)(hy + 1) / (float)G - q.y);
    if (lz > 0)     cl = fminf(cl, q.z - (float)lz / (float)G);
    if (hz < G - 1) cl = fminf(cl, (float)(hz + 1) / (float)G - q.z);
    bool full = (lx == 0 && hx == G - 1 && ly == 0 && hy == G - 1 &&
                 lz == 0 && hz == G - 1);
    if (full || tau * 1.00002f <= cl * cl) { vres = v; break; }
  }

  // ---- softmax weights; dist recovered from key's high word (=|q-c|^2) ----
  int myid = (lane < KNN) ? (int)(unsigned)(vres & 0xffffffffULL) : 0;
  float mywg = 0.f;
  {
    float dd = __uint_as_float((unsigned)(vres >> 32));
    float dist = sqrtf(fmaxf(dd, 1e-12f));
    float md = (lane < KNN) ? dist : INFINITY;
    #pragma unroll
    for (int off = 1; off < KNN; off <<= 1) md = fminf(md, __shfl_xor(md, off));
    float e = __expf(md - dist);
    float se = (lane < KNN) ? e : 0.f;
    #pragma unroll
    for (int off = 1; off < KNN; off <<= 1) se += __shfl_xor(se, off);
    mywg = e / se;  // valid on lanes < 16
  }

  // ---- in-lane gather-max: lane owns channels (2*lane, 2*lane+1) ----
  float A0 = -INFINITY, A1 = -INFINITY, B0 = -INFINITY, B1 = -INFINITY;
  size_t coff = (size_t)(lane * 2);
  #pragma unroll
  for (int k = 0; k < KNN; ++k) {
    int id = __shfl(myid, k);      // constant lane -> v_readlane
    float wg = __shfl(mywg, k);
    unsigned v = *(const unsigned*)&ycf[(size_t)id * 128 + coff];
    unsigned u = *(const unsigned*)&yimg[(size_t)id * 128 + coff];
    A0 = fmaxf(A0, bflo(v) * wg);
    A1 = fmaxf(A1, bfhi(v) * wg);
    B0 = fmaxf(B0, bflo(u) * wg);
    B1 = fmaxf(B1, bfhi(u) * wg);
  }
  // ---- featb row: 4 direct u32 stores build the 832B bf16 row ----
  unsigned* frow = (unsigned*)(featb + (size_t)pid * 416);
  frow[lane] = (unsigned)f2bf(lrelu(A0)) | ((unsigned)f2bf(lrelu(A1)) << 16);
  frow[80 + lane] = (unsigned)f2bf(lrelu(B0)) | ((unsigned)f2bf(lrelu(B1)) << 16);
  if (lane < 16) {  // imf pairs 64..79 (channels 0..31)
    unsigned vi = *(const unsigned*)&imfh[(size_t)pid * 32 + lane * 2];
    frow[64 + lane] =
        (unsigned)f2bf(lrelu(bflo(vi))) | ((unsigned)f2bf(lrelu(bfhi(vi))) << 16);
  }
  unsigned vcf = *(const unsigned*)&cfh[(size_t)pid * 128 + coff];
  frow[144 + lane] =
      (unsigned)f2bf(lrelu(bflo(vcf))) | ((unsigned)f2bf(lrelu(bfhi(vcf))) << 16);
}

// ---------------------------------------------------------------------------
// fing: final GEMM on MFMA with fused transpose. C = fwh[32][416] x
// featb[pt][416]^T -> store directly to out[ch][N] (64B segments).
// ---------------------------------------------------------------------------
__global__ __launch_bounds__(256) void fing_kernel(
    const ushort_t* __restrict__ featb, const ushort_t* __restrict__ fwh,
    const float* __restrict__ fb, float* __restrict__ out) {
  int t = threadIdx.x;
  int wv = t >> 6, lane = t & 63;
  int col = lane & 15, quad = lane >> 4;
  int pbase = blockIdx.x * 64 + wv * 16;  // this wave's 16 points
  f32x4 acc[2];
  acc[0] = (f32x4){0.f, 0.f, 0.f, 0.f};
  acc[1] = (f32x4){0.f, 0.f, 0.f, 0.f};
  for (int k0 = 0; k0 < 416; k0 += 32) {
    bf16x8 b = *(const bf16x8*)&featb[(size_t)(pbase + col) * 416 + k0 + quad * 8];
    #pragma unroll
    for (int tt = 0; tt < 2; ++tt) {
      bf16x8 a = *(const bf16x8*)&fwh[(tt * 16 + col) * 416 + k0 + quad * 8];
      acc[tt] = __builtin_amdgcn_mfma_f32_16x16x32_bf16(a, b, acc[tt], 0, 0, 0);
    }
  }
  #pragma unroll
  for (int tt = 0; tt < 2; ++tt) {
    #pragma unroll
    for (int r = 0; r < 4; ++r) {
      int ch = tt * 16 + quad * 4 + r;
      out[(size_t)ch * N + pbase + col] = acc[tt][r] + fb[ch];
    }
  }
}

// ---------------------------------------------------------------------------
extern "C" void kernel_launch(void* const* d_in, const int* in_sizes, int n_in,
                              void* d_out, int out_size, void* d_ws, size_t ws_size,
                              hipStream_t stream) {
  const float* img   = (const float*)d_in[0];
  const float* cloud = (const float*)d_in[1];
  const float* c1w   = (const float*)d_in[2];
  const float* c1b   = (const float*)d_in[3];
  const float* c2w   = (const float*)d_in[4];
  const float* c2b   = (const float*)d_in[5];
  const float* ps1w  = (const float*)d_in[6];
  const float* ps1b  = (const float*)d_in[7];
  const float* ps2w  = (const float*)d_in[8];
  const float* ps2b  = (const float*)d_in[9];
  const float* p1w   = (const float*)d_in[10];
  const float* p1b   = (const float*)d_in[11];
  const float* p2w   = (const float*)d_in[12];
  const float* p2b   = (const float*)d_in[13];
  const float* fw    = (const float*)d_in[14];
  const float* fb    = (const float*)d_in[15];
  float* out = (float*)d_out;

  char* ws = (char*)d_ws;
  float4*   pts4  = (float4*)(ws + 0);             // 256 KB   -> 262144
  ushort_t* cfh   = (ushort_t*)(ws + 262144);      // 4 MB     -> 4456448
  ushort_t* imfh  = (ushort_t*)(ws + 4456448);     // 1 MB     -> 5505024
  ushort_t* w1h   = (ushort_t*)(ws + 5505024);     // 64 KB    -> 5570560
  ushort_t* w2h   = (ushort_t*)(ws + 5570560);     // 64 KB    -> 5636096
  ushort_t* c1h   = (ushort_t*)(ws + 5636096);     // 4 KB     -> 5640192
  ushort_t* c2h   = (ushort_t*)(ws + 5640192);     // 16 KB    -> 5656576
  ushort_t* ycf   = (ushort_t*)(ws + 5656576);     // 4 MB     -> 9850880
  ushort_t* yimg  = (ushort_t*)(ws + 9850880);     // 4 MB     -> 14045184
  float4*   spts  = (float4*)(ws + 14045184);      // 256 KB   -> 14307328
  int*      cellStart = (int*)(ws + 14307328);     // 16 KB    -> 14323712
  int*      cellofs   = (int*)(ws + 14323712);     // 16 KB    -> 14339840
  int*      count     = (int*)(ws + 14339840);     // 16 KB    -> 14356224
  ushort_t* fwh       = (ushort_t*)(ws + 14356224);// 32 KB    -> 14388992
  ushort_t* featb     = (ushort_t*)(ws + 14388992);// 13.6 MB  -> 28020480

  hipMemsetAsync(count, 0, NCELL * sizeof(int), stream);
  wconv_kernel<<<348, 256, 0, stream>>>(ps1w, ps2w, c1w, c2w, fw,
                                        w1h, w2h, c1h, c2h, fwh);
  prepf_kernel<<<256, 256, 0, stream>>>(img, cloud, p1w, p1b, p2w, p2b,
                                        w1h, ps1b, w2h, ps2b,
                                        c1h, c1b, c2h, c2b,
                                        pts4, cfh, imfh, ycf, yimg, count);
  scan_kernel<<<1, 256, 0, stream>>>(count, cellStart, cellofs);
  scatter_kernel<<<64, 256, 0, stream>>>(pts4, cellofs, spts);
  knng_kernel<<<N / 4, 256, 0, stream>>>(spts, cellStart,
                                         ycf, yimg, cfh, imfh, featb);
  fing_kernel<<<N / 64, 256, 0, stream>>>(featb, fwh, fb, out);
}